// Round 11
// baseline (3408.474 us; speedup 1.0000x reference)
//
#include <hip/hip_runtime.h>

#define B_ 64
#define R_ 196
#define F_ 2048
#define E_ 512
#define H_ 512
#define A_ 512
#define V_ 12000
#define L_ 24
#define NBLK 256

typedef __attribute__((ext_vector_type(8))) short bf16x8;
typedef __attribute__((ext_vector_type(4))) float f32x4;
typedef unsigned short ush;

__device__ __forceinline__ float fast_tanh(float x) {
    float t = __expf(2.f * x);
    return 1.f - 2.f / (t + 1.f);
}
__device__ __forceinline__ float fast_sig(float x) {
    return 1.f / (1.f + __expf(-x));
}
__device__ __forceinline__ ush f2bf(float x) {
    unsigned int u = __float_as_uint(x);
    return (ush)((u + 0x7fffu + ((u >> 16) & 1u)) >> 16);
}
__device__ __forceinline__ float bf2f(ush b) {
    return __uint_as_float(((unsigned int)b) << 16);
}

#define LROW 40   // LDS row stride (32 k-elems + 8 pad)

// device-scope barrier: one counter per barrier instance (memset each launch).
// Polling MUST be an atomic RMW (plain/volatile loads don't cross XCD L2s).
__device__ __forceinline__ void gbar(int* bar, int idx) {
    __syncthreads();
    if (threadIdx.x == 0) {
        __threadfence();                       // release: wbl2
        atomicAdd(bar + idx, 1);
        while (atomicAdd(bar + idx, 0) < NBLK)
            __builtin_amdgcn_s_sleep(2);
        __threadfence();                       // acquire: inv
    }
    __syncthreads();
}

// LSTM cell for (b, n=tid), step t (t=0 -> load h0). Single writer per b.
__device__ __forceinline__ float cell_compute(
    const float* __restrict__ gparts, const float* __restrict__ egates,
    const float* __restrict__ b_ih, const float* __restrict__ b_hh,
    float* __restrict__ c2, const float* __restrict__ h0f,
    ush* __restrict__ h_hi, ush* __restrict__ h_lo,
    ush* __restrict__ hallh, ush* __restrict__ halll,
    int b, int n, int t)
{
    float hh;
    if (t > 0) {
        const float* c_old = c2 + (size_t)((t - 1) & 1) * B_ * H_;
        float* c_new = c2 + (size_t)(t & 1) * B_ * H_;
        const float* eg = egates + ((size_t)b * L_ + (t - 1)) * 2048;
        float gi = b_ih[n] + b_hh[n] + eg[n];
        float gf = b_ih[n + 512] + b_hh[n + 512] + eg[n + 512];
        float gg = b_ih[n + 1024] + b_hh[n + 1024] + eg[n + 1024];
        float go = b_ih[n + 1536] + b_hh[n + 1536] + eg[n + 1536];
        #pragma unroll
        for (int z = 0; z < 8; ++z) {
            const float* gz = gparts + (size_t)z * B_ * 2048 + (size_t)b * 2048;
            gi += gz[n]; gf += gz[n + 512]; gg += gz[n + 1024]; go += gz[n + 1536];
        }
        const float cc = fast_sig(gf) * c_old[b * H_ + n] + fast_sig(gi) * fast_tanh(gg);
        hh = fast_sig(go) * fast_tanh(cc);
        c_new[b * H_ + n] = cc;
        const ush hi = f2bf(hh);
        const ush lo = f2bf(hh - bf2f(hi));
        h_hi[b * H_ + n] = hi;
        h_lo[b * H_ + n] = lo;
        const size_t hidx = ((size_t)(t - 1) * B_ + b) * H_ + n;
        hallh[hidx] = hi;
        halll[hidx] = lo;
    } else {
        hh = h0f[b * H_ + n];
    }
    return hh;
}

// ---------------------------------------------------------------------------
// Persistent loop kernel: 256 blocks x 512 threads, all 24 steps.
// Per step: P1 (64 blocks): cell + hid_proj + scores + softmax -> alpha.
//           P2 (256): ctx quarter per (b, fs).  P3 (256): gates tile -> gparts.
// 3 device barriers per step.
// ---------------------------------------------------------------------------
__global__ __launch_bounds__(512) void loop_kernel(
    float* __restrict__ gparts, const float* __restrict__ egates,
    const float* __restrict__ b_ih, const float* __restrict__ b_hh,
    float* __restrict__ c2, const float* __restrict__ h0f,
    ush* __restrict__ h_hi, ush* __restrict__ h_lo,
    ush* __restrict__ hallh, ush* __restrict__ halll,
    const ush* __restrict__ whpT, const float* __restrict__ b_hidp,
    const ush* __restrict__ fpb, const float* __restrict__ W_score,
    const float* __restrict__ b_score, const ush* __restrict__ fbh,
    ush* __restrict__ ctx_hi, ush* __restrict__ ctx_lo,
    float* __restrict__ alpha_glob, float* __restrict__ alph_out,
    const ush* __restrict__ wg2h, const ush* __restrict__ wg2l,
    int* bar)
{
    __shared__ __align__(16) char smem[20480];
    const int bid = blockIdx.x, tid = threadIdx.x;
    const int lane = tid & 63, w = tid >> 6;

    for (int t = 0; t < L_; ++t) {
        // ---- P1: cell + attention scores + softmax (blocks 0..63) ----
        if (bid < B_) {
            float* sh_h  = (float*)smem;
            float* sh_hp = (float*)(smem + 2048);
            float* sh_ws = (float*)(smem + 4096);
            float* sh_sc = (float*)(smem + 6144);
            float* red   = (float*)(smem + 7168);
            const int b = bid;
            const float hh = cell_compute(gparts, egates, b_ih, b_hh, c2, h0f,
                                          h_hi, h_lo, hallh, halll, b, tid, t);
            sh_h[tid] = hh;
            sh_ws[tid] = W_score[tid];
            __syncthreads();

            {   // hid_proj: thread tid computes hp[tid] (coalesced bf16 whpT)
                float a0 = 0.f, a1 = 0.f, a2 = 0.f, a3 = 0.f;
                #pragma unroll 4
                for (int k = 0; k < H_; k += 4) {
                    a0 = fmaf(sh_h[k + 0], bf2f(whpT[(size_t)(k + 0) * A_ + tid]), a0);
                    a1 = fmaf(sh_h[k + 1], bf2f(whpT[(size_t)(k + 1) * A_ + tid]), a1);
                    a2 = fmaf(sh_h[k + 2], bf2f(whpT[(size_t)(k + 2) * A_ + tid]), a2);
                    a3 = fmaf(sh_h[k + 3], bf2f(whpT[(size_t)(k + 3) * A_ + tid]), a3);
                }
                sh_hp[tid] = (a0 + a1) + (a2 + a3) + b_hidp[tid];
            }
            __syncthreads();

            for (int r = w; r < R_; r += 8) {
                const ushort2* row = reinterpret_cast<const ushort2*>(fpb + ((size_t)b * R_ + r) * A_);
                float acc = 0.f;
                #pragma unroll
                for (int j = 0; j < 4; ++j) {
                    const ushort2 u = row[lane + 64 * j];
                    const int a = 2 * (lane + 64 * j);
                    acc += fast_tanh(bf2f(u.x) + sh_hp[a]) * sh_ws[a];
                    acc += fast_tanh(bf2f(u.y) + sh_hp[a + 1]) * sh_ws[a + 1];
                }
                for (int off = 32; off > 0; off >>= 1) acc += __shfl_down(acc, off);
                if (lane == 0) sh_sc[r] = acc + b_score[0];
            }
            __syncthreads();

            if (tid < 64) {
                float m = -1e30f;
                for (int r = tid; r < R_; r += 64) m = fmaxf(m, sh_sc[r]);
                for (int off = 32; off > 0; off >>= 1) m = fmaxf(m, __shfl_xor(m, off));
                float s = 0.f;
                for (int r = tid; r < R_; r += 64) s += __expf(sh_sc[r] - m);
                for (int off = 32; off > 0; off >>= 1) s += __shfl_xor(s, off);
                if (tid == 0) { red[0] = m; red[1] = 1.f / s; }
            }
            __syncthreads();
            const float m = red[0], is = red[1];
            if (tid < R_) {
                const float av = __expf(sh_sc[tid] - m) * is;
                alpha_glob[b * R_ + tid] = av;
                alph_out[((size_t)b * L_ + t) * R_ + tid] = av;
            }
        }
        gbar(bar, 3 * t);

        // ---- P2: context quarters (all 256 blocks: b=bid>>2, fs=bid&3) ----
        {
            float* sa = (float*)smem;
            const int b = bid >> 2, fs = bid & 3;
            if (tid < R_) sa[tid] = alpha_glob[b * R_ + tid];
            __syncthreads();
            const int f0 = fs * 512 + tid;
            const ush* fp2 = fbh + (size_t)b * R_ * F_ + f0;
            float cx = 0.f;
            #pragma unroll 4
            for (int r = 0; r < R_; ++r)
                cx = fmaf(sa[r], bf2f(fp2[(size_t)r * F_]), cx);
            const size_t ci = (size_t)b * F_ + f0;
            const ush hx = f2bf(cx);
            ctx_hi[ci] = hx;
            ctx_lo[ci] = f2bf(cx - bf2f(hx));
        }
        gbar(bar, 3 * t + 1);

        // ---- P3: gates tile (all 256 blocks: nt=bid&31, z=bid>>5) ----
        {
            ush* sAh = (ush*)smem;
            ush* sBh = (ush*)(smem + 5120);
            ush* sAl = (ush*)(smem + 10240);
            ush* sBl = (ush*)(smem + 15360);
            const int nt = bid & 31, z = bid >> 5;
            const int ntile = nt * 64;
            const int nw = w & 3, mbase = (w >> 2) * 2;
            const int fr = lane & 15, kg = (lane >> 4) * 8;
            const int lrow = tid >> 2, lcol = (tid & 3) * 8;
            f32x4 acc0 = {0.f, 0.f, 0.f, 0.f};
            f32x4 acc1 = {0.f, 0.f, 0.f, 0.f};

            for (int kb = z * 320; kb < z * 320 + 320; kb += 32) {
                uint4 a_h, a_l, b_h4, b_l4;
                if (tid < 256) {
                    const ush *ph, *pl; int lda, loc;
                    if (kb < F_) { ph = ctx_hi; pl = ctx_lo; lda = F_; loc = kb; }
                    else         { ph = h_hi;   pl = h_lo;   lda = H_; loc = kb - F_; }
                    a_h  = *(const uint4*)(ph + (size_t)lrow * lda + loc + lcol);
                    a_l  = *(const uint4*)(pl + (size_t)lrow * lda + loc + lcol);
                    b_h4 = *(const uint4*)(wg2h + (size_t)(ntile + lrow) * (F_ + H_) + kb + lcol);
                    b_l4 = *(const uint4*)(wg2l + (size_t)(ntile + lrow) * (F_ + H_) + kb + lcol);
                }
                __syncthreads();
                if (tid < 256) {
                    *(uint4*)(sAh + lrow * LROW + lcol) = a_h;
                    *(uint4*)(sBh + lrow * LROW + lcol) = b_h4;
                    *(uint4*)(sAl + lrow * LROW + lcol) = a_l;
                    *(uint4*)(sBl + lrow * LROW + lcol) = b_l4;
                }
                __syncthreads();

                const bf16x8 bh = *(const bf16x8*)(sBh + (16 * nw + fr) * LROW + kg);
                const bf16x8 bl = *(const bf16x8*)(sBl + (16 * nw + fr) * LROW + kg);
                {
                    const bf16x8 ah = *(const bf16x8*)(sAh + (16 * mbase + fr) * LROW + kg);
                    const bf16x8 al = *(const bf16x8*)(sAl + (16 * mbase + fr) * LROW + kg);
                    acc0 = __builtin_amdgcn_mfma_f32_16x16x32_bf16(ah, bh, acc0, 0, 0, 0);
                    acc0 = __builtin_amdgcn_mfma_f32_16x16x32_bf16(ah, bl, acc0, 0, 0, 0);
                    acc0 = __builtin_amdgcn_mfma_f32_16x16x32_bf16(al, bh, acc0, 0, 0, 0);
                }
                {
                    const bf16x8 ah = *(const bf16x8*)(sAh + (16 * (mbase + 1) + fr) * LROW + kg);
                    const bf16x8 al = *(const bf16x8*)(sAl + (16 * (mbase + 1) + fr) * LROW + kg);
                    acc1 = __builtin_amdgcn_mfma_f32_16x16x32_bf16(ah, bh, acc1, 0, 0, 0);
                    acc1 = __builtin_amdgcn_mfma_f32_16x16x32_bf16(ah, bl, acc1, 0, 0, 0);
                    acc1 = __builtin_amdgcn_mfma_f32_16x16x32_bf16(al, bh, acc1, 0, 0, 0);
                }
            }

            float* Cz = gparts + (size_t)z * B_ * 2048;
            const int n = ntile + 16 * nw + fr;
            #pragma unroll
            for (int rr = 0; rr < 4; ++rr) {
                Cz[(size_t)(16 * mbase + (lane >> 4) * 4 + rr) * 2048 + n] = acc0[rr];
                Cz[(size_t)(16 * (mbase + 1) + (lane >> 4) * 4 + rr) * 2048 + n] = acc1[rr];
            }
        }
        gbar(bar, 3 * t + 2);
    }

    // ---- final cell: h_L -> hall[L-1] ----
    if (bid < B_) {
        cell_compute(gparts, egates, b_ih, b_hh, c2, h0f,
                     h_hi, h_lo, hallh, halll, bid, tid, L_);
    }
}

// ---------------------------------------------------------------------------
// gemm_big128: pred GEMM (128x256 tile, 512 thr). CMAP=2: pred layout, NT.
// ---------------------------------------------------------------------------
template<int SPLIT, int CMAP, bool NFAST>
__global__ __launch_bounds__(512) void gemm_big128(
    const ush* __restrict__ Ah, const ush* __restrict__ Al, int lda,
    const ush* __restrict__ Wh, const ush* __restrict__ Wl, int ldw,
    const float* __restrict__ bias, void* __restrict__ Cv,
    int ldc, int N, int K)
{
    constexpr int SMEM_BYTES = (SPLIT == 3) ? 61440 : 30720;
    __shared__ __align__(16) char smem[SMEM_BYTES];
    ush* sAh = (ush*)smem;
    ush* sBh = (ush*)(smem + 10240);
    ush* sAl = (ush*)(smem + 30720);
    ush* sBl = (ush*)(smem + 40960);

    const int tid = threadIdx.x;
    const int lane = tid & 63, w = tid >> 6;
    const int mw = w >> 2, nw = w & 3;

    const int nbx = gridDim.x, nby = gridDim.y;
    const int nwg = nbx * nby;
    const int orig = blockIdx.x + nbx * blockIdx.y;
    const int q = nwg >> 3, r = nwg & 7;
    const int xcd = orig & 7, idx = orig >> 3;
    const int lin = (xcd < r ? xcd * (q + 1) : r * (q + 1) + (xcd - r) * q) + idx;
    int bx, by;
    if constexpr (NFAST) { by = lin % nby; bx = lin / nby; }
    else                 { bx = lin % nbx; by = lin / nbx; }
    const int mtile = bx * 128;
    const int ntile = by * 256;

    const int fr = lane & 15, kg = (lane >> 4) * 8;
    const int arow = tid >> 2, aq = (tid & 3) * 8;

    f32x4 acc[4][4];
    #pragma unroll
    for (int mf = 0; mf < 4; ++mf)
        #pragma unroll
        for (int nf = 0; nf < 4; ++nf) acc[mf][nf] = {0.f, 0.f, 0.f, 0.f};

    const uint4 zv = make_uint4(0u, 0u, 0u, 0u);

    for (int kb = 0; kb < K; kb += 32) {
        uint4 a_h = *(const uint4*)(Ah + (size_t)(mtile + arow) * lda + kb + aq);
        uint4 a_l;
        uint4 b_h[2], b_l[2];
        #pragma unroll
        for (int p = 0; p < 2; ++p) {
            const int row = ntile + arow + 128 * p;
            b_h[p] = (row < N) ? *(const uint4*)(Wh + (size_t)row * ldw + kb + aq) : zv;
        }
        if constexpr (SPLIT == 3) {
            a_l = *(const uint4*)(Al + (size_t)(mtile + arow) * lda + kb + aq);
            #pragma unroll
            for (int p = 0; p < 2; ++p) {
                const int row = ntile + arow + 128 * p;
                b_l[p] = (row < N) ? *(const uint4*)(Wl + (size_t)row * ldw + kb + aq) : zv;
            }
        }

        __syncthreads();
        *(uint4*)(sAh + arow * LROW + aq) = a_h;
        #pragma unroll
        for (int p = 0; p < 2; ++p)
            *(uint4*)(sBh + (arow + 128 * p) * LROW + aq) = b_h[p];
        if constexpr (SPLIT == 3) {
            *(uint4*)(sAl + arow * LROW + aq) = a_l;
            #pragma unroll
            for (int p = 0; p < 2; ++p)
                *(uint4*)(sBl + (arow + 128 * p) * LROW + aq) = b_l[p];
        }
        __syncthreads();

        bf16x8 bh[4], bl[4];
        #pragma unroll
        for (int nf = 0; nf < 4; ++nf) {
            bh[nf] = *(const bf16x8*)(sBh + (nw * 64 + nf * 16 + fr) * LROW + kg);
            if constexpr (SPLIT == 3)
                bl[nf] = *(const bf16x8*)(sBl + (nw * 64 + nf * 16 + fr) * LROW + kg);
        }
        #pragma unroll
        for (int mf = 0; mf < 4; ++mf) {
            const bf16x8 ah = *(const bf16x8*)(sAh + (mw * 64 + mf * 16 + fr) * LROW + kg);
            if constexpr (SPLIT == 3) {
                const bf16x8 al = *(const bf16x8*)(sAl + (mw * 64 + mf * 16 + fr) * LROW + kg);
                #pragma unroll
                for (int nf = 0; nf < 4; ++nf) {
                    acc[mf][nf] = __builtin_amdgcn_mfma_f32_16x16x32_bf16(ah, bh[nf], acc[mf][nf], 0, 0, 0);
                    acc[mf][nf] = __builtin_amdgcn_mfma_f32_16x16x32_bf16(ah, bl[nf], acc[mf][nf], 0, 0, 0);
                    acc[mf][nf] = __builtin_amdgcn_mfma_f32_16x16x32_bf16(al, bh[nf], acc[mf][nf], 0, 0, 0);
                }
            } else {
                #pragma unroll
                for (int nf = 0; nf < 4; ++nf)
                    acc[mf][nf] = __builtin_amdgcn_mfma_f32_16x16x32_bf16(ah, bh[nf], acc[mf][nf], 0, 0, 0);
            }
        }
    }

    #pragma unroll
    for (int nf = 0; nf < 4; ++nf) {
        const int nn = ntile + nw * 64 + nf * 16 + fr;
        if (nn < N) {
            const float bv = bias ? bias[nn] : 0.f;
            #pragma unroll
            for (int mf = 0; mf < 4; ++mf) {
                #pragma unroll
                for (int rr = 0; rr < 4; ++rr) {
                    const int m = mtile + mw * 64 + mf * 16 + (lane >> 4) * 4 + rr;
                    const float v = acc[mf][nf][rr] + bv;
                    if constexpr (CMAP == 1)
                        ((ush*)Cv)[(size_t)m * ldc + nn] = f2bf(v);
                    else if constexpr (CMAP == 2) {
                        float* dst = (float*)Cv + (size_t)(m & 63) * (L_ * V_)
                                   + (size_t)(m >> 6) * V_ + nn;
                        __builtin_nontemporal_store(v, dst);
                    } else
                        ((float*)Cv)[(size_t)m * ldc + nn] = v;
                }
            }
        }
    }
}

// ---------------------------------------------------------------------------
// gemm_big: 64M x (64*NF)N tile, 256 threads. NF=1 for feat_proj.
// ---------------------------------------------------------------------------
template<int SPLIT, int CMAP, bool NFAST, int NF>
__global__ __launch_bounds__(256) void gemm_big(
    const ush* __restrict__ Ah, const ush* __restrict__ Al, int lda,
    const ush* __restrict__ Wh, const ush* __restrict__ Wl, int ldw,
    const float* __restrict__ bias, void* __restrict__ Cv,
    int ldc, int N, int K)
{
    constexpr int ABYTES = 64 * LROW * 2;
    constexpr int BBYTES = 64 * NF * LROW * 2;
    constexpr int SMEM_BYTES = (SPLIT == 3) ? 2 * (ABYTES + BBYTES) : (ABYTES + BBYTES);
    __shared__ __align__(16) char smem[SMEM_BYTES];
    ush* sAh = (ush*)smem;
    ush* sBh = (ush*)(smem + ABYTES);
    ush* sAl = (ush*)(smem + ABYTES + BBYTES);
    ush* sBl = (ush*)(smem + 2 * ABYTES + BBYTES);

    const int tid = threadIdx.x;
    const int lane = tid & 63, w = tid >> 6;

    const int nbx = gridDim.x, nby = gridDim.y;
    const int nwg = nbx * nby;
    int lin = blockIdx.x + nbx * blockIdx.y;
    if ((nwg & 7) == 0) {
        const int q = nwg >> 3;
        lin = (lin & 7) * q + (lin >> 3);
    }
    int bx, by;
    if constexpr (NFAST) { by = lin % nby; bx = lin / nby; }
    else                 { bx = lin % nbx; by = lin / nbx; }
    const int mtile = bx * 64;
    const int ntile = by * (64 * NF);

    const int fr = lane & 15, kg = (lane >> 4) * 8;
    const int arow = tid >> 2, aq = (tid & 3) * 8;

    f32x4 acc[4][NF];
    #pragma unroll
    for (int mf = 0; mf < 4; ++mf)
        #pragma unroll
        for (int nf = 0; nf < NF; ++nf) acc[mf][nf] = {0.f, 0.f, 0.f, 0.f};

    const uint4 zv = make_uint4(0u, 0u, 0u, 0u);

    for (int kb = 0; kb < K; kb += 32) {
        uint4 a_h = *(const uint4*)(Ah + (size_t)(mtile + arow) * lda + kb + aq);
        uint4 a_l;
        uint4 b_h[NF], b_l[NF];
        #pragma unroll
        for (int p = 0; p < NF; ++p) {
            const int row = ntile + arow + 64 * p;
            b_h[p] = (row < N) ? *(const uint4*)(Wh + (size_t)row * ldw + kb + aq) : zv;
        }
        if constexpr (SPLIT == 3) {
            a_l = *(const uint4*)(Al + (size_t)(mtile + arow) * lda + kb + aq);
            #pragma unroll
            for (int p = 0; p < NF; ++p) {
                const int row = ntile + arow + 64 * p;
                b_l[p] = (row < N) ? *(const uint4*)(Wl + (size_t)row * ldw + kb + aq) : zv;
            }
        }

        __syncthreads();
        *(uint4*)(sAh + arow * LROW + aq) = a_h;
        #pragma unroll
        for (int p = 0; p < NF; ++p)
            *(uint4*)(sBh + (arow + 64 * p) * LROW + aq) = b_h[p];
        if constexpr (SPLIT == 3) {
            *(uint4*)(sAl + arow * LROW + aq) = a_l;
            #pragma unroll
            for (int p = 0; p < NF; ++p)
                *(uint4*)(sBl + (arow + 64 * p) * LROW + aq) = b_l[p];
        }
        __syncthreads();

        bf16x8 bh[NF], bl[NF];
        #pragma unroll
        for (int nf = 0; nf < NF; ++nf) {
            bh[nf] = *(const bf16x8*)(sBh + (w * (16 * NF) + nf * 16 + fr) * LROW + kg);
            if constexpr (SPLIT == 3)
                bl[nf] = *(const bf16x8*)(sBl + (w * (16 * NF) + nf * 16 + fr) * LROW + kg);
        }
        #pragma unroll
        for (int mf = 0; mf < 4; ++mf) {
            const bf16x8 ah = *(const bf16x8*)(sAh + (mf * 16 + fr) * LROW + kg);
            if constexpr (SPLIT == 3) {
                const bf16x8 al = *(const bf16x8*)(sAl + (mf * 16 + fr) * LROW + kg);
                #pragma unroll
                for (int nf = 0; nf < NF; ++nf) {
                    acc[mf][nf] = __builtin_amdgcn_mfma_f32_16x16x32_bf16(ah, bh[nf], acc[mf][nf], 0, 0, 0);
                    acc[mf][nf] = __builtin_amdgcn_mfma_f32_16x16x32_bf16(ah, bl[nf], acc[mf][nf], 0, 0, 0);
                    acc[mf][nf] = __builtin_amdgcn_mfma_f32_16x16x32_bf16(al, bh[nf], acc[mf][nf], 0, 0, 0);
                }
            } else {
                #pragma unroll
                for (int nf = 0; nf < NF; ++nf)
                    acc[mf][nf] = __builtin_amdgcn_mfma_f32_16x16x32_bf16(ah, bh[nf], acc[mf][nf], 0, 0, 0);
            }
        }
    }

    #pragma unroll
    for (int nf = 0; nf < NF; ++nf) {
        const int nn = ntile + w * (16 * NF) + nf * 16 + fr;
        if (nn < N) {
            const float bv = bias ? bias[nn] : 0.f;
            #pragma unroll
            for (int mf = 0; mf < 4; ++mf) {
                #pragma unroll
                for (int rr = 0; rr < 4; ++rr) {
                    const int m = mtile + mf * 16 + (lane >> 4) * 4 + rr;
                    const float v = acc[mf][nf][rr] + bv;
                    if constexpr (CMAP == 1)
                        ((ush*)Cv)[(size_t)m * ldc + nn] = f2bf(v);
                    else
                        ((float*)Cv)[(size_t)m * ldc + nn] = v;
                }
            }
        }
    }
}

// ---------------------------------------------------------------------------
// gemm_gates: 64x64 tile, 256 threads, segmented A, split-K (init GEMM only).
// ---------------------------------------------------------------------------
__global__ __launch_bounds__(256) void gemm_gates(
    const ush* __restrict__ Ah0, const ush* __restrict__ Al0, int lda0, int k0,
    const ush* __restrict__ Ah1, const ush* __restrict__ Al1, int lda1,
    const ush* __restrict__ Wh, const ush* __restrict__ Wl, int ldw,
    float* __restrict__ C, int ldc, long zstride, int kChunk)
{
    __shared__ ush sAh[64 * LROW];
    __shared__ ush sBh[64 * LROW];
    __shared__ ush sAl[64 * LROW];
    __shared__ ush sBl[64 * LROW];

    const int tid = threadIdx.x;
    const int ntile = blockIdx.x * 64;
    const int kStart = blockIdx.z * kChunk;
    const int lane = tid & 63, w = tid >> 6;
    const int lrow = tid >> 2;
    const int lcol = (tid & 3) * 8;
    const int nrow = ntile + lrow;

    f32x4 acc[4];
    #pragma unroll
    for (int f = 0; f < 4; ++f) acc[f] = {0.f, 0.f, 0.f, 0.f};

    const int fr = lane & 15;
    const int kg = (lane >> 4) * 8;

    for (int kb = kStart; kb < kStart + kChunk; kb += 32) {
        const ush *ph, *pl; int lda, loc;
        if (kb < k0) { ph = Ah0; pl = Al0; lda = lda0; loc = kb; }
        else         { ph = Ah1; pl = Al1; lda = lda1; loc = kb - k0; }

        uint4 a_h = *(const uint4*)(ph + (size_t)lrow * lda + loc + lcol);
        uint4 b_h = *(const uint4*)(Wh + (size_t)nrow * ldw + kb + lcol);
        uint4 a_l = *(const uint4*)(pl + (size_t)lrow * lda + loc + lcol);
        uint4 b_l = *(const uint4*)(Wl + (size_t)nrow * ldw + kb + lcol);

        __syncthreads();
        *(uint4*)(sAh + lrow * LROW + lcol) = a_h;
        *(uint4*)(sBh + lrow * LROW + lcol) = b_h;
        *(uint4*)(sAl + lrow * LROW + lcol) = a_l;
        *(uint4*)(sBl + lrow * LROW + lcol) = b_l;
        __syncthreads();

        const bf16x8 bh = *(const bf16x8*)(sBh + (16 * w + fr) * LROW + kg);
        const bf16x8 bl = *(const bf16x8*)(sBl + (16 * w + fr) * LROW + kg);

        #pragma unroll
        for (int f = 0; f < 4; ++f) {
            const bf16x8 ah = *(const bf16x8*)(sAh + (16 * f + fr) * LROW + kg);
            const bf16x8 al = *(const bf16x8*)(sAl + (16 * f + fr) * LROW + kg);
            acc[f] = __builtin_amdgcn_mfma_f32_16x16x32_bf16(ah, bh, acc[f], 0, 0, 0);
            acc[f] = __builtin_amdgcn_mfma_f32_16x16x32_bf16(ah, bl, acc[f], 0, 0, 0);
            acc[f] = __builtin_amdgcn_mfma_f32_16x16x32_bf16(al, bh, acc[f], 0, 0, 0);
        }
    }

    const int n = ntile + 16 * w + (lane & 15);
    float* Cz = C + (size_t)blockIdx.z * zstride;
    #pragma unroll
    for (int f = 0; f < 4; ++f)
        #pragma unroll
        for (int rr = 0; rr < 4; ++rr) {
            const int m = 16 * f + (lane >> 4) * 4 + rr;
            Cz[(size_t)m * ldc + n] = acc[f][rr];
        }
}

// fused feats pass: fbh (bf16) + per-(b,f) mean -> mh/ml. block (fs, b).
__global__ __launch_bounds__(256) void prep_feats(
    const float* __restrict__ feats, ush* __restrict__ fbh,
    ush* __restrict__ mh, ush* __restrict__ ml)
{
    const int fs = blockIdx.x;
    const int b  = blockIdx.y;
    const int f = fs * 512 + threadIdx.x * 2;
    const float2* fp = (const float2*)(feats + (size_t)b * R_ * F_ + f);
    ush* fo = fbh + (size_t)b * R_ * F_ + f;
    float sx = 0.f, sy = 0.f;
    for (int r = 0; r < R_; ++r) {
        const float2 v = fp[(size_t)r * (F_ / 2)];
        sx += v.x; sy += v.y;
        ushort2 u; u.x = f2bf(v.x); u.y = f2bf(v.y);
        *(ushort2*)(fo + (size_t)r * F_) = u;
    }
    const float s = 1.f / (float)R_;
    sx *= s; sy *= s;
    const size_t mi = (size_t)b * F_ + f;
    const ush hx = f2bf(sx); mh[mi] = hx;     ml[mi] = f2bf(sx - bf2f(hx));
    const ush hy = f2bf(sy); mh[mi + 1] = hy; ml[mi + 1] = f2bf(sy - bf2f(hy));
}

// gather embeddings -> bf16 hi/lo (B,L,E)
__global__ __launch_bounds__(256) void gather_split(
    const float* __restrict__ emb, const int* __restrict__ cap,
    ush* __restrict__ eh, ush* __restrict__ el)
{
    const int idx = blockIdx.x * 256 + threadIdx.x;
    const int bt = idx >> 7, j = idx & 127;
    const int tok = cap[bt];
    const float4 v = reinterpret_cast<const float4*>(emb)[(size_t)tok * (E_ / 4) + j];
    const float a[4] = {v.x, v.y, v.z, v.w};
    #pragma unroll
    for (int c = 0; c < 4; ++c) {
        const ush hi = f2bf(a[c]);
        eh[idx * 4 + c] = hi;
        el[idx * 4 + c] = f2bf(a[c] - bf2f(hi));
    }
}

// generic fp32 -> bf16 (hi, optional lo)
__global__ __launch_bounds__(256) void split_kernel(
    const float* __restrict__ in, ush* __restrict__ hi, ush* __restrict__ lo, int n4)
{
    for (int i = blockIdx.x * 256 + threadIdx.x; i < n4; i += gridDim.x * 256) {
        const float4 v = reinterpret_cast<const float4*>(in)[i];
        const float a[4] = {v.x, v.y, v.z, v.w};
        #pragma unroll
        for (int c = 0; c < 4; ++c) {
            const ush h = f2bf(a[c]);
            hi[i * 4 + c] = h;
            if (lo) lo[i * 4 + c] = f2bf(a[c] - bf2f(h));
        }
    }
}

// W_ih columns [0:E) -> wx (2048x512); [E:) ++ W_hh -> wg2 (2048x2560); hi/lo
__global__ __launch_bounds__(256) void prep_wih(
    const float* __restrict__ W_ih, const float* __restrict__ W_hh,
    ush* __restrict__ wxh, ush* __restrict__ wxl,
    ush* __restrict__ wg2h, ush* __restrict__ wg2l)
{
    const int nrow = blockIdx.x;
    for (int k = threadIdx.x; k < E_; k += 256) {
        const float v = W_ih[(size_t)nrow * (E_ + F_) + k];
        const ush h = f2bf(v);
        wxh[(size_t)nrow * E_ + k] = h;
        wxl[(size_t)nrow * E_ + k] = f2bf(v - bf2f(h));
    }
    for (int k = threadIdx.x; k < F_ + H_; k += 256) {
        const float v = (k < F_) ? W_ih[(size_t)nrow * (E_ + F_) + E_ + k]
                                 : W_hh[(size_t)nrow * H_ + (k - F_)];
        const ush h = f2bf(v);
        wg2h[(size_t)nrow * (F_ + H_) + k] = h;
        wg2l[(size_t)nrow * (F_ + H_) + k] = f2bf(v - bf2f(h));
    }
}

// transpose W_hidp (A x H) -> whpT (H x A), bf16
__global__ __launch_bounds__(256) void transpose512(
    const float* __restrict__ in, ush* __restrict__ out)
{
    const int idx = blockIdx.x * 256 + threadIdx.x;
    const int k = idx >> 9, a = idx & 511;
    out[idx] = f2bf(in[(size_t)a * 512 + k]);
}

// reduce init GEMM partials: n<512 -> h0 (+split), n>=512 -> c0 (buffer 0)
__global__ __launch_bounds__(256) void init_reduce(
    const float* __restrict__ initp, const float* __restrict__ b_init_h,
    const float* __restrict__ b_init_c, float* __restrict__ h0f,
    float* __restrict__ c0, ush* __restrict__ h_hi, ush* __restrict__ h_lo)
{
    const int idx = blockIdx.x * 256 + threadIdx.x;
    const int b = idx >> 10, n = idx & 1023;
    float s = 0.f;
    #pragma unroll
    for (int z = 0; z < 8; ++z)
        s += initp[(size_t)z * (B_ * 1024) + (size_t)b * 1024 + n];
    if (n < 512) {
        s += b_init_h[n];
        h0f[b * H_ + n] = s;
        const ush hi = f2bf(s);
        h_hi[b * H_ + n] = hi;
        h_lo[b * H_ + n] = f2bf(s - bf2f(hi));
    } else {
        s += b_init_c[n - 512];
        c0[b * H_ + (n - 512)] = s;
    }
}

extern "C" void kernel_launch(void* const* d_in, const int* in_sizes, int n_in,
                              void* d_out, int out_size, void* d_ws, size_t ws_size,
                              hipStream_t stream)
{
    const float* feats    = (const float*)d_in[0];
    const int*   cap      = (const int*)  d_in[1];
    const float* emb      = (const float*)d_in[2];
    const float* W_init_h = (const float*)d_in[3];
    const float* b_init_h = (const float*)d_in[4];
    const float* W_init_c = (const float*)d_in[5];
    const float* b_init_c = (const float*)d_in[6];
    const float* W_ih     = (const float*)d_in[7];
    const float* b_ih     = (const float*)d_in[8];
    const float* W_hh     = (const float*)d_in[9];
    const float* b_hh     = (const float*)d_in[10];
    const float* W_featp  = (const float*)d_in[11];
    const float* b_featp  = (const float*)d_in[12];
    const float* W_hidp   = (const float*)d_in[13];
    const float* b_hidp   = (const float*)d_in[14];
    const float* W_score  = (const float*)d_in[15];
    const float* b_score  = (const float*)d_in[16];
    const float* W_out    = (const float*)d_in[17];
    const float* b_out    = (const float*)d_in[18];

    float* pred     = (float*)d_out;                          // (B,L,V)
    float* alph_out = pred + (size_t)B_ * L_ * V_;            // (B,L,R)

    char* p = (char*)d_ws;
    auto alloc = [&](size_t bytes) { char* q = p; p += (bytes + 255) & ~(size_t)255; return q; };

    ush*   fpb    = (ush*)  alloc((size_t)B_ * R_ * A_ * 2);
    ush*   eh     = (ush*)  alloc((size_t)B_ * L_ * E_ * 2);
    ush*   el     = (ush*)  alloc((size_t)B_ * L_ * E_ * 2);
    ush*   mh     = (ush*)  alloc((size_t)B_ * F_ * 2);
    ush*   ml     = (ush*)  alloc((size_t)B_ * F_ * 2);
    ush*   fbh    = (ush*)  alloc((size_t)B_ * R_ * F_ * 2);
    ush*   wfp_h  = (ush*)  alloc((size_t)A_ * F_ * 2);
    ush*   wiH    = (ush*)  alloc((size_t)1024 * F_ * 2);
    ush*   wiL    = (ush*)  alloc((size_t)1024 * F_ * 2);
    ush*   wxh    = (ush*)  alloc((size_t)2048 * E_ * 2);
    ush*   wxl    = (ush*)  alloc((size_t)2048 * E_ * 2);
    ush*   wg2h   = (ush*)  alloc((size_t)2048 * (F_ + H_) * 2);
    ush*   wg2l   = (ush*)  alloc((size_t)2048 * (F_ + H_) * 2);
    ush*   woh    = (ush*)  alloc((size_t)V_ * H_ * 2);
    ush*   wol    = (ush*)  alloc((size_t)V_ * H_ * 2);
    ush*   whpT   = (ush*)  alloc((size_t)H_ * A_ * 2);
    float* egates = (float*)alloc((size_t)B_ * L_ * 2048 * 4);
    float* h0f    = (float*)alloc((size_t)B_ * H_ * 4);
    float* c2     = (float*)alloc((size_t)2 * B_ * H_ * 4);
    ush*   h_hi   = (ush*)  alloc((size_t)B_ * H_ * 2);
    ush*   h_lo   = (ush*)  alloc((size_t)B_ * H_ * 2);
    ush*   hallh  = (ush*)  alloc((size_t)L_ * B_ * H_ * 2);
    ush*   halll  = (ush*)  alloc((size_t)L_ * B_ * H_ * 2);
    ush*   ctx_hi = (ush*)  alloc((size_t)B_ * F_ * 2);
    ush*   ctx_lo = (ush*)  alloc((size_t)B_ * F_ * 2);
    float* alphag = (float*)alloc((size_t)B_ * R_ * 4);
    float* gparts = (float*)alloc((size_t)8 * B_ * 2048 * 4);
    float* initp  = (float*)alloc((size_t)8 * B_ * 1024 * 4);
    int*   bar    = (int*)  alloc((size_t)3 * L_ * 4);

    // reset device barriers (captured as a graph node)
    hipMemsetAsync(bar, 0, (size_t)3 * L_ * 4, stream);

    // ---- one-time prep ----
    prep_feats<<<dim3(4, B_), 256, 0, stream>>>(feats, fbh, mh, ml);
    gather_split<<<768, 256, 0, stream>>>(emb, cap, eh, el);
    split_kernel<<<2048, 256, 0, stream>>>(W_out, woh, wol, V_ * H_ / 4);
    split_kernel<<<512, 256, 0, stream>>>(W_init_h, wiH, wiL, H_ * F_ / 4);
    split_kernel<<<512, 256, 0, stream>>>(W_init_c, wiH + (size_t)512 * F_,
                                          wiL + (size_t)512 * F_, H_ * F_ / 4);
    split_kernel<<<512, 256, 0, stream>>>(W_featp, wfp_h, nullptr, A_ * F_ / 4);
    prep_wih<<<2048, 256, 0, stream>>>(W_ih, W_hh, wxh, wxl, wg2h, wg2l);
    transpose512<<<1024, 256, 0, stream>>>(W_hidp, whpT);

    // h0/c0 init: M=64, N=1024 (stacked), K=2048, split-K=8
    gemm_gates<<<dim3(16, 1, 8), 256, 0, stream>>>(
        mh, ml, F_, F_,
        mh, ml, F_,
        wiH, wiL, F_,
        initp, 1024, (long)B_ * 1024, F_ / 8);
    init_reduce<<<256, 256, 0, stream>>>(initp, b_init_h, b_init_c, h0f, c2, h_hi, h_lo);

    // feat_proj (SPLIT=1, bf16 out, NF=1): 64x64 tiles -> grid(196,8)=1568
    gemm_big<1, 1, true, 1><<<dim3(196, 8), 256, 0, stream>>>(
        fbh, nullptr, F_, wfp_h, nullptr, F_, b_featp, fpb, A_, A_, F_);

    // emb gate part for ALL steps (SPLIT=3, NF=2): grid(24,16)=384
    gemm_big<3, 0, false, 2><<<dim3(24, 16), 256, 0, stream>>>(
        eh, el, E_, wxh, wxl, E_, nullptr, egates, 2048, 2048, E_);

    // ---- persistent fused decode loop: ONE kernel for all 24 steps ----
    loop_kernel<<<NBLK, 512, 0, stream>>>(
        gparts, egates, b_ih, b_hh, c2, h0f, h_hi, h_lo, hallh, halll,
        whpT, b_hidp, fpb, W_score, b_score, fbh, ctx_hi, ctx_lo,
        alphag, alph_out, wg2h, wg2l, bar);

    // predictions for ALL steps (SPLIT=3): M=1536 -> 12 tiles of 128, N=12000
    gemm_big128<3, 2, false><<<dim3(12, 47), 512, 0, stream>>>(
        hallh, halll, H_, woh, wol, H_, b_out, pred, 0, V_, H_);
}

// Round 12
// 3405.429 us; speedup vs baseline: 1.0009x; 1.0009x over previous
//
#include <hip/hip_runtime.h>

#define B_ 64
#define R_ 196
#define F_ 2048
#define E_ 512
#define H_ 512
#define A_ 512
#define V_ 12000
#define L_ 24
#define NBLK 256

typedef __attribute__((ext_vector_type(8))) short bf16x8;
typedef __attribute__((ext_vector_type(4))) float f32x4;
typedef unsigned short ush;

__device__ __forceinline__ float fast_tanh(float x) {
    float t = __expf(2.f * x);
    return 1.f - 2.f / (t + 1.f);
}
__device__ __forceinline__ float fast_sig(float x) {
    return 1.f / (1.f + __expf(-x));
}
__device__ __forceinline__ ush f2bf(float x) {
    unsigned int u = __float_as_uint(x);
    return (ush)((u + 0x7fffu + ((u >> 16) & 1u)) >> 16);
}
__device__ __forceinline__ float bf2f(ush b) {
    return __uint_as_float(((unsigned int)b) << 16);
}

#define LROW 40   // LDS row stride (32 k-elems + 8 pad)

// device-scope barrier. Arrival: one atomicAdd per block (pipelined RMW).
// Polling: COHERENT LOAD (not RMW!) -- broadcast, no serialization. The
// r11 version polled with atomicAdd(bar,0); 256 serialized RMWs per round
// cost ~43us/barrier. Scoped atomic load fixes that.
__device__ __forceinline__ void gbar(int* bar, int idx) {
    __syncthreads();
    if (threadIdx.x == 0) {
        __threadfence();                       // release
        atomicAdd(bar + idx, 1);
        while (__hip_atomic_load(bar + idx, __ATOMIC_RELAXED,
                                 __HIP_MEMORY_SCOPE_AGENT) < NBLK)
            __builtin_amdgcn_s_sleep(4);
        __threadfence();                       // acquire
    }
    __syncthreads();
}

// LSTM cell for (b, n=tid), step t (t=0 -> load h0). Single writer per b.
__device__ __forceinline__ float cell_compute(
    const float* __restrict__ gparts, const float* __restrict__ egates,
    const float* __restrict__ b_ih, const float* __restrict__ b_hh,
    float* __restrict__ c2, const float* __restrict__ h0f,
    ush* __restrict__ h_hi, ush* __restrict__ h_lo,
    ush* __restrict__ hallh, ush* __restrict__ halll,
    int b, int n, int t)
{
    float hh;
    if (t > 0) {
        const float* c_old = c2 + (size_t)((t - 1) & 1) * B_ * H_;
        float* c_new = c2 + (size_t)(t & 1) * B_ * H_;
        const float* eg = egates + ((size_t)b * L_ + (t - 1)) * 2048;
        float gi = b_ih[n] + b_hh[n] + eg[n];
        float gf = b_ih[n + 512] + b_hh[n + 512] + eg[n + 512];
        float gg = b_ih[n + 1024] + b_hh[n + 1024] + eg[n + 1024];
        float go = b_ih[n + 1536] + b_hh[n + 1536] + eg[n + 1536];
        #pragma unroll
        for (int z = 0; z < 8; ++z) {
            const float* gz = gparts + (size_t)z * B_ * 2048 + (size_t)b * 2048;
            gi += gz[n]; gf += gz[n + 512]; gg += gz[n + 1024]; go += gz[n + 1536];
        }
        const float cc = fast_sig(gf) * c_old[b * H_ + n] + fast_sig(gi) * fast_tanh(gg);
        hh = fast_sig(go) * fast_tanh(cc);
        c_new[b * H_ + n] = cc;
        const ush hi = f2bf(hh);
        const ush lo = f2bf(hh - bf2f(hi));
        h_hi[b * H_ + n] = hi;
        h_lo[b * H_ + n] = lo;
        const size_t hidx = ((size_t)(t - 1) * B_ + b) * H_ + n;
        hallh[hidx] = hi;
        halll[hidx] = lo;
    } else {
        hh = h0f[b * H_ + n];
    }
    return hh;
}

// ---------------------------------------------------------------------------
// Persistent loop kernel: 256 blocks x 512 threads, all 24 steps.
// Per step: P1 (64 blocks): cell + hid_proj + scores + softmax -> alpha.
//           P2 (256): ctx quarter per (b, fs).  P3 (256): gates tile -> gparts.
// 3 device barriers per step.
// ---------------------------------------------------------------------------
__global__ __launch_bounds__(512) void loop_kernel(
    float* __restrict__ gparts, const float* __restrict__ egates,
    const float* __restrict__ b_ih, const float* __restrict__ b_hh,
    float* __restrict__ c2, const float* __restrict__ h0f,
    ush* __restrict__ h_hi, ush* __restrict__ h_lo,
    ush* __restrict__ hallh, ush* __restrict__ halll,
    const ush* __restrict__ whpT, const float* __restrict__ b_hidp,
    const ush* __restrict__ fpb, const float* __restrict__ W_score,
    const float* __restrict__ b_score, const ush* __restrict__ fbh,
    ush* __restrict__ ctx_hi, ush* __restrict__ ctx_lo,
    float* __restrict__ alpha_glob, float* __restrict__ alph_out,
    const ush* __restrict__ wg2h, const ush* __restrict__ wg2l,
    int* bar)
{
    __shared__ __align__(16) char smem[20480];
    const int bid = blockIdx.x, tid = threadIdx.x;
    const int lane = tid & 63, w = tid >> 6;

    for (int t = 0; t < L_; ++t) {
        // ---- P1: cell + attention scores + softmax (blocks 0..63) ----
        if (bid < B_) {
            float* sh_h  = (float*)smem;
            float* sh_hp = (float*)(smem + 2048);
            float* sh_ws = (float*)(smem + 4096);
            float* sh_sc = (float*)(smem + 6144);
            float* red   = (float*)(smem + 7168);
            const int b = bid;
            const float hh = cell_compute(gparts, egates, b_ih, b_hh, c2, h0f,
                                          h_hi, h_lo, hallh, halll, b, tid, t);
            sh_h[tid] = hh;
            sh_ws[tid] = W_score[tid];
            __syncthreads();

            {   // hid_proj: thread tid computes hp[tid] (coalesced bf16 whpT)
                float a0 = 0.f, a1 = 0.f, a2 = 0.f, a3 = 0.f;
                #pragma unroll 4
                for (int k = 0; k < H_; k += 4) {
                    a0 = fmaf(sh_h[k + 0], bf2f(whpT[(size_t)(k + 0) * A_ + tid]), a0);
                    a1 = fmaf(sh_h[k + 1], bf2f(whpT[(size_t)(k + 1) * A_ + tid]), a1);
                    a2 = fmaf(sh_h[k + 2], bf2f(whpT[(size_t)(k + 2) * A_ + tid]), a2);
                    a3 = fmaf(sh_h[k + 3], bf2f(whpT[(size_t)(k + 3) * A_ + tid]), a3);
                }
                sh_hp[tid] = (a0 + a1) + (a2 + a3) + b_hidp[tid];
            }
            __syncthreads();

            for (int r = w; r < R_; r += 8) {
                const ushort2* row = reinterpret_cast<const ushort2*>(fpb + ((size_t)b * R_ + r) * A_);
                float acc = 0.f;
                #pragma unroll
                for (int j = 0; j < 4; ++j) {
                    const ushort2 u = row[lane + 64 * j];
                    const int a = 2 * (lane + 64 * j);
                    acc += fast_tanh(bf2f(u.x) + sh_hp[a]) * sh_ws[a];
                    acc += fast_tanh(bf2f(u.y) + sh_hp[a + 1]) * sh_ws[a + 1];
                }
                for (int off = 32; off > 0; off >>= 1) acc += __shfl_down(acc, off);
                if (lane == 0) sh_sc[r] = acc + b_score[0];
            }
            __syncthreads();

            if (tid < 64) {
                float m = -1e30f;
                for (int r = tid; r < R_; r += 64) m = fmaxf(m, sh_sc[r]);
                for (int off = 32; off > 0; off >>= 1) m = fmaxf(m, __shfl_xor(m, off));
                float s = 0.f;
                for (int r = tid; r < R_; r += 64) s += __expf(sh_sc[r] - m);
                for (int off = 32; off > 0; off >>= 1) s += __shfl_xor(s, off);
                if (tid == 0) { red[0] = m; red[1] = 1.f / s; }
            }
            __syncthreads();
            const float m = red[0], is = red[1];
            if (tid < R_) {
                const float av = __expf(sh_sc[tid] - m) * is;
                alpha_glob[b * R_ + tid] = av;
                alph_out[((size_t)b * L_ + t) * R_ + tid] = av;
            }
        }
        gbar(bar, 3 * t);

        // ---- P2: context quarters (all 256 blocks: b=bid>>2, fs=bid&3) ----
        {
            float* sa = (float*)smem;
            const int b = bid >> 2, fs = bid & 3;
            if (tid < R_) sa[tid] = alpha_glob[b * R_ + tid];
            __syncthreads();
            const int f0 = fs * 512 + tid;
            const ush* fp2 = fbh + (size_t)b * R_ * F_ + f0;
            float cx = 0.f;
            #pragma unroll 4
            for (int r = 0; r < R_; ++r)
                cx = fmaf(sa[r], bf2f(fp2[(size_t)r * F_]), cx);
            const size_t ci = (size_t)b * F_ + f0;
            const ush hx = f2bf(cx);
            ctx_hi[ci] = hx;
            ctx_lo[ci] = f2bf(cx - bf2f(hx));
        }
        gbar(bar, 3 * t + 1);

        // ---- P3: gates tile (all 256 blocks: nt=bid&31, z=bid>>5) ----
        {
            ush* sAh = (ush*)smem;
            ush* sBh = (ush*)(smem + 5120);
            ush* sAl = (ush*)(smem + 10240);
            ush* sBl = (ush*)(smem + 15360);
            const int nt = bid & 31, z = bid >> 5;
            const int ntile = nt * 64;
            const int nw = w & 3, mbase = (w >> 2) * 2;
            const int fr = lane & 15, kg = (lane >> 4) * 8;
            const int lrow = tid >> 2, lcol = (tid & 3) * 8;
            f32x4 acc0 = {0.f, 0.f, 0.f, 0.f};
            f32x4 acc1 = {0.f, 0.f, 0.f, 0.f};

            for (int kb = z * 320; kb < z * 320 + 320; kb += 32) {
                uint4 a_h, a_l, b_h4, b_l4;
                if (tid < 256) {
                    const ush *ph, *pl; int lda, loc;
                    if (kb < F_) { ph = ctx_hi; pl = ctx_lo; lda = F_; loc = kb; }
                    else         { ph = h_hi;   pl = h_lo;   lda = H_; loc = kb - F_; }
                    a_h  = *(const uint4*)(ph + (size_t)lrow * lda + loc + lcol);
                    a_l  = *(const uint4*)(pl + (size_t)lrow * lda + loc + lcol);
                    b_h4 = *(const uint4*)(wg2h + (size_t)(ntile + lrow) * (F_ + H_) + kb + lcol);
                    b_l4 = *(const uint4*)(wg2l + (size_t)(ntile + lrow) * (F_ + H_) + kb + lcol);
                }
                __syncthreads();
                if (tid < 256) {
                    *(uint4*)(sAh + lrow * LROW + lcol) = a_h;
                    *(uint4*)(sBh + lrow * LROW + lcol) = b_h4;
                    *(uint4*)(sAl + lrow * LROW + lcol) = a_l;
                    *(uint4*)(sBl + lrow * LROW + lcol) = b_l4;
                }
                __syncthreads();

                const bf16x8 bh = *(const bf16x8*)(sBh + (16 * nw + fr) * LROW + kg);
                const bf16x8 bl = *(const bf16x8*)(sBl + (16 * nw + fr) * LROW + kg);
                {
                    const bf16x8 ah = *(const bf16x8*)(sAh + (16 * mbase + fr) * LROW + kg);
                    const bf16x8 al = *(const bf16x8*)(sAl + (16 * mbase + fr) * LROW + kg);
                    acc0 = __builtin_amdgcn_mfma_f32_16x16x32_bf16(ah, bh, acc0, 0, 0, 0);
                    acc0 = __builtin_amdgcn_mfma_f32_16x16x32_bf16(ah, bl, acc0, 0, 0, 0);
                    acc0 = __builtin_amdgcn_mfma_f32_16x16x32_bf16(al, bh, acc0, 0, 0, 0);
                }
                {
                    const bf16x8 ah = *(const bf16x8*)(sAh + (16 * (mbase + 1) + fr) * LROW + kg);
                    const bf16x8 al = *(const bf16x8*)(sAl + (16 * (mbase + 1) + fr) * LROW + kg);
                    acc1 = __builtin_amdgcn_mfma_f32_16x16x32_bf16(ah, bh, acc1, 0, 0, 0);
                    acc1 = __builtin_amdgcn_mfma_f32_16x16x32_bf16(ah, bl, acc1, 0, 0, 0);
                    acc1 = __builtin_amdgcn_mfma_f32_16x16x32_bf16(al, bh, acc1, 0, 0, 0);
                }
            }

            float* Cz = gparts + (size_t)z * B_ * 2048;
            const int n = ntile + 16 * nw + fr;
            #pragma unroll
            for (int rr = 0; rr < 4; ++rr) {
                Cz[(size_t)(16 * mbase + (lane >> 4) * 4 + rr) * 2048 + n] = acc0[rr];
                Cz[(size_t)(16 * (mbase + 1) + (lane >> 4) * 4 + rr) * 2048 + n] = acc1[rr];
            }
        }
        gbar(bar, 3 * t + 2);
    }

    // ---- final cell: h_L -> hall[L-1] ----
    if (bid < B_) {
        cell_compute(gparts, egates, b_ih, b_hh, c2, h0f,
                     h_hi, h_lo, hallh, halll, bid, tid, L_);
    }
}

// ---------------------------------------------------------------------------
// gemm_big128: pred GEMM (128x256 tile, 512 thr). CMAP=2: pred layout, NT.
// ---------------------------------------------------------------------------
template<int SPLIT, int CMAP, bool NFAST>
__global__ __launch_bounds__(512) void gemm_big128(
    const ush* __restrict__ Ah, const ush* __restrict__ Al, int lda,
    const ush* __restrict__ Wh, const ush* __restrict__ Wl, int ldw,
    const float* __restrict__ bias, void* __restrict__ Cv,
    int ldc, int N, int K)
{
    constexpr int SMEM_BYTES = (SPLIT == 3) ? 61440 : 30720;
    __shared__ __align__(16) char smem[SMEM_BYTES];
    ush* sAh = (ush*)smem;
    ush* sBh = (ush*)(smem + 10240);
    ush* sAl = (ush*)(smem + 30720);
    ush* sBl = (ush*)(smem + 40960);

    const int tid = threadIdx.x;
    const int lane = tid & 63, w = tid >> 6;
    const int mw = w >> 2, nw = w & 3;

    const int nbx = gridDim.x, nby = gridDim.y;
    const int nwg = nbx * nby;
    const int orig = blockIdx.x + nbx * blockIdx.y;
    const int q = nwg >> 3, r = nwg & 7;
    const int xcd = orig & 7, idx = orig >> 3;
    const int lin = (xcd < r ? xcd * (q + 1) : r * (q + 1) + (xcd - r) * q) + idx;
    int bx, by;
    if constexpr (NFAST) { by = lin % nby; bx = lin / nby; }
    else                 { bx = lin % nbx; by = lin / nbx; }
    const int mtile = bx * 128;
    const int ntile = by * 256;

    const int fr = lane & 15, kg = (lane >> 4) * 8;
    const int arow = tid >> 2, aq = (tid & 3) * 8;

    f32x4 acc[4][4];
    #pragma unroll
    for (int mf = 0; mf < 4; ++mf)
        #pragma unroll
        for (int nf = 0; nf < 4; ++nf) acc[mf][nf] = {0.f, 0.f, 0.f, 0.f};

    const uint4 zv = make_uint4(0u, 0u, 0u, 0u);

    for (int kb = 0; kb < K; kb += 32) {
        uint4 a_h = *(const uint4*)(Ah + (size_t)(mtile + arow) * lda + kb + aq);
        uint4 a_l;
        uint4 b_h[2], b_l[2];
        #pragma unroll
        for (int p = 0; p < 2; ++p) {
            const int row = ntile + arow + 128 * p;
            b_h[p] = (row < N) ? *(const uint4*)(Wh + (size_t)row * ldw + kb + aq) : zv;
        }
        if constexpr (SPLIT == 3) {
            a_l = *(const uint4*)(Al + (size_t)(mtile + arow) * lda + kb + aq);
            #pragma unroll
            for (int p = 0; p < 2; ++p) {
                const int row = ntile + arow + 128 * p;
                b_l[p] = (row < N) ? *(const uint4*)(Wl + (size_t)row * ldw + kb + aq) : zv;
            }
        }

        __syncthreads();
        *(uint4*)(sAh + arow * LROW + aq) = a_h;
        #pragma unroll
        for (int p = 0; p < 2; ++p)
            *(uint4*)(sBh + (arow + 128 * p) * LROW + aq) = b_h[p];
        if constexpr (SPLIT == 3) {
            *(uint4*)(sAl + arow * LROW + aq) = a_l;
            #pragma unroll
            for (int p = 0; p < 2; ++p)
                *(uint4*)(sBl + (arow + 128 * p) * LROW + aq) = b_l[p];
        }
        __syncthreads();

        bf16x8 bh[4], bl[4];
        #pragma unroll
        for (int nf = 0; nf < 4; ++nf) {
            bh[nf] = *(const bf16x8*)(sBh + (nw * 64 + nf * 16 + fr) * LROW + kg);
            if constexpr (SPLIT == 3)
                bl[nf] = *(const bf16x8*)(sBl + (nw * 64 + nf * 16 + fr) * LROW + kg);
        }
        #pragma unroll
        for (int mf = 0; mf < 4; ++mf) {
            const bf16x8 ah = *(const bf16x8*)(sAh + (mw * 64 + mf * 16 + fr) * LROW + kg);
            if constexpr (SPLIT == 3) {
                const bf16x8 al = *(const bf16x8*)(sAl + (mw * 64 + mf * 16 + fr) * LROW + kg);
                #pragma unroll
                for (int nf = 0; nf < 4; ++nf) {
                    acc[mf][nf] = __builtin_amdgcn_mfma_f32_16x16x32_bf16(ah, bh[nf], acc[mf][nf], 0, 0, 0);
                    acc[mf][nf] = __builtin_amdgcn_mfma_f32_16x16x32_bf16(ah, bl[nf], acc[mf][nf], 0, 0, 0);
                    acc[mf][nf] = __builtin_amdgcn_mfma_f32_16x16x32_bf16(al, bh[nf], acc[mf][nf], 0, 0, 0);
                }
            } else {
                #pragma unroll
                for (int nf = 0; nf < 4; ++nf)
                    acc[mf][nf] = __builtin_amdgcn_mfma_f32_16x16x32_bf16(ah, bh[nf], acc[mf][nf], 0, 0, 0);
            }
        }
    }

    #pragma unroll
    for (int nf = 0; nf < 4; ++nf) {
        const int nn = ntile + nw * 64 + nf * 16 + fr;
        if (nn < N) {
            const float bv = bias ? bias[nn] : 0.f;
            #pragma unroll
            for (int mf = 0; mf < 4; ++mf) {
                #pragma unroll
                for (int rr = 0; rr < 4; ++rr) {
                    const int m = mtile + mw * 64 + mf * 16 + (lane >> 4) * 4 + rr;
                    const float v = acc[mf][nf][rr] + bv;
                    if constexpr (CMAP == 1)
                        ((ush*)Cv)[(size_t)m * ldc + nn] = f2bf(v);
                    else if constexpr (CMAP == 2) {
                        float* dst = (float*)Cv + (size_t)(m & 63) * (L_ * V_)
                                   + (size_t)(m >> 6) * V_ + nn;
                        __builtin_nontemporal_store(v, dst);
                    } else
                        ((float*)Cv)[(size_t)m * ldc + nn] = v;
                }
            }
        }
    }
}

// ---------------------------------------------------------------------------
// gemm_big: 64M x (64*NF)N tile, 256 threads. NF=1 for feat_proj.
// ---------------------------------------------------------------------------
template<int SPLIT, int CMAP, bool NFAST, int NF>
__global__ __launch_bounds__(256) void gemm_big(
    const ush* __restrict__ Ah, const ush* __restrict__ Al, int lda,
    const ush* __restrict__ Wh, const ush* __restrict__ Wl, int ldw,
    const float* __restrict__ bias, void* __restrict__ Cv,
    int ldc, int N, int K)
{
    constexpr int ABYTES = 64 * LROW * 2;
    constexpr int BBYTES = 64 * NF * LROW * 2;
    constexpr int SMEM_BYTES = (SPLIT == 3) ? 2 * (ABYTES + BBYTES) : (ABYTES + BBYTES);
    __shared__ __align__(16) char smem[SMEM_BYTES];
    ush* sAh = (ush*)smem;
    ush* sBh = (ush*)(smem + ABYTES);
    ush* sAl = (ush*)(smem + ABYTES + BBYTES);
    ush* sBl = (ush*)(smem + 2 * ABYTES + BBYTES);

    const int tid = threadIdx.x;
    const int lane = tid & 63, w = tid >> 6;

    const int nbx = gridDim.x, nby = gridDim.y;
    const int nwg = nbx * nby;
    int lin = blockIdx.x + nbx * blockIdx.y;
    if ((nwg & 7) == 0) {
        const int q = nwg >> 3;
        lin = (lin & 7) * q + (lin >> 3);
    }
    int bx, by;
    if constexpr (NFAST) { by = lin % nby; bx = lin / nby; }
    else                 { bx = lin % nbx; by = lin / nbx; }
    const int mtile = bx * 64;
    const int ntile = by * (64 * NF);

    const int fr = lane & 15, kg = (lane >> 4) * 8;
    const int arow = tid >> 2, aq = (tid & 3) * 8;

    f32x4 acc[4][NF];
    #pragma unroll
    for (int mf = 0; mf < 4; ++mf)
        #pragma unroll
        for (int nf = 0; nf < NF; ++nf) acc[mf][nf] = {0.f, 0.f, 0.f, 0.f};

    const uint4 zv = make_uint4(0u, 0u, 0u, 0u);

    for (int kb = 0; kb < K; kb += 32) {
        uint4 a_h = *(const uint4*)(Ah + (size_t)(mtile + arow) * lda + kb + aq);
        uint4 a_l;
        uint4 b_h[NF], b_l[NF];
        #pragma unroll
        for (int p = 0; p < NF; ++p) {
            const int row = ntile + arow + 64 * p;
            b_h[p] = (row < N) ? *(const uint4*)(Wh + (size_t)row * ldw + kb + aq) : zv;
        }
        if constexpr (SPLIT == 3) {
            a_l = *(const uint4*)(Al + (size_t)(mtile + arow) * lda + kb + aq);
            #pragma unroll
            for (int p = 0; p < NF; ++p) {
                const int row = ntile + arow + 64 * p;
                b_l[p] = (row < N) ? *(const uint4*)(Wl + (size_t)row * ldw + kb + aq) : zv;
            }
        }

        __syncthreads();
        *(uint4*)(sAh + arow * LROW + aq) = a_h;
        #pragma unroll
        for (int p = 0; p < NF; ++p)
            *(uint4*)(sBh + (arow + 64 * p) * LROW + aq) = b_h[p];
        if constexpr (SPLIT == 3) {
            *(uint4*)(sAl + arow * LROW + aq) = a_l;
            #pragma unroll
            for (int p = 0; p < NF; ++p)
                *(uint4*)(sBl + (arow + 64 * p) * LROW + aq) = b_l[p];
        }
        __syncthreads();

        bf16x8 bh[NF], bl[NF];
        #pragma unroll
        for (int nf = 0; nf < NF; ++nf) {
            bh[nf] = *(const bf16x8*)(sBh + (w * (16 * NF) + nf * 16 + fr) * LROW + kg);
            if constexpr (SPLIT == 3)
                bl[nf] = *(const bf16x8*)(sBl + (w * (16 * NF) + nf * 16 + fr) * LROW + kg);
        }
        #pragma unroll
        for (int mf = 0; mf < 4; ++mf) {
            const bf16x8 ah = *(const bf16x8*)(sAh + (mf * 16 + fr) * LROW + kg);
            if constexpr (SPLIT == 3) {
                const bf16x8 al = *(const bf16x8*)(sAl + (mf * 16 + fr) * LROW + kg);
                #pragma unroll
                for (int nf = 0; nf < NF; ++nf) {
                    acc[mf][nf] = __builtin_amdgcn_mfma_f32_16x16x32_bf16(ah, bh[nf], acc[mf][nf], 0, 0, 0);
                    acc[mf][nf] = __builtin_amdgcn_mfma_f32_16x16x32_bf16(ah, bl[nf], acc[mf][nf], 0, 0, 0);
                    acc[mf][nf] = __builtin_amdgcn_mfma_f32_16x16x32_bf16(al, bh[nf], acc[mf][nf], 0, 0, 0);
                }
            } else {
                #pragma unroll
                for (int nf = 0; nf < NF; ++nf)
                    acc[mf][nf] = __builtin_amdgcn_mfma_f32_16x16x32_bf16(ah, bh[nf], acc[mf][nf], 0, 0, 0);
            }
        }
    }

    #pragma unroll
    for (int nf = 0; nf < NF; ++nf) {
        const int nn = ntile + w * (16 * NF) + nf * 16 + fr;
        if (nn < N) {
            const float bv = bias ? bias[nn] : 0.f;
            #pragma unroll
            for (int mf = 0; mf < 4; ++mf) {
                #pragma unroll
                for (int rr = 0; rr < 4; ++rr) {
                    const int m = mtile + mf * 16 + (lane >> 4) * 4 + rr;
                    const float v = acc[mf][nf][rr] + bv;
                    if constexpr (CMAP == 1)
                        ((ush*)Cv)[(size_t)m * ldc + nn] = f2bf(v);
                    else
                        ((float*)Cv)[(size_t)m * ldc + nn] = v;
                }
            }
        }
    }
}

// ---------------------------------------------------------------------------
// gemm_gates: 64x64 tile, 256 threads, segmented A, split-K (init GEMM only).
// ---------------------------------------------------------------------------
__global__ __launch_bounds__(256) void gemm_gates(
    const ush* __restrict__ Ah0, const ush* __restrict__ Al0, int lda0, int k0,
    const ush* __restrict__ Ah1, const ush* __restrict__ Al1, int lda1,
    const ush* __restrict__ Wh, const ush* __restrict__ Wl, int ldw,
    float* __restrict__ C, int ldc, long zstride, int kChunk)
{
    __shared__ ush sAh[64 * LROW];
    __shared__ ush sBh[64 * LROW];
    __shared__ ush sAl[64 * LROW];
    __shared__ ush sBl[64 * LROW];

    const int tid = threadIdx.x;
    const int ntile = blockIdx.x * 64;
    const int kStart = blockIdx.z * kChunk;
    const int lane = tid & 63, w = tid >> 6;
    const int lrow = tid >> 2;
    const int lcol = (tid & 3) * 8;
    const int nrow = ntile + lrow;

    f32x4 acc[4];
    #pragma unroll
    for (int f = 0; f < 4; ++f) acc[f] = {0.f, 0.f, 0.f, 0.f};

    const int fr = lane & 15;
    const int kg = (lane >> 4) * 8;

    for (int kb = kStart; kb < kStart + kChunk; kb += 32) {
        const ush *ph, *pl; int lda, loc;
        if (kb < k0) { ph = Ah0; pl = Al0; lda = lda0; loc = kb; }
        else         { ph = Ah1; pl = Al1; lda = lda1; loc = kb - k0; }

        uint4 a_h = *(const uint4*)(ph + (size_t)lrow * lda + loc + lcol);
        uint4 b_h = *(const uint4*)(Wh + (size_t)nrow * ldw + kb + lcol);
        uint4 a_l = *(const uint4*)(pl + (size_t)lrow * lda + loc + lcol);
        uint4 b_l = *(const uint4*)(Wl + (size_t)nrow * ldw + kb + lcol);

        __syncthreads();
        *(uint4*)(sAh + lrow * LROW + lcol) = a_h;
        *(uint4*)(sBh + lrow * LROW + lcol) = b_h;
        *(uint4*)(sAl + lrow * LROW + lcol) = a_l;
        *(uint4*)(sBl + lrow * LROW + lcol) = b_l;
        __syncthreads();

        const bf16x8 bh = *(const bf16x8*)(sBh + (16 * w + fr) * LROW + kg);
        const bf16x8 bl = *(const bf16x8*)(sBl + (16 * w + fr) * LROW + kg);

        #pragma unroll
        for (int f = 0; f < 4; ++f) {
            const bf16x8 ah = *(const bf16x8*)(sAh + (16 * f + fr) * LROW + kg);
            const bf16x8 al = *(const bf16x8*)(sAl + (16 * f + fr) * LROW + kg);
            acc[f] = __builtin_amdgcn_mfma_f32_16x16x32_bf16(ah, bh, acc[f], 0, 0, 0);
            acc[f] = __builtin_amdgcn_mfma_f32_16x16x32_bf16(ah, bl, acc[f], 0, 0, 0);
            acc[f] = __builtin_amdgcn_mfma_f32_16x16x32_bf16(al, bh, acc[f], 0, 0, 0);
        }
    }

    const int n = ntile + 16 * w + (lane & 15);
    float* Cz = C + (size_t)blockIdx.z * zstride;
    #pragma unroll
    for (int f = 0; f < 4; ++f)
        #pragma unroll
        for (int rr = 0; rr < 4; ++rr) {
            const int m = 16 * f + (lane >> 4) * 4 + rr;
            Cz[(size_t)m * ldc + n] = acc[f][rr];
        }
}

// fused feats pass: fbh (bf16) + per-(b,f) mean -> mh/ml. block (fs, b).
__global__ __launch_bounds__(256) void prep_feats(
    const float* __restrict__ feats, ush* __restrict__ fbh,
    ush* __restrict__ mh, ush* __restrict__ ml)
{
    const int fs = blockIdx.x;
    const int b  = blockIdx.y;
    const int f = fs * 512 + threadIdx.x * 2;
    const float2* fp = (const float2*)(feats + (size_t)b * R_ * F_ + f);
    ush* fo = fbh + (size_t)b * R_ * F_ + f;
    float sx = 0.f, sy = 0.f;
    for (int r = 0; r < R_; ++r) {
        const float2 v = fp[(size_t)r * (F_ / 2)];
        sx += v.x; sy += v.y;
        ushort2 u; u.x = f2bf(v.x); u.y = f2bf(v.y);
        *(ushort2*)(fo + (size_t)r * F_) = u;
    }
    const float s = 1.f / (float)R_;
    sx *= s; sy *= s;
    const size_t mi = (size_t)b * F_ + f;
    const ush hx = f2bf(sx); mh[mi] = hx;     ml[mi] = f2bf(sx - bf2f(hx));
    const ush hy = f2bf(sy); mh[mi + 1] = hy; ml[mi + 1] = f2bf(sy - bf2f(hy));
}

// gather embeddings -> bf16 hi/lo (B,L,E)
__global__ __launch_bounds__(256) void gather_split(
    const float* __restrict__ emb, const int* __restrict__ cap,
    ush* __restrict__ eh, ush* __restrict__ el)
{
    const int idx = blockIdx.x * 256 + threadIdx.x;
    const int bt = idx >> 7, j = idx & 127;
    const int tok = cap[bt];
    const float4 v = reinterpret_cast<const float4*>(emb)[(size_t)tok * (E_ / 4) + j];
    const float a[4] = {v.x, v.y, v.z, v.w};
    #pragma unroll
    for (int c = 0; c < 4; ++c) {
        const ush hi = f2bf(a[c]);
        eh[idx * 4 + c] = hi;
        el[idx * 4 + c] = f2bf(a[c] - bf2f(hi));
    }
}

// generic fp32 -> bf16 (hi, optional lo)
__global__ __launch_bounds__(256) void split_kernel(
    const float* __restrict__ in, ush* __restrict__ hi, ush* __restrict__ lo, int n4)
{
    for (int i = blockIdx.x * 256 + threadIdx.x; i < n4; i += gridDim.x * 256) {
        const float4 v = reinterpret_cast<const float4*>(in)[i];
        const float a[4] = {v.x, v.y, v.z, v.w};
        #pragma unroll
        for (int c = 0; c < 4; ++c) {
            const ush h = f2bf(a[c]);
            hi[i * 4 + c] = h;
            if (lo) lo[i * 4 + c] = f2bf(a[c] - bf2f(h));
        }
    }
}

// W_ih columns [0:E) -> wx (2048x512); [E:) ++ W_hh -> wg2 (2048x2560); hi/lo
__global__ __launch_bounds__(256) void prep_wih(
    const float* __restrict__ W_ih, const float* __restrict__ W_hh,
    ush* __restrict__ wxh, ush* __restrict__ wxl,
    ush* __restrict__ wg2h, ush* __restrict__ wg2l)
{
    const int nrow = blockIdx.x;
    for (int k = threadIdx.x; k < E_; k += 256) {
        const float v = W_ih[(size_t)nrow * (E_ + F_) + k];
        const ush h = f2bf(v);
        wxh[(size_t)nrow * E_ + k] = h;
        wxl[(size_t)nrow * E_ + k] = f2bf(v - bf2f(h));
    }
    for (int k = threadIdx.x; k < F_ + H_; k += 256) {
        const float v = (k < F_) ? W_ih[(size_t)nrow * (E_ + F_) + E_ + k]
                                 : W_hh[(size_t)nrow * H_ + (k - F_)];
        const ush h = f2bf(v);
        wg2h[(size_t)nrow * (F_ + H_) + k] = h;
        wg2l[(size_t)nrow * (F_ + H_) + k] = f2bf(v - bf2f(h));
    }
}

// transpose W_hidp (A x H) -> whpT (H x A), bf16
__global__ __launch_bounds__(256) void transpose512(
    const float* __restrict__ in, ush* __restrict__ out)
{
    const int idx = blockIdx.x * 256 + threadIdx.x;
    const int k = idx >> 9, a = idx & 511;
    out[idx] = f2bf(in[(size_t)a * 512 + k]);
}

// reduce init GEMM partials: n<512 -> h0 (+split), n>=512 -> c0 (buffer 0)
__global__ __launch_bounds__(256) void init_reduce(
    const float* __restrict__ initp, const float* __restrict__ b_init_h,
    const float* __restrict__ b_init_c, float* __restrict__ h0f,
    float* __restrict__ c0, ush* __restrict__ h_hi, ush* __restrict__ h_lo)
{
    const int idx = blockIdx.x * 256 + threadIdx.x;
    const int b = idx >> 10, n = idx & 1023;
    float s = 0.f;
    #pragma unroll
    for (int z = 0; z < 8; ++z)
        s += initp[(size_t)z * (B_ * 1024) + (size_t)b * 1024 + n];
    if (n < 512) {
        s += b_init_h[n];
        h0f[b * H_ + n] = s;
        const ush hi = f2bf(s);
        h_hi[b * H_ + n] = hi;
        h_lo[b * H_ + n] = f2bf(s - bf2f(hi));
    } else {
        s += b_init_c[n - 512];
        c0[b * H_ + (n - 512)] = s;
    }
}

extern "C" void kernel_launch(void* const* d_in, const int* in_sizes, int n_in,
                              void* d_out, int out_size, void* d_ws, size_t ws_size,
                              hipStream_t stream)
{
    const float* feats    = (const float*)d_in[0];
    const int*   cap      = (const int*)  d_in[1];
    const float* emb      = (const float*)d_in[2];
    const float* W_init_h = (const float*)d_in[3];
    const float* b_init_h = (const float*)d_in[4];
    const float* W_init_c = (const float*)d_in[5];
    const float* b_init_c = (const float*)d_in[6];
    const float* W_ih     = (const float*)d_in[7];
    const float* b_ih     = (const float*)d_in[8];
    const float* W_hh     = (const float*)d_in[9];
    const float* b_hh     = (const float*)d_in[10];
    const float* W_featp  = (const float*)d_in[11];
    const float* b_featp  = (const float*)d_in[12];
    const float* W_hidp   = (const float*)d_in[13];
    const float* b_hidp   = (const float*)d_in[14];
    const float* W_score  = (const float*)d_in[15];
    const float* b_score  = (const float*)d_in[16];
    const float* W_out    = (const float*)d_in[17];
    const float* b_out    = (const float*)d_in[18];

    float* pred     = (float*)d_out;                          // (B,L,V)
    float* alph_out = pred + (size_t)B_ * L_ * V_;            // (B,L,R)

    char* p = (char*)d_ws;
    auto alloc = [&](size_t bytes) { char* q = p; p += (bytes + 255) & ~(size_t)255; return q; };

    ush*   fpb    = (ush*)  alloc((size_t)B_ * R_ * A_ * 2);
    ush*   eh     = (ush*)  alloc((size_t)B_ * L_ * E_ * 2);
    ush*   el     = (ush*)  alloc((size_t)B_ * L_ * E_ * 2);
    ush*   mh     = (ush*)  alloc((size_t)B_ * F_ * 2);
    ush*   ml     = (ush*)  alloc((size_t)B_ * F_ * 2);
    ush*   fbh    = (ush*)  alloc((size_t)B_ * R_ * F_ * 2);
    ush*   wfp_h  = (ush*)  alloc((size_t)A_ * F_ * 2);
    ush*   wiH    = (ush*)  alloc((size_t)1024 * F_ * 2);
    ush*   wiL    = (ush*)  alloc((size_t)1024 * F_ * 2);
    ush*   wxh    = (ush*)  alloc((size_t)2048 * E_ * 2);
    ush*   wxl    = (ush*)  alloc((size_t)2048 * E_ * 2);
    ush*   wg2h   = (ush*)  alloc((size_t)2048 * (F_ + H_) * 2);
    ush*   wg2l   = (ush*)  alloc((size_t)2048 * (F_ + H_) * 2);
    ush*   woh    = (ush*)  alloc((size_t)V_ * H_ * 2);
    ush*   wol    = (ush*)  alloc((size_t)V_ * H_ * 2);
    ush*   whpT   = (ush*)  alloc((size_t)H_ * A_ * 2);
    float* egates = (float*)alloc((size_t)B_ * L_ * 2048 * 4);
    float* h0f    = (float*)alloc((size_t)B_ * H_ * 4);
    float* c2     = (float*)alloc((size_t)2 * B_ * H_ * 4);
    ush*   h_hi   = (ush*)  alloc((size_t)B_ * H_ * 2);
    ush*   h_lo   = (ush*)  alloc((size_t)B_ * H_ * 2);
    ush*   hallh  = (ush*)  alloc((size_t)L_ * B_ * H_ * 2);
    ush*   halll  = (ush*)  alloc((size_t)L_ * B_ * H_ * 2);
    ush*   ctx_hi = (ush*)  alloc((size_t)B_ * F_ * 2);
    ush*   ctx_lo = (ush*)  alloc((size_t)B_ * F_ * 2);
    float* alphag = (float*)alloc((size_t)B_ * R_ * 4);
    float* gparts = (float*)alloc((size_t)8 * B_ * 2048 * 4);
    float* initp  = (float*)alloc((size_t)8 * B_ * 1024 * 4);
    int*   bar    = (int*)  alloc((size_t)3 * L_ * 4);

    // reset device barriers (captured as a graph node)
    hipMemsetAsync(bar, 0, (size_t)3 * L_ * 4, stream);

    // ---- one-time prep ----
    prep_feats<<<dim3(4, B_), 256, 0, stream>>>(feats, fbh, mh, ml);
    gather_split<<<768, 256, 0, stream>>>(emb, cap, eh, el);
    split_kernel<<<2048, 256, 0, stream>>>(W_out, woh, wol, V_ * H_ / 4);
    split_kernel<<<512, 256, 0, stream>>>(W_init_h, wiH, wiL, H_ * F_ / 4);
    split_kernel<<<512, 256, 0, stream>>>(W_init_c, wiH + (size_t)512 * F_,
                                          wiL + (size_t)512 * F_, H_ * F_ / 4);
    split_kernel<<<512, 256, 0, stream>>>(W_featp, wfp_h, nullptr, A_ * F_ / 4);
    prep_wih<<<2048, 256, 0, stream>>>(W_ih, W_hh, wxh, wxl, wg2h, wg2l);
    transpose512<<<1024, 256, 0, stream>>>(W_hidp, whpT);

    // h0/c0 init: M=64, N=1024 (stacked), K=2048, split-K=8
    gemm_gates<<<dim3(16, 1, 8), 256, 0, stream>>>(
        mh, ml, F_, F_,
        mh, ml, F_,
        wiH, wiL, F_,
        initp, 1024, (long)B_ * 1024, F_ / 8);
    init_reduce<<<256, 256, 0, stream>>>(initp, b_init_h, b_init_c, h0f, c2, h_hi, h_lo);

    // feat_proj (SPLIT=1, bf16 out, NF=1): 64x64 tiles -> grid(196,8)=1568
    gemm_big<1, 1, true, 1><<<dim3(196, 8), 256, 0, stream>>>(
        fbh, nullptr, F_, wfp_h, nullptr, F_, b_featp, fpb, A_, A_, F_);

    // emb gate part for ALL steps (SPLIT=3, NF=2): grid(24,16)=384
    gemm_big<3, 0, false, 2><<<dim3(24, 16), 256, 0, stream>>>(
        eh, el, E_, wxh, wxl, E_, nullptr, egates, 2048, 2048, E_);

    // ---- persistent fused decode loop: ONE kernel for all 24 steps ----
    loop_kernel<<<NBLK, 512, 0, stream>>>(
        gparts, egates, b_ih, b_hh, c2, h0f, h_hi, h_lo, hallh, halll,
        whpT, b_hidp, fpb, W_score, b_score, fbh, ctx_hi, ctx_lo,
        alphag, alph_out, wg2h, wg2l, bar);

    // predictions for ALL steps (SPLIT=3): M=1536 -> 12 tiles of 128, N=12000
    gemm_big128<3, 2, false><<<dim3(12, 47), 512, 0, stream>>>(
        hallh, halll, H_, woh, wol, H_, b_out, pred, 0, V_, H_);
}

// Round 13
// 1955.486 us; speedup vs baseline: 1.7430x; 1.7415x over previous
//
#include <hip/hip_runtime.h>

#define B_ 64
#define R_ 196
#define F_ 2048
#define E_ 512
#define H_ 512
#define A_ 512
#define V_ 12000
#define L_ 24

typedef __attribute__((ext_vector_type(8))) short bf16x8;
typedef __attribute__((ext_vector_type(4))) float f32x4;
typedef unsigned short ush;

__device__ __forceinline__ float fast_tanh(float x) {
    float t = __expf(2.f * x);
    return 1.f - 2.f / (t + 1.f);
}
__device__ __forceinline__ float fast_sig(float x) {
    return 1.f / (1.f + __expf(-x));
}
__device__ __forceinline__ ush f2bf(float x) {
    unsigned int u = __float_as_uint(x);
    return (ush)((u + 0x7fffu + ((u >> 16) & 1u)) >> 16);
}
__device__ __forceinline__ float bf2f(ush b) {
    return __uint_as_float(((unsigned int)b) << 16);
}

#define LROW 40   // LDS row stride (32 k-elems + 8 pad)

// ---------------------------------------------------------------------------
// gemm_big128: C = A @ W^T (+bias). Tile 128M x 256N, BK=32, 512 threads.
// Pred GEMM (564 blocks; WRITE-amp fixed by 128-tile). Bijective XCD swizzle.
// SPLIT=3: (hi,lo) bf16x2, 3 MFMAs. CMAP=2: pred layout, fp32 NT stores.
// ---------------------------------------------------------------------------
template<int SPLIT, int CMAP, bool NFAST>
__global__ __launch_bounds__(512) void gemm_big128(
    const ush* __restrict__ Ah, const ush* __restrict__ Al, int lda,
    const ush* __restrict__ Wh, const ush* __restrict__ Wl, int ldw,
    const float* __restrict__ bias, void* __restrict__ Cv,
    int ldc, int N, int K)
{
    constexpr int SMEM_BYTES = (SPLIT == 3) ? 61440 : 30720;
    __shared__ __align__(16) char smem[SMEM_BYTES];
    ush* sAh = (ush*)smem;
    ush* sBh = (ush*)(smem + 10240);
    ush* sAl = (ush*)(smem + 30720);
    ush* sBl = (ush*)(smem + 40960);

    const int tid = threadIdx.x;
    const int lane = tid & 63, w = tid >> 6;
    const int mw = w >> 2, nw = w & 3;

    const int nbx = gridDim.x, nby = gridDim.y;
    const int nwg = nbx * nby;
    const int orig = blockIdx.x + nbx * blockIdx.y;
    const int q = nwg >> 3, r = nwg & 7;
    const int xcd = orig & 7, idx = orig >> 3;
    const int lin = (xcd < r ? xcd * (q + 1) : r * (q + 1) + (xcd - r) * q) + idx;
    int bx, by;
    if constexpr (NFAST) { by = lin % nby; bx = lin / nby; }
    else                 { bx = lin % nbx; by = lin / nbx; }
    const int mtile = bx * 128;
    const int ntile = by * 256;

    const int fr = lane & 15, kg = (lane >> 4) * 8;
    const int arow = tid >> 2, aq = (tid & 3) * 8;

    f32x4 acc[4][4];
    #pragma unroll
    for (int mf = 0; mf < 4; ++mf)
        #pragma unroll
        for (int nf = 0; nf < 4; ++nf) acc[mf][nf] = {0.f, 0.f, 0.f, 0.f};

    const uint4 zv = make_uint4(0u, 0u, 0u, 0u);

    for (int kb = 0; kb < K; kb += 32) {
        uint4 a_h = *(const uint4*)(Ah + (size_t)(mtile + arow) * lda + kb + aq);
        uint4 a_l;
        uint4 b_h[2], b_l[2];
        #pragma unroll
        for (int p = 0; p < 2; ++p) {
            const int row = ntile + arow + 128 * p;
            b_h[p] = (row < N) ? *(const uint4*)(Wh + (size_t)row * ldw + kb + aq) : zv;
        }
        if constexpr (SPLIT == 3) {
            a_l = *(const uint4*)(Al + (size_t)(mtile + arow) * lda + kb + aq);
            #pragma unroll
            for (int p = 0; p < 2; ++p) {
                const int row = ntile + arow + 128 * p;
                b_l[p] = (row < N) ? *(const uint4*)(Wl + (size_t)row * ldw + kb + aq) : zv;
            }
        }

        __syncthreads();
        *(uint4*)(sAh + arow * LROW + aq) = a_h;
        #pragma unroll
        for (int p = 0; p < 2; ++p)
            *(uint4*)(sBh + (arow + 128 * p) * LROW + aq) = b_h[p];
        if constexpr (SPLIT == 3) {
            *(uint4*)(sAl + arow * LROW + aq) = a_l;
            #pragma unroll
            for (int p = 0; p < 2; ++p)
                *(uint4*)(sBl + (arow + 128 * p) * LROW + aq) = b_l[p];
        }
        __syncthreads();

        bf16x8 bh[4], bl[4];
        #pragma unroll
        for (int nf = 0; nf < 4; ++nf) {
            bh[nf] = *(const bf16x8*)(sBh + (nw * 64 + nf * 16 + fr) * LROW + kg);
            if constexpr (SPLIT == 3)
                bl[nf] = *(const bf16x8*)(sBl + (nw * 64 + nf * 16 + fr) * LROW + kg);
        }
        #pragma unroll
        for (int mf = 0; mf < 4; ++mf) {
            const bf16x8 ah = *(const bf16x8*)(sAh + (mw * 64 + mf * 16 + fr) * LROW + kg);
            if constexpr (SPLIT == 3) {
                const bf16x8 al = *(const bf16x8*)(sAl + (mw * 64 + mf * 16 + fr) * LROW + kg);
                #pragma unroll
                for (int nf = 0; nf < 4; ++nf) {
                    acc[mf][nf] = __builtin_amdgcn_mfma_f32_16x16x32_bf16(ah, bh[nf], acc[mf][nf], 0, 0, 0);
                    acc[mf][nf] = __builtin_amdgcn_mfma_f32_16x16x32_bf16(ah, bl[nf], acc[mf][nf], 0, 0, 0);
                    acc[mf][nf] = __builtin_amdgcn_mfma_f32_16x16x32_bf16(al, bh[nf], acc[mf][nf], 0, 0, 0);
                }
            } else {
                #pragma unroll
                for (int nf = 0; nf < 4; ++nf)
                    acc[mf][nf] = __builtin_amdgcn_mfma_f32_16x16x32_bf16(ah, bh[nf], acc[mf][nf], 0, 0, 0);
            }
        }
    }

    #pragma unroll
    for (int nf = 0; nf < 4; ++nf) {
        const int nn = ntile + nw * 64 + nf * 16 + fr;
        if (nn < N) {
            const float bv = bias ? bias[nn] : 0.f;
            #pragma unroll
            for (int mf = 0; mf < 4; ++mf) {
                #pragma unroll
                for (int rr = 0; rr < 4; ++rr) {
                    const int m = mtile + mw * 64 + mf * 16 + (lane >> 4) * 4 + rr;
                    const float v = acc[mf][nf][rr] + bv;
                    if constexpr (CMAP == 1)
                        ((ush*)Cv)[(size_t)m * ldc + nn] = f2bf(v);
                    else if constexpr (CMAP == 2) {
                        float* dst = (float*)Cv + (size_t)(m & 63) * (L_ * V_)
                                   + (size_t)(m >> 6) * V_ + nn;
                        __builtin_nontemporal_store(v, dst);
                    } else
                        ((float*)Cv)[(size_t)m * ldc + nn] = v;
                }
            }
        }
    }
}

// ---------------------------------------------------------------------------
// gemm_big: 64M x (64*NF)N tile, 256 threads. NF=1 -> 64x64 (max blocks).
// ---------------------------------------------------------------------------
template<int SPLIT, int CMAP, bool NFAST, int NF>
__global__ __launch_bounds__(256) void gemm_big(
    const ush* __restrict__ Ah, const ush* __restrict__ Al, int lda,
    const ush* __restrict__ Wh, const ush* __restrict__ Wl, int ldw,
    const float* __restrict__ bias, void* __restrict__ Cv,
    int ldc, int N, int K)
{
    constexpr int ABYTES = 64 * LROW * 2;
    constexpr int BBYTES = 64 * NF * LROW * 2;
    constexpr int SMEM_BYTES = (SPLIT == 3) ? 2 * (ABYTES + BBYTES) : (ABYTES + BBYTES);
    __shared__ __align__(16) char smem[SMEM_BYTES];
    ush* sAh = (ush*)smem;
    ush* sBh = (ush*)(smem + ABYTES);
    ush* sAl = (ush*)(smem + ABYTES + BBYTES);
    ush* sBl = (ush*)(smem + 2 * ABYTES + BBYTES);

    const int tid = threadIdx.x;
    const int lane = tid & 63, w = tid >> 6;

    const int nbx = gridDim.x, nby = gridDim.y;
    const int nwg = nbx * nby;
    int lin = blockIdx.x + nbx * blockIdx.y;
    if ((nwg & 7) == 0) {
        const int q = nwg >> 3;
        lin = (lin & 7) * q + (lin >> 3);
    }
    int bx, by;
    if constexpr (NFAST) { by = lin % nby; bx = lin / nby; }
    else                 { bx = lin % nbx; by = lin / nbx; }
    const int mtile = bx * 64;
    const int ntile = by * (64 * NF);

    const int fr = lane & 15, kg = (lane >> 4) * 8;
    const int arow = tid >> 2, aq = (tid & 3) * 8;

    f32x4 acc[4][NF];
    #pragma unroll
    for (int mf = 0; mf < 4; ++mf)
        #pragma unroll
        for (int nf = 0; nf < NF; ++nf) acc[mf][nf] = {0.f, 0.f, 0.f, 0.f};

    const uint4 zv = make_uint4(0u, 0u, 0u, 0u);

    for (int kb = 0; kb < K; kb += 32) {
        uint4 a_h = *(const uint4*)(Ah + (size_t)(mtile + arow) * lda + kb + aq);
        uint4 a_l;
        uint4 b_h[NF], b_l[NF];
        #pragma unroll
        for (int p = 0; p < NF; ++p) {
            const int row = ntile + arow + 64 * p;
            b_h[p] = (row < N) ? *(const uint4*)(Wh + (size_t)row * ldw + kb + aq) : zv;
        }
        if constexpr (SPLIT == 3) {
            a_l = *(const uint4*)(Al + (size_t)(mtile + arow) * lda + kb + aq);
            #pragma unroll
            for (int p = 0; p < NF; ++p) {
                const int row = ntile + arow + 64 * p;
                b_l[p] = (row < N) ? *(const uint4*)(Wl + (size_t)row * ldw + kb + aq) : zv;
            }
        }

        __syncthreads();
        *(uint4*)(sAh + arow * LROW + aq) = a_h;
        #pragma unroll
        for (int p = 0; p < NF; ++p)
            *(uint4*)(sBh + (arow + 64 * p) * LROW + aq) = b_h[p];
        if constexpr (SPLIT == 3) {
            *(uint4*)(sAl + arow * LROW + aq) = a_l;
            #pragma unroll
            for (int p = 0; p < NF; ++p)
                *(uint4*)(sBl + (arow + 64 * p) * LROW + aq) = b_l[p];
        }
        __syncthreads();

        bf16x8 bh[NF], bl[NF];
        #pragma unroll
        for (int nf = 0; nf < NF; ++nf) {
            bh[nf] = *(const bf16x8*)(sBh + (w * (16 * NF) + nf * 16 + fr) * LROW + kg);
            if constexpr (SPLIT == 3)
                bl[nf] = *(const bf16x8*)(sBl + (w * (16 * NF) + nf * 16 + fr) * LROW + kg);
        }
        #pragma unroll
        for (int mf = 0; mf < 4; ++mf) {
            const bf16x8 ah = *(const bf16x8*)(sAh + (mf * 16 + fr) * LROW + kg);
            if constexpr (SPLIT == 3) {
                const bf16x8 al = *(const bf16x8*)(sAl + (mf * 16 + fr) * LROW + kg);
                #pragma unroll
                for (int nf = 0; nf < NF; ++nf) {
                    acc[mf][nf] = __builtin_amdgcn_mfma_f32_16x16x32_bf16(ah, bh[nf], acc[mf][nf], 0, 0, 0);
                    acc[mf][nf] = __builtin_amdgcn_mfma_f32_16x16x32_bf16(ah, bl[nf], acc[mf][nf], 0, 0, 0);
                    acc[mf][nf] = __builtin_amdgcn_mfma_f32_16x16x32_bf16(al, bh[nf], acc[mf][nf], 0, 0, 0);
                }
            } else {
                #pragma unroll
                for (int nf = 0; nf < NF; ++nf)
                    acc[mf][nf] = __builtin_amdgcn_mfma_f32_16x16x32_bf16(ah, bh[nf], acc[mf][nf], 0, 0, 0);
            }
        }
    }

    #pragma unroll
    for (int nf = 0; nf < NF; ++nf) {
        const int nn = ntile + w * (16 * NF) + nf * 16 + fr;
        if (nn < N) {
            const float bv = bias ? bias[nn] : 0.f;
            #pragma unroll
            for (int mf = 0; mf < 4; ++mf) {
                #pragma unroll
                for (int rr = 0; rr < 4; ++rr) {
                    const int m = mtile + mf * 16 + (lane >> 4) * 4 + rr;
                    const float v = acc[mf][nf][rr] + bv;
                    if constexpr (CMAP == 1)
                        ((ush*)Cv)[(size_t)m * ldc + nn] = f2bf(v);
                    else
                        ((float*)Cv)[(size_t)m * ldc + nn] = v;
                }
            }
        }
    }
}

// ---------------------------------------------------------------------------
// gemm_gates: 64x64 tile, segmented A (2 segments), split-K via grid.z.
// ---------------------------------------------------------------------------
__global__ __launch_bounds__(256) void gemm_gates(
    const ush* __restrict__ Ah0, const ush* __restrict__ Al0, int lda0, int k0,
    const ush* __restrict__ Ah1, const ush* __restrict__ Al1, int lda1,
    const ush* __restrict__ Wh, const ush* __restrict__ Wl, int ldw,
    float* __restrict__ C, int ldc, long zstride, int kChunk)
{
    __shared__ ush sAh[64 * LROW];
    __shared__ ush sBh[64 * LROW];
    __shared__ ush sAl[64 * LROW];
    __shared__ ush sBl[64 * LROW];

    const int tid = threadIdx.x;
    const int ntile = blockIdx.x * 64;
    const int kStart = blockIdx.z * kChunk;
    const int lane = tid & 63, w = tid >> 6;
    const int lrow = tid >> 2;
    const int lcol = (tid & 3) * 8;
    const int nrow = ntile + lrow;

    f32x4 acc[4];
    #pragma unroll
    for (int f = 0; f < 4; ++f) acc[f] = {0.f, 0.f, 0.f, 0.f};

    const int fr = lane & 15;
    const int kg = (lane >> 4) * 8;

    for (int kb = kStart; kb < kStart + kChunk; kb += 32) {
        const ush *ph, *pl; int lda, loc;
        if (kb < k0) { ph = Ah0; pl = Al0; lda = lda0; loc = kb; }
        else         { ph = Ah1; pl = Al1; lda = lda1; loc = kb - k0; }

        uint4 a_h = *(const uint4*)(ph + (size_t)lrow * lda + loc + lcol);
        uint4 b_h = *(const uint4*)(Wh + (size_t)nrow * ldw + kb + lcol);
        uint4 a_l = *(const uint4*)(pl + (size_t)lrow * lda + loc + lcol);
        uint4 b_l = *(const uint4*)(Wl + (size_t)nrow * ldw + kb + lcol);

        __syncthreads();
        *(uint4*)(sAh + lrow * LROW + lcol) = a_h;
        *(uint4*)(sBh + lrow * LROW + lcol) = b_h;
        *(uint4*)(sAl + lrow * LROW + lcol) = a_l;
        *(uint4*)(sBl + lrow * LROW + lcol) = b_l;
        __syncthreads();

        const bf16x8 bh = *(const bf16x8*)(sBh + (16 * w + fr) * LROW + kg);
        const bf16x8 bl = *(const bf16x8*)(sBl + (16 * w + fr) * LROW + kg);

        #pragma unroll
        for (int f = 0; f < 4; ++f) {
            const bf16x8 ah = *(const bf16x8*)(sAh + (16 * f + fr) * LROW + kg);
            const bf16x8 al = *(const bf16x8*)(sAl + (16 * f + fr) * LROW + kg);
            acc[f] = __builtin_amdgcn_mfma_f32_16x16x32_bf16(ah, bh, acc[f], 0, 0, 0);
            acc[f] = __builtin_amdgcn_mfma_f32_16x16x32_bf16(ah, bl, acc[f], 0, 0, 0);
            acc[f] = __builtin_amdgcn_mfma_f32_16x16x32_bf16(al, bh, acc[f], 0, 0, 0);
        }
    }

    const int n = ntile + 16 * w + (lane & 15);
    float* Cz = C + (size_t)blockIdx.z * zstride;
    #pragma unroll
    for (int f = 0; f < 4; ++f)
        #pragma unroll
        for (int rr = 0; rr < 4; ++rr) {
            const int m = 16 * f + (lane >> 4) * 4 + rr;
            Cz[(size_t)m * ldc + n] = acc[f][rr];
        }
}

// fused feats pass: fbh (bf16) + per-(b,f) mean -> mh/ml. block (fs, b).
__global__ __launch_bounds__(256) void prep_feats(
    const float* __restrict__ feats, ush* __restrict__ fbh,
    ush* __restrict__ mh, ush* __restrict__ ml)
{
    const int fs = blockIdx.x;
    const int b  = blockIdx.y;
    const int f = fs * 512 + threadIdx.x * 2;
    const float2* fp = (const float2*)(feats + (size_t)b * R_ * F_ + f);
    ush* fo = fbh + (size_t)b * R_ * F_ + f;
    float sx = 0.f, sy = 0.f;
    for (int r = 0; r < R_; ++r) {
        const float2 v = fp[(size_t)r * (F_ / 2)];
        sx += v.x; sy += v.y;
        ushort2 u; u.x = f2bf(v.x); u.y = f2bf(v.y);
        *(ushort2*)(fo + (size_t)r * F_) = u;
    }
    const float s = 1.f / (float)R_;
    sx *= s; sy *= s;
    const size_t mi = (size_t)b * F_ + f;
    const ush hx = f2bf(sx); mh[mi] = hx;     ml[mi] = f2bf(sx - bf2f(hx));
    const ush hy = f2bf(sy); mh[mi + 1] = hy; ml[mi + 1] = f2bf(sy - bf2f(hy));
}

// gather embeddings -> bf16 hi/lo (B,L,E)
__global__ __launch_bounds__(256) void gather_split(
    const float* __restrict__ emb, const int* __restrict__ cap,
    ush* __restrict__ eh, ush* __restrict__ el)
{
    const int idx = blockIdx.x * 256 + threadIdx.x;
    const int bt = idx >> 7, j = idx & 127;
    const int tok = cap[bt];
    const float4 v = reinterpret_cast<const float4*>(emb)[(size_t)tok * (E_ / 4) + j];
    const float a[4] = {v.x, v.y, v.z, v.w};
    #pragma unroll
    for (int c = 0; c < 4; ++c) {
        const ush hi = f2bf(a[c]);
        eh[idx * 4 + c] = hi;
        el[idx * 4 + c] = f2bf(a[c] - bf2f(hi));
    }
}

// generic fp32 -> bf16 (hi, optional lo)
__global__ __launch_bounds__(256) void split_kernel(
    const float* __restrict__ in, ush* __restrict__ hi, ush* __restrict__ lo, int n4)
{
    for (int i = blockIdx.x * 256 + threadIdx.x; i < n4; i += gridDim.x * 256) {
        const float4 v = reinterpret_cast<const float4*>(in)[i];
        const float a[4] = {v.x, v.y, v.z, v.w};
        #pragma unroll
        for (int c = 0; c < 4; ++c) {
            const ush h = f2bf(a[c]);
            hi[i * 4 + c] = h;
            if (lo) lo[i * 4 + c] = f2bf(a[c] - bf2f(h));
        }
    }
}

// W_ih columns [0:E) -> wx (2048x512); [E:) ++ W_hh -> wg2 (2048x2560); hi/lo
__global__ __launch_bounds__(256) void prep_wih(
    const float* __restrict__ W_ih, const float* __restrict__ W_hh,
    ush* __restrict__ wxh, ush* __restrict__ wxl,
    ush* __restrict__ wg2h, ush* __restrict__ wg2l)
{
    const int nrow = blockIdx.x;
    for (int k = threadIdx.x; k < E_; k += 256) {
        const float v = W_ih[(size_t)nrow * (E_ + F_) + k];
        const ush h = f2bf(v);
        wxh[(size_t)nrow * E_ + k] = h;
        wxl[(size_t)nrow * E_ + k] = f2bf(v - bf2f(h));
    }
    for (int k = threadIdx.x; k < F_ + H_; k += 256) {
        const float v = (k < F_) ? W_ih[(size_t)nrow * (E_ + F_) + E_ + k]
                                 : W_hh[(size_t)nrow * H_ + (k - F_)];
        const ush h = f2bf(v);
        wg2h[(size_t)nrow * (F_ + H_) + k] = h;
        wg2l[(size_t)nrow * (F_ + H_) + k] = f2bf(v - bf2f(h));
    }
}

// transpose W_hidp (A x H) -> whpT (H x A), bf16
__global__ __launch_bounds__(256) void transpose512(
    const float* __restrict__ in, ush* __restrict__ out)
{
    const int idx = blockIdx.x * 256 + threadIdx.x;
    const int k = idx >> 9, a = idx & 511;
    out[idx] = f2bf(in[(size_t)a * 512 + k]);
}

// reduce init GEMM partials: n<512 -> h0 (+split), n>=512 -> c0 (buffer 0)
__global__ __launch_bounds__(256) void init_reduce(
    const float* __restrict__ initp, const float* __restrict__ b_init_h,
    const float* __restrict__ b_init_c, float* __restrict__ h0f,
    float* __restrict__ c0, ush* __restrict__ h_hi, ush* __restrict__ h_lo)
{
    const int idx = blockIdx.x * 256 + threadIdx.x;
    const int b = idx >> 10, n = idx & 1023;
    float s = 0.f;
    #pragma unroll
    for (int z = 0; z < 8; ++z)
        s += initp[(size_t)z * (B_ * 1024) + (size_t)b * 1024 + n];
    if (n < 512) {
        s += b_init_h[n];
        h0f[b * H_ + n] = s;
        const ush hi = f2bf(s);
        h_hi[b * H_ + n] = hi;
        h_lo[b * H_ + n] = f2bf(s - bf2f(hi));
    } else {
        s += b_init_c[n - 512];
        c0[b * H_ + (n - 512)] = s;
    }
}

// ---------------------------------------------------------------------------
// step2_kernel<ATT>: grid (4, B) when ATT (fs = f-quarter), (1, B) else.
// 512 threads. All fs-blocks redundantly compute cell -> h, hid_proj,
// scores, softmax (alpha in LDS); each block then computes its 512-f ctx
// quarter. Only fs==0 writes h/c/hall/alph_out. c is double-buffered:
// read c2[(t-1)&1], write c2[t&1] -- no cross-block race.
// ---------------------------------------------------------------------------
template<bool ATT>
__global__ __launch_bounds__(512) void step2_kernel(
    const float* __restrict__ gparts, const float* __restrict__ egates,
    const float* __restrict__ b_ih, const float* __restrict__ b_hh,
    float* __restrict__ c2, const float* __restrict__ h0f,
    ush* __restrict__ h_hi, ush* __restrict__ h_lo,
    ush* __restrict__ hall_hi, ush* __restrict__ hall_lo,
    const ush* __restrict__ whpT, const float* __restrict__ b_hidp,
    const ush* __restrict__ fpb, const float* __restrict__ W_score,
    const float* __restrict__ b_score, const ush* __restrict__ fbh,
    ush* __restrict__ ctx_hi, ush* __restrict__ ctx_lo,
    float* __restrict__ alph_out, int t)
{
    __shared__ float sh_h[H_];
    __shared__ float sh_hp[A_];
    __shared__ float sh_ws[A_];
    __shared__ float sh_sc[200];
    __shared__ float red[2];
    const int tid = threadIdx.x;
    const int fs = blockIdx.x;
    const int b = blockIdx.y;
    const int n = tid;

    float hh;
    if (t > 0) {
        const float* c_old = c2 + (size_t)((t - 1) & 1) * B_ * H_;
        float* c_new = c2 + (size_t)(t & 1) * B_ * H_;
        const float* eg = egates + ((size_t)b * L_ + (t - 1)) * 2048;
        float gi = b_ih[n] + b_hh[n] + eg[n];
        float gf = b_ih[n + 512] + b_hh[n + 512] + eg[n + 512];
        float gg = b_ih[n + 1024] + b_hh[n + 1024] + eg[n + 1024];
        float go = b_ih[n + 1536] + b_hh[n + 1536] + eg[n + 1536];
        #pragma unroll
        for (int z = 0; z < 8; ++z) {
            const float* gz = gparts + (size_t)z * B_ * 2048 + (size_t)b * 2048;
            gi += gz[n]; gf += gz[n + 512]; gg += gz[n + 1024]; go += gz[n + 1536];
        }
        const float cc = fast_sig(gf) * c_old[b * H_ + n] + fast_sig(gi) * fast_tanh(gg);
        hh = fast_sig(go) * fast_tanh(cc);
        if (fs == 0) {
            c_new[b * H_ + n] = cc;
            const ush hi = f2bf(hh);
            const ush lo = f2bf(hh - bf2f(hi));
            h_hi[b * H_ + n] = hi;
            h_lo[b * H_ + n] = lo;
            const size_t hidx = ((size_t)(t - 1) * B_ + b) * H_ + n;
            hall_hi[hidx] = hi;
            hall_lo[hidx] = lo;
        }
    } else {
        hh = h0f[b * H_ + n];
    }
    if constexpr (!ATT) return;

    sh_h[n] = hh;
    sh_ws[n] = W_score[n];
    __syncthreads();

    // hid_proj (coalesced, bf16 whpT)
    {
        float a0 = 0.f, a1 = 0.f, a2 = 0.f, a3 = 0.f;
        #pragma unroll 4
        for (int k = 0; k < H_; k += 4) {
            a0 = fmaf(sh_h[k + 0], bf2f(whpT[(size_t)(k + 0) * A_ + tid]), a0);
            a1 = fmaf(sh_h[k + 1], bf2f(whpT[(size_t)(k + 1) * A_ + tid]), a1);
            a2 = fmaf(sh_h[k + 2], bf2f(whpT[(size_t)(k + 2) * A_ + tid]), a2);
            a3 = fmaf(sh_h[k + 3], bf2f(whpT[(size_t)(k + 3) * A_ + tid]), a3);
        }
        sh_hp[tid] = (a0 + a1) + (a2 + a3) + b_hidp[tid];
    }
    __syncthreads();

    const int lane = tid & 63, wid = tid >> 6;
    for (int r = wid; r < R_; r += 8) {
        const ushort2* row = reinterpret_cast<const ushort2*>(fpb + ((size_t)b * R_ + r) * A_);
        float acc = 0.f;
        #pragma unroll
        for (int j = 0; j < 4; ++j) {
            const ushort2 u = row[lane + 64 * j];
            const int a = 2 * (lane + 64 * j);
            acc += fast_tanh(bf2f(u.x) + sh_hp[a]) * sh_ws[a];
            acc += fast_tanh(bf2f(u.y) + sh_hp[a + 1]) * sh_ws[a + 1];
        }
        for (int off = 32; off > 0; off >>= 1) acc += __shfl_down(acc, off);
        if (lane == 0) sh_sc[r] = acc + b_score[0];
    }
    __syncthreads();

    if (tid < 64) {
        float m = -1e30f;
        for (int r = tid; r < R_; r += 64) m = fmaxf(m, sh_sc[r]);
        for (int off = 32; off > 0; off >>= 1) m = fmaxf(m, __shfl_xor(m, off));
        float s = 0.f;
        for (int r = tid; r < R_; r += 64) s += __expf(sh_sc[r] - m);
        for (int off = 32; off > 0; off >>= 1) s += __shfl_xor(s, off);
        if (tid == 0) { red[0] = m; red[1] = 1.f / s; }
    }
    __syncthreads();
    const float m = red[0], is = red[1];
    if (tid < R_) {
        const float av = __expf(sh_sc[tid] - m) * is;
        sh_sc[tid] = av;
        if (fs == 0) alph_out[((size_t)b * L_ + t) * R_ + tid] = av;
    }
    __syncthreads();

    // ---- ctx quarter: f = fs*512 + tid, sum over 196 regions (bf16 fbh) ----
    {
        const int f0 = fs * 512 + tid;
        const ush* fp2 = fbh + (size_t)b * R_ * F_ + f0;
        float cx = 0.f;
        #pragma unroll 4
        for (int r = 0; r < R_; ++r)
            cx = fmaf(sh_sc[r], bf2f(fp2[(size_t)r * F_]), cx);
        const size_t ci = (size_t)b * F_ + f0;
        const ush hx = f2bf(cx);
        ctx_hi[ci] = hx;
        ctx_lo[ci] = f2bf(cx - bf2f(hx));
    }
}

extern "C" void kernel_launch(void* const* d_in, const int* in_sizes, int n_in,
                              void* d_out, int out_size, void* d_ws, size_t ws_size,
                              hipStream_t stream)
{
    const float* feats    = (const float*)d_in[0];
    const int*   cap      = (const int*)  d_in[1];
    const float* emb      = (const float*)d_in[2];
    const float* W_init_h = (const float*)d_in[3];
    const float* b_init_h = (const float*)d_in[4];
    const float* W_init_c = (const float*)d_in[5];
    const float* b_init_c = (const float*)d_in[6];
    const float* W_ih     = (const float*)d_in[7];
    const float* b_ih     = (const float*)d_in[8];
    const float* W_hh     = (const float*)d_in[9];
    const float* b_hh     = (const float*)d_in[10];
    const float* W_featp  = (const float*)d_in[11];
    const float* b_featp  = (const float*)d_in[12];
    const float* W_hidp   = (const float*)d_in[13];
    const float* b_hidp   = (const float*)d_in[14];
    const float* W_score  = (const float*)d_in[15];
    const float* b_score  = (const float*)d_in[16];
    const float* W_out    = (const float*)d_in[17];
    const float* b_out    = (const float*)d_in[18];

    float* pred     = (float*)d_out;                          // (B,L,V)
    float* alph_out = pred + (size_t)B_ * L_ * V_;            // (B,L,R)

    char* p = (char*)d_ws;
    auto alloc = [&](size_t bytes) { char* q = p; p += (bytes + 255) & ~(size_t)255; return q; };

    ush*   fpb    = (ush*)  alloc((size_t)B_ * R_ * A_ * 2);
    ush*   eh     = (ush*)  alloc((size_t)B_ * L_ * E_ * 2);
    ush*   el     = (ush*)  alloc((size_t)B_ * L_ * E_ * 2);
    ush*   mh     = (ush*)  alloc((size_t)B_ * F_ * 2);
    ush*   ml     = (ush*)  alloc((size_t)B_ * F_ * 2);
    ush*   fbh    = (ush*)  alloc((size_t)B_ * R_ * F_ * 2);
    ush*   wfp_h  = (ush*)  alloc((size_t)A_ * F_ * 2);
    ush*   wiH    = (ush*)  alloc((size_t)1024 * F_ * 2);
    ush*   wiL    = (ush*)  alloc((size_t)1024 * F_ * 2);
    ush*   wxh    = (ush*)  alloc((size_t)2048 * E_ * 2);
    ush*   wxl    = (ush*)  alloc((size_t)2048 * E_ * 2);
    ush*   wg2h   = (ush*)  alloc((size_t)2048 * (F_ + H_) * 2);
    ush*   wg2l   = (ush*)  alloc((size_t)2048 * (F_ + H_) * 2);
    ush*   woh    = (ush*)  alloc((size_t)V_ * H_ * 2);
    ush*   wol    = (ush*)  alloc((size_t)V_ * H_ * 2);
    ush*   whpT   = (ush*)  alloc((size_t)H_ * A_ * 2);
    float* egates = (float*)alloc((size_t)B_ * L_ * 2048 * 4);
    float* h0f    = (float*)alloc((size_t)B_ * H_ * 4);
    float* c2     = (float*)alloc((size_t)2 * B_ * H_ * 4);   // double-buffered c
    ush*   h_hi   = (ush*)  alloc((size_t)B_ * H_ * 2);
    ush*   h_lo   = (ush*)  alloc((size_t)B_ * H_ * 2);
    ush*   hallh  = (ush*)  alloc((size_t)L_ * B_ * H_ * 2);
    ush*   halll  = (ush*)  alloc((size_t)L_ * B_ * H_ * 2);
    ush*   ctx_hi = (ush*)  alloc((size_t)B_ * F_ * 2);
    ush*   ctx_lo = (ush*)  alloc((size_t)B_ * F_ * 2);
    float* gparts = (float*)alloc((size_t)8 * B_ * 2048 * 4);
    float* initp  = (float*)alloc((size_t)8 * B_ * 1024 * 4);

    // ---- one-time prep ----
    prep_feats<<<dim3(4, B_), 256, 0, stream>>>(feats, fbh, mh, ml);
    gather_split<<<768, 256, 0, stream>>>(emb, cap, eh, el);
    split_kernel<<<2048, 256, 0, stream>>>(W_out, woh, wol, V_ * H_ / 4);
    split_kernel<<<512, 256, 0, stream>>>(W_init_h, wiH, wiL, H_ * F_ / 4);
    split_kernel<<<512, 256, 0, stream>>>(W_init_c, wiH + (size_t)512 * F_,
                                          wiL + (size_t)512 * F_, H_ * F_ / 4);
    split_kernel<<<512, 256, 0, stream>>>(W_featp, wfp_h, nullptr, A_ * F_ / 4);
    prep_wih<<<2048, 256, 0, stream>>>(W_ih, W_hh, wxh, wxl, wg2h, wg2l);
    transpose512<<<1024, 256, 0, stream>>>(W_hidp, whpT);

    // h0/c0 init: M=64, N=1024 (stacked), K=2048, split-K=8
    gemm_gates<<<dim3(16, 1, 8), 256, 0, stream>>>(
        mh, ml, F_, F_,
        mh, ml, F_,
        wiH, wiL, F_,
        initp, 1024, (long)B_ * 1024, F_ / 8);
    init_reduce<<<256, 256, 0, stream>>>(initp, b_init_h, b_init_c, h0f, c2, h_hi, h_lo);

    // feat_proj (SPLIT=1, bf16 out, NF=1): 64x64 tiles -> grid(196,8)=1568
    gemm_big<1, 1, true, 1><<<dim3(196, 8), 256, 0, stream>>>(
        fbh, nullptr, F_, wfp_h, nullptr, F_, b_featp, fpb, A_, A_, F_);

    // emb gate part for ALL steps (SPLIT=3, NF=2): grid(24,16)=384
    gemm_big<3, 0, false, 2><<<dim3(24, 16), 256, 0, stream>>>(
        eh, el, E_, wxh, wxl, E_, nullptr, egates, 2048, 2048, E_);

    // ---- sequential decode: 2 kernels per step ----
    for (int t = 0; t < L_; ++t) {
        step2_kernel<true><<<dim3(4, B_), 512, 0, stream>>>(
            gparts, egates, b_ih, b_hh, c2, h0f, h_hi, h_lo, hallh, halll,
            whpT, b_hidp, fpb, W_score, b_score, fbh, ctx_hi, ctx_lo,
            alph_out, t);

        gemm_gates<<<dim3(32, 1, 8), 256, 0, stream>>>(
            ctx_hi, ctx_lo, F_, F_,
            h_hi, h_lo, H_,
            wg2h, wg2l, F_ + H_,
            gparts, 4 * H_, (long)B_ * 4 * H_, (F_ + H_) / 8);
    }

    // final cell: h_L -> hall[L-1]
    step2_kernel<false><<<dim3(1, B_), 512, 0, stream>>>(
        gparts, egates, b_ih, b_hh, c2, h0f, h_hi, h_lo, hallh, halll,
        whpT, b_hidp, fpb, W_score, b_score, fbh, ctx_hi, ctx_lo,
        alph_out, L_);

    // predictions for ALL steps (SPLIT=3): M=1536 -> 12 tiles of 128, N=12000
    gemm_big128<3, 2, false><<<dim3(12, 47), 512, 0, stream>>>(
        hallh, halll, H_, woh, wol, H_, b_out, pred, 0, V_, H_);
}

// Round 14
// 1933.517 us; speedup vs baseline: 1.7628x; 1.0114x over previous
//
#include <hip/hip_runtime.h>

#define B_ 64
#define R_ 196
#define F_ 2048
#define E_ 512
#define H_ 512
#define A_ 512
#define V_ 12000
#define L_ 24

typedef __attribute__((ext_vector_type(8))) short bf16x8;
typedef __attribute__((ext_vector_type(4))) float f32x4;
typedef unsigned short ush;

__device__ __forceinline__ float fast_tanh(float x) {
    float t = __expf(2.f * x);
    return 1.f - 2.f / (t + 1.f);
}
__device__ __forceinline__ float fast_sig(float x) {
    return 1.f / (1.f + __expf(-x));
}
__device__ __forceinline__ ush f2bf(float x) {
    unsigned int u = __float_as_uint(x);
    return (ush)((u + 0x7fffu + ((u >> 16) & 1u)) >> 16);
}
__device__ __forceinline__ float bf2f(ush b) {
    return __uint_as_float(((unsigned int)b) << 16);
}

#define LROW 40   // LDS row stride (32 k-elems + 8 pad)

// ---------------------------------------------------------------------------
// gemm_big128: C = A @ W^T (+bias). Tile 128M x 256N, BK=32, 512 threads.
// Pred GEMM (564 blocks; WRITE-amp fixed by 128-tile). Bijective XCD swizzle.
// SPLIT=3: (hi,lo) bf16x2, 3 MFMAs. CMAP=2: pred layout, fp32 NT stores.
// ---------------------------------------------------------------------------
template<int SPLIT, int CMAP, bool NFAST>
__global__ __launch_bounds__(512) void gemm_big128(
    const ush* __restrict__ Ah, const ush* __restrict__ Al, int lda,
    const ush* __restrict__ Wh, const ush* __restrict__ Wl, int ldw,
    const float* __restrict__ bias, void* __restrict__ Cv,
    int ldc, int N, int K)
{
    constexpr int SMEM_BYTES = (SPLIT == 3) ? 61440 : 30720;
    __shared__ __align__(16) char smem[SMEM_BYTES];
    ush* sAh = (ush*)smem;
    ush* sBh = (ush*)(smem + 10240);
    ush* sAl = (ush*)(smem + 30720);
    ush* sBl = (ush*)(smem + 40960);

    const int tid = threadIdx.x;
    const int lane = tid & 63, w = tid >> 6;
    const int mw = w >> 2, nw = w & 3;

    const int nbx = gridDim.x, nby = gridDim.y;
    const int nwg = nbx * nby;
    const int orig = blockIdx.x + nbx * blockIdx.y;
    const int q = nwg >> 3, r = nwg & 7;
    const int xcd = orig & 7, idx = orig >> 3;
    const int lin = (xcd < r ? xcd * (q + 1) : r * (q + 1) + (xcd - r) * q) + idx;
    int bx, by;
    if constexpr (NFAST) { by = lin % nby; bx = lin / nby; }
    else                 { bx = lin % nbx; by = lin / nbx; }
    const int mtile = bx * 128;
    const int ntile = by * 256;

    const int fr = lane & 15, kg = (lane >> 4) * 8;
    const int arow = tid >> 2, aq = (tid & 3) * 8;

    f32x4 acc[4][4];
    #pragma unroll
    for (int mf = 0; mf < 4; ++mf)
        #pragma unroll
        for (int nf = 0; nf < 4; ++nf) acc[mf][nf] = {0.f, 0.f, 0.f, 0.f};

    const uint4 zv = make_uint4(0u, 0u, 0u, 0u);

    for (int kb = 0; kb < K; kb += 32) {
        uint4 a_h = *(const uint4*)(Ah + (size_t)(mtile + arow) * lda + kb + aq);
        uint4 a_l;
        uint4 b_h[2], b_l[2];
        #pragma unroll
        for (int p = 0; p < 2; ++p) {
            const int row = ntile + arow + 128 * p;
            b_h[p] = (row < N) ? *(const uint4*)(Wh + (size_t)row * ldw + kb + aq) : zv;
        }
        if constexpr (SPLIT == 3) {
            a_l = *(const uint4*)(Al + (size_t)(mtile + arow) * lda + kb + aq);
            #pragma unroll
            for (int p = 0; p < 2; ++p) {
                const int row = ntile + arow + 128 * p;
                b_l[p] = (row < N) ? *(const uint4*)(Wl + (size_t)row * ldw + kb + aq) : zv;
            }
        }

        __syncthreads();
        *(uint4*)(sAh + arow * LROW + aq) = a_h;
        #pragma unroll
        for (int p = 0; p < 2; ++p)
            *(uint4*)(sBh + (arow + 128 * p) * LROW + aq) = b_h[p];
        if constexpr (SPLIT == 3) {
            *(uint4*)(sAl + arow * LROW + aq) = a_l;
            #pragma unroll
            for (int p = 0; p < 2; ++p)
                *(uint4*)(sBl + (arow + 128 * p) * LROW + aq) = b_l[p];
        }
        __syncthreads();

        bf16x8 bh[4], bl[4];
        #pragma unroll
        for (int nf = 0; nf < 4; ++nf) {
            bh[nf] = *(const bf16x8*)(sBh + (nw * 64 + nf * 16 + fr) * LROW + kg);
            if constexpr (SPLIT == 3)
                bl[nf] = *(const bf16x8*)(sBl + (nw * 64 + nf * 16 + fr) * LROW + kg);
        }
        #pragma unroll
        for (int mf = 0; mf < 4; ++mf) {
            const bf16x8 ah = *(const bf16x8*)(sAh + (mw * 64 + mf * 16 + fr) * LROW + kg);
            if constexpr (SPLIT == 3) {
                const bf16x8 al = *(const bf16x8*)(sAl + (mw * 64 + mf * 16 + fr) * LROW + kg);
                #pragma unroll
                for (int nf = 0; nf < 4; ++nf) {
                    acc[mf][nf] = __builtin_amdgcn_mfma_f32_16x16x32_bf16(ah, bh[nf], acc[mf][nf], 0, 0, 0);
                    acc[mf][nf] = __builtin_amdgcn_mfma_f32_16x16x32_bf16(ah, bl[nf], acc[mf][nf], 0, 0, 0);
                    acc[mf][nf] = __builtin_amdgcn_mfma_f32_16x16x32_bf16(al, bh[nf], acc[mf][nf], 0, 0, 0);
                }
            } else {
                #pragma unroll
                for (int nf = 0; nf < 4; ++nf)
                    acc[mf][nf] = __builtin_amdgcn_mfma_f32_16x16x32_bf16(ah, bh[nf], acc[mf][nf], 0, 0, 0);
            }
        }
    }

    #pragma unroll
    for (int nf = 0; nf < 4; ++nf) {
        const int nn = ntile + nw * 64 + nf * 16 + fr;
        if (nn < N) {
            const float bv = bias ? bias[nn] : 0.f;
            #pragma unroll
            for (int mf = 0; mf < 4; ++mf) {
                #pragma unroll
                for (int rr = 0; rr < 4; ++rr) {
                    const int m = mtile + mw * 64 + mf * 16 + (lane >> 4) * 4 + rr;
                    const float v = acc[mf][nf][rr] + bv;
                    if constexpr (CMAP == 1)
                        ((ush*)Cv)[(size_t)m * ldc + nn] = f2bf(v);
                    else if constexpr (CMAP == 2) {
                        float* dst = (float*)Cv + (size_t)(m & 63) * (L_ * V_)
                                   + (size_t)(m >> 6) * V_ + nn;
                        __builtin_nontemporal_store(v, dst);
                    } else
                        ((float*)Cv)[(size_t)m * ldc + nn] = v;
                }
            }
        }
    }
}

// ---------------------------------------------------------------------------
// gemm_big: 64M x (64*NF)N tile, 256 threads. NF=1 -> 64x64 (max blocks).
// ---------------------------------------------------------------------------
template<int SPLIT, int CMAP, bool NFAST, int NF>
__global__ __launch_bounds__(256) void gemm_big(
    const ush* __restrict__ Ah, const ush* __restrict__ Al, int lda,
    const ush* __restrict__ Wh, const ush* __restrict__ Wl, int ldw,
    const float* __restrict__ bias, void* __restrict__ Cv,
    int ldc, int N, int K)
{
    constexpr int ABYTES = 64 * LROW * 2;
    constexpr int BBYTES = 64 * NF * LROW * 2;
    constexpr int SMEM_BYTES = (SPLIT == 3) ? 2 * (ABYTES + BBYTES) : (ABYTES + BBYTES);
    __shared__ __align__(16) char smem[SMEM_BYTES];
    ush* sAh = (ush*)smem;
    ush* sBh = (ush*)(smem + ABYTES);
    ush* sAl = (ush*)(smem + ABYTES + BBYTES);
    ush* sBl = (ush*)(smem + 2 * ABYTES + BBYTES);

    const int tid = threadIdx.x;
    const int lane = tid & 63, w = tid >> 6;

    const int nbx = gridDim.x, nby = gridDim.y;
    const int nwg = nbx * nby;
    int lin = blockIdx.x + nbx * blockIdx.y;
    if ((nwg & 7) == 0) {
        const int q = nwg >> 3;
        lin = (lin & 7) * q + (lin >> 3);
    }
    int bx, by;
    if constexpr (NFAST) { by = lin % nby; bx = lin / nby; }
    else                 { bx = lin % nbx; by = lin / nbx; }
    const int mtile = bx * 64;
    const int ntile = by * (64 * NF);

    const int fr = lane & 15, kg = (lane >> 4) * 8;
    const int arow = tid >> 2, aq = (tid & 3) * 8;

    f32x4 acc[4][NF];
    #pragma unroll
    for (int mf = 0; mf < 4; ++mf)
        #pragma unroll
        for (int nf = 0; nf < NF; ++nf) acc[mf][nf] = {0.f, 0.f, 0.f, 0.f};

    const uint4 zv = make_uint4(0u, 0u, 0u, 0u);

    for (int kb = 0; kb < K; kb += 32) {
        uint4 a_h = *(const uint4*)(Ah + (size_t)(mtile + arow) * lda + kb + aq);
        uint4 a_l;
        uint4 b_h[NF], b_l[NF];
        #pragma unroll
        for (int p = 0; p < NF; ++p) {
            const int row = ntile + arow + 64 * p;
            b_h[p] = (row < N) ? *(const uint4*)(Wh + (size_t)row * ldw + kb + aq) : zv;
        }
        if constexpr (SPLIT == 3) {
            a_l = *(const uint4*)(Al + (size_t)(mtile + arow) * lda + kb + aq);
            #pragma unroll
            for (int p = 0; p < NF; ++p) {
                const int row = ntile + arow + 64 * p;
                b_l[p] = (row < N) ? *(const uint4*)(Wl + (size_t)row * ldw + kb + aq) : zv;
            }
        }

        __syncthreads();
        *(uint4*)(sAh + arow * LROW + aq) = a_h;
        #pragma unroll
        for (int p = 0; p < NF; ++p)
            *(uint4*)(sBh + (arow + 64 * p) * LROW + aq) = b_h[p];
        if constexpr (SPLIT == 3) {
            *(uint4*)(sAl + arow * LROW + aq) = a_l;
            #pragma unroll
            for (int p = 0; p < NF; ++p)
                *(uint4*)(sBl + (arow + 64 * p) * LROW + aq) = b_l[p];
        }
        __syncthreads();

        bf16x8 bh[NF], bl[NF];
        #pragma unroll
        for (int nf = 0; nf < NF; ++nf) {
            bh[nf] = *(const bf16x8*)(sBh + (w * (16 * NF) + nf * 16 + fr) * LROW + kg);
            if constexpr (SPLIT == 3)
                bl[nf] = *(const bf16x8*)(sBl + (w * (16 * NF) + nf * 16 + fr) * LROW + kg);
        }
        #pragma unroll
        for (int mf = 0; mf < 4; ++mf) {
            const bf16x8 ah = *(const bf16x8*)(sAh + (mf * 16 + fr) * LROW + kg);
            if constexpr (SPLIT == 3) {
                const bf16x8 al = *(const bf16x8*)(sAl + (mf * 16 + fr) * LROW + kg);
                #pragma unroll
                for (int nf = 0; nf < NF; ++nf) {
                    acc[mf][nf] = __builtin_amdgcn_mfma_f32_16x16x32_bf16(ah, bh[nf], acc[mf][nf], 0, 0, 0);
                    acc[mf][nf] = __builtin_amdgcn_mfma_f32_16x16x32_bf16(ah, bl[nf], acc[mf][nf], 0, 0, 0);
                    acc[mf][nf] = __builtin_amdgcn_mfma_f32_16x16x32_bf16(al, bh[nf], acc[mf][nf], 0, 0, 0);
                }
            } else {
                #pragma unroll
                for (int nf = 0; nf < NF; ++nf)
                    acc[mf][nf] = __builtin_amdgcn_mfma_f32_16x16x32_bf16(ah, bh[nf], acc[mf][nf], 0, 0, 0);
            }
        }
    }

    #pragma unroll
    for (int nf = 0; nf < NF; ++nf) {
        const int nn = ntile + w * (16 * NF) + nf * 16 + fr;
        if (nn < N) {
            const float bv = bias ? bias[nn] : 0.f;
            #pragma unroll
            for (int mf = 0; mf < 4; ++mf) {
                #pragma unroll
                for (int rr = 0; rr < 4; ++rr) {
                    const int m = mtile + mf * 16 + (lane >> 4) * 4 + rr;
                    const float v = acc[mf][nf][rr] + bv;
                    if constexpr (CMAP == 1)
                        ((ush*)Cv)[(size_t)m * ldc + nn] = f2bf(v);
                    else
                        ((float*)Cv)[(size_t)m * ldc + nn] = v;
                }
            }
        }
    }
}

// ---------------------------------------------------------------------------
// gemm_gates<AMODE>: 64x64 tile, segmented A (2 segments), split-K via grid.z.
// AMODE=3: full bf16x2 (3 MFMAs). AMODE=2: drop A-lo term (2 MFMAs) -- used
// for the per-step gates GEMM (ctx/h quantization error ~1e-3 on gate
// pre-activations, absorbed by sigmoid/tanh contraction).
// ---------------------------------------------------------------------------
template<int AMODE>
__global__ __launch_bounds__(256) void gemm_gates(
    const ush* __restrict__ Ah0, const ush* __restrict__ Al0, int lda0, int k0,
    const ush* __restrict__ Ah1, const ush* __restrict__ Al1, int lda1,
    const ush* __restrict__ Wh, const ush* __restrict__ Wl, int ldw,
    float* __restrict__ C, int ldc, long zstride, int kChunk)
{
    __shared__ ush sAh[64 * LROW];
    __shared__ ush sBh[64 * LROW];
    __shared__ ush sAl[64 * LROW];
    __shared__ ush sBl[64 * LROW];

    const int tid = threadIdx.x;
    const int ntile = blockIdx.x * 64;
    const int kStart = blockIdx.z * kChunk;
    const int lane = tid & 63, w = tid >> 6;
    const int lrow = tid >> 2;
    const int lcol = (tid & 3) * 8;
    const int nrow = ntile + lrow;

    f32x4 acc[4];
    #pragma unroll
    for (int f = 0; f < 4; ++f) acc[f] = {0.f, 0.f, 0.f, 0.f};

    const int fr = lane & 15;
    const int kg = (lane >> 4) * 8;

    for (int kb = kStart; kb < kStart + kChunk; kb += 32) {
        const ush *ph, *pl; int lda, loc;
        if (kb < k0) { ph = Ah0; pl = Al0; lda = lda0; loc = kb; }
        else         { ph = Ah1; pl = Al1; lda = lda1; loc = kb - k0; }

        uint4 a_h = *(const uint4*)(ph + (size_t)lrow * lda + loc + lcol);
        uint4 b_h = *(const uint4*)(Wh + (size_t)nrow * ldw + kb + lcol);
        uint4 b_l = *(const uint4*)(Wl + (size_t)nrow * ldw + kb + lcol);
        uint4 a_l;
        if constexpr (AMODE == 3)
            a_l = *(const uint4*)(pl + (size_t)lrow * lda + loc + lcol);

        __syncthreads();
        *(uint4*)(sAh + lrow * LROW + lcol) = a_h;
        *(uint4*)(sBh + lrow * LROW + lcol) = b_h;
        *(uint4*)(sBl + lrow * LROW + lcol) = b_l;
        if constexpr (AMODE == 3)
            *(uint4*)(sAl + lrow * LROW + lcol) = a_l;
        __syncthreads();

        const bf16x8 bh = *(const bf16x8*)(sBh + (16 * w + fr) * LROW + kg);
        const bf16x8 bl = *(const bf16x8*)(sBl + (16 * w + fr) * LROW + kg);

        #pragma unroll
        for (int f = 0; f < 4; ++f) {
            const bf16x8 ah = *(const bf16x8*)(sAh + (16 * f + fr) * LROW + kg);
            acc[f] = __builtin_amdgcn_mfma_f32_16x16x32_bf16(ah, bh, acc[f], 0, 0, 0);
            acc[f] = __builtin_amdgcn_mfma_f32_16x16x32_bf16(ah, bl, acc[f], 0, 0, 0);
            if constexpr (AMODE == 3) {
                const bf16x8 al = *(const bf16x8*)(sAl + (16 * f + fr) * LROW + kg);
                acc[f] = __builtin_amdgcn_mfma_f32_16x16x32_bf16(al, bh, acc[f], 0, 0, 0);
            }
        }
    }

    const int n = ntile + 16 * w + (lane & 15);
    float* Cz = C + (size_t)blockIdx.z * zstride;
    #pragma unroll
    for (int f = 0; f < 4; ++f)
        #pragma unroll
        for (int rr = 0; rr < 4; ++rr) {
            const int m = 16 * f + (lane >> 4) * 4 + rr;
            Cz[(size_t)m * ldc + n] = acc[f][rr];
        }
}

// fused feats pass: fbh (bf16) + per-(b,f) mean -> mh/ml. block (fs, b).
__global__ __launch_bounds__(256) void prep_feats(
    const float* __restrict__ feats, ush* __restrict__ fbh,
    ush* __restrict__ mh, ush* __restrict__ ml)
{
    const int fs = blockIdx.x;
    const int b  = blockIdx.y;
    const int f = fs * 512 + threadIdx.x * 2;
    const float2* fp = (const float2*)(feats + (size_t)b * R_ * F_ + f);
    ush* fo = fbh + (size_t)b * R_ * F_ + f;
    float sx = 0.f, sy = 0.f;
    for (int r = 0; r < R_; ++r) {
        const float2 v = fp[(size_t)r * (F_ / 2)];
        sx += v.x; sy += v.y;
        ushort2 u; u.x = f2bf(v.x); u.y = f2bf(v.y);
        *(ushort2*)(fo + (size_t)r * F_) = u;
    }
    const float s = 1.f / (float)R_;
    sx *= s; sy *= s;
    const size_t mi = (size_t)b * F_ + f;
    const ush hx = f2bf(sx); mh[mi] = hx;     ml[mi] = f2bf(sx - bf2f(hx));
    const ush hy = f2bf(sy); mh[mi + 1] = hy; ml[mi + 1] = f2bf(sy - bf2f(hy));
}

// gather embeddings -> bf16 hi/lo (B,L,E)
__global__ __launch_bounds__(256) void gather_split(
    const float* __restrict__ emb, const int* __restrict__ cap,
    ush* __restrict__ eh, ush* __restrict__ el)
{
    const int idx = blockIdx.x * 256 + threadIdx.x;
    const int bt = idx >> 7, j = idx & 127;
    const int tok = cap[bt];
    const float4 v = reinterpret_cast<const float4*>(emb)[(size_t)tok * (E_ / 4) + j];
    const float a[4] = {v.x, v.y, v.z, v.w};
    #pragma unroll
    for (int c = 0; c < 4; ++c) {
        const ush hi = f2bf(a[c]);
        eh[idx * 4 + c] = hi;
        el[idx * 4 + c] = f2bf(a[c] - bf2f(hi));
    }
}

// generic fp32 -> bf16 (hi, optional lo)
__global__ __launch_bounds__(256) void split_kernel(
    const float* __restrict__ in, ush* __restrict__ hi, ush* __restrict__ lo, int n4)
{
    for (int i = blockIdx.x * 256 + threadIdx.x; i < n4; i += gridDim.x * 256) {
        const float4 v = reinterpret_cast<const float4*>(in)[i];
        const float a[4] = {v.x, v.y, v.z, v.w};
        #pragma unroll
        for (int c = 0; c < 4; ++c) {
            const ush h = f2bf(a[c]);
            hi[i * 4 + c] = h;
            if (lo) lo[i * 4 + c] = f2bf(a[c] - bf2f(h));
        }
    }
}

// W_ih columns [0:E) -> wx (2048x512); [E:) ++ W_hh -> wg2 (2048x2560); hi/lo
__global__ __launch_bounds__(256) void prep_wih(
    const float* __restrict__ W_ih, const float* __restrict__ W_hh,
    ush* __restrict__ wxh, ush* __restrict__ wxl,
    ush* __restrict__ wg2h, ush* __restrict__ wg2l)
{
    const int nrow = blockIdx.x;
    for (int k = threadIdx.x; k < E_; k += 256) {
        const float v = W_ih[(size_t)nrow * (E_ + F_) + k];
        const ush h = f2bf(v);
        wxh[(size_t)nrow * E_ + k] = h;
        wxl[(size_t)nrow * E_ + k] = f2bf(v - bf2f(h));
    }
    for (int k = threadIdx.x; k < F_ + H_; k += 256) {
        const float v = (k < F_) ? W_ih[(size_t)nrow * (E_ + F_) + E_ + k]
                                 : W_hh[(size_t)nrow * H_ + (k - F_)];
        const ush h = f2bf(v);
        wg2h[(size_t)nrow * (F_ + H_) + k] = h;
        wg2l[(size_t)nrow * (F_ + H_) + k] = f2bf(v - bf2f(h));
    }
}

// transpose W_hidp (A x H) -> whpT (H x A), bf16
__global__ __launch_bounds__(256) void transpose512(
    const float* __restrict__ in, ush* __restrict__ out)
{
    const int idx = blockIdx.x * 256 + threadIdx.x;
    const int k = idx >> 9, a = idx & 511;
    out[idx] = f2bf(in[(size_t)a * 512 + k]);
}

// reduce init GEMM partials: n<512 -> h0 (+split), n>=512 -> c0 (buffer 0)
__global__ __launch_bounds__(256) void init_reduce(
    const float* __restrict__ initp, const float* __restrict__ b_init_h,
    const float* __restrict__ b_init_c, float* __restrict__ h0f,
    float* __restrict__ c0, ush* __restrict__ h_hi, ush* __restrict__ h_lo)
{
    const int idx = blockIdx.x * 256 + threadIdx.x;
    const int b = idx >> 10, n = idx & 1023;
    float s = 0.f;
    #pragma unroll
    for (int z = 0; z < 8; ++z)
        s += initp[(size_t)z * (B_ * 1024) + (size_t)b * 1024 + n];
    if (n < 512) {
        s += b_init_h[n];
        h0f[b * H_ + n] = s;
        const ush hi = f2bf(s);
        h_hi[b * H_ + n] = hi;
        h_lo[b * H_ + n] = f2bf(s - bf2f(hi));
    } else {
        s += b_init_c[n - 512];
        c0[b * H_ + (n - 512)] = s;
    }
}

// ---------------------------------------------------------------------------
// step2_kernel<ATT>: grid (4, B) when ATT (fs = f-quarter), (1, B) else.
// 512 threads. All fs-blocks redundantly compute cell -> h, hid_proj,
// scores, softmax (alpha in LDS); each block then computes its 512-f ctx
// quarter (bf16 hi only -- lo dropped, error absorbed by gate nonlinearity).
// Only fs==0 writes h/c/hall/alph_out. c double-buffered by t parity.
// ---------------------------------------------------------------------------
template<bool ATT>
__global__ __launch_bounds__(512) void step2_kernel(
    const float* __restrict__ gparts, const float* __restrict__ egates,
    const float* __restrict__ b_ih, const float* __restrict__ b_hh,
    float* __restrict__ c2, const float* __restrict__ h0f,
    ush* __restrict__ h_hi, ush* __restrict__ h_lo,
    ush* __restrict__ hall_hi, ush* __restrict__ hall_lo,
    const ush* __restrict__ whpT, const float* __restrict__ b_hidp,
    const ush* __restrict__ fpb, const float* __restrict__ W_score,
    const float* __restrict__ b_score, const ush* __restrict__ fbh,
    ush* __restrict__ ctx_hi,
    float* __restrict__ alph_out, int t)
{
    __shared__ float sh_h[H_];
    __shared__ float sh_hp[A_];
    __shared__ float sh_ws[A_];
    __shared__ float sh_sc[200];
    __shared__ float red[2];
    const int tid = threadIdx.x;
    const int fs = blockIdx.x;
    const int b = blockIdx.y;
    const int n = tid;

    float hh;
    if (t > 0) {
        const float* c_old = c2 + (size_t)((t - 1) & 1) * B_ * H_;
        float* c_new = c2 + (size_t)(t & 1) * B_ * H_;
        const float* eg = egates + ((size_t)b * L_ + (t - 1)) * 2048;
        float gi = b_ih[n] + b_hh[n] + eg[n];
        float gf = b_ih[n + 512] + b_hh[n + 512] + eg[n + 512];
        float gg = b_ih[n + 1024] + b_hh[n + 1024] + eg[n + 1024];
        float go = b_ih[n + 1536] + b_hh[n + 1536] + eg[n + 1536];
        #pragma unroll
        for (int z = 0; z < 8; ++z) {
            const float* gz = gparts + (size_t)z * B_ * 2048 + (size_t)b * 2048;
            gi += gz[n]; gf += gz[n + 512]; gg += gz[n + 1024]; go += gz[n + 1536];
        }
        const float cc = fast_sig(gf) * c_old[b * H_ + n] + fast_sig(gi) * fast_tanh(gg);
        hh = fast_sig(go) * fast_tanh(cc);
        if (fs == 0) {
            c_new[b * H_ + n] = cc;
            const ush hi = f2bf(hh);
            const ush lo = f2bf(hh - bf2f(hi));
            h_hi[b * H_ + n] = hi;
            h_lo[b * H_ + n] = lo;
            const size_t hidx = ((size_t)(t - 1) * B_ + b) * H_ + n;
            hall_hi[hidx] = hi;
            hall_lo[hidx] = lo;
        }
    } else {
        hh = h0f[b * H_ + n];
    }
    if constexpr (!ATT) return;

    sh_h[n] = hh;
    sh_ws[n] = W_score[n];
    __syncthreads();

    // hid_proj (coalesced, bf16 whpT)
    {
        float a0 = 0.f, a1 = 0.f, a2 = 0.f, a3 = 0.f;
        #pragma unroll 4
        for (int k = 0; k < H_; k += 4) {
            a0 = fmaf(sh_h[k + 0], bf2f(whpT[(size_t)(k + 0) * A_ + tid]), a0);
            a1 = fmaf(sh_h[k + 1], bf2f(whpT[(size_t)(k + 1) * A_ + tid]), a1);
            a2 = fmaf(sh_h[k + 2], bf2f(whpT[(size_t)(k + 2) * A_ + tid]), a2);
            a3 = fmaf(sh_h[k + 3], bf2f(whpT[(size_t)(k + 3) * A_ + tid]), a3);
        }
        sh_hp[tid] = (a0 + a1) + (a2 + a3) + b_hidp[tid];
    }
    __syncthreads();

    const int lane = tid & 63, wid = tid >> 6;
    for (int r = wid; r < R_; r += 8) {
        const ushort2* row = reinterpret_cast<const ushort2*>(fpb + ((size_t)b * R_ + r) * A_);
        float acc = 0.f;
        #pragma unroll
        for (int j = 0; j < 4; ++j) {
            const ushort2 u = row[lane + 64 * j];
            const int a = 2 * (lane + 64 * j);
            acc += fast_tanh(bf2f(u.x) + sh_hp[a]) * sh_ws[a];
            acc += fast_tanh(bf2f(u.y) + sh_hp[a + 1]) * sh_ws[a + 1];
        }
        for (int off = 32; off > 0; off >>= 1) acc += __shfl_down(acc, off);
        if (lane == 0) sh_sc[r] = acc + b_score[0];
    }
    __syncthreads();

    if (tid < 64) {
        float m = -1e30f;
        for (int r = tid; r < R_; r += 64) m = fmaxf(m, sh_sc[r]);
        for (int off = 32; off > 0; off >>= 1) m = fmaxf(m, __shfl_xor(m, off));
        float s = 0.f;
        for (int r = tid; r < R_; r += 64) s += __expf(sh_sc[r] - m);
        for (int off = 32; off > 0; off >>= 1) s += __shfl_xor(s, off);
        if (tid == 0) { red[0] = m; red[1] = 1.f / s; }
    }
    __syncthreads();
    const float m = red[0], is = red[1];
    if (tid < R_) {
        const float av = __expf(sh_sc[tid] - m) * is;
        sh_sc[tid] = av;
        if (fs == 0) alph_out[((size_t)b * L_ + t) * R_ + tid] = av;
    }
    __syncthreads();

    // ---- ctx quarter: f = fs*512 + tid, sum over 196 regions (bf16 fbh) ----
    {
        const int f0 = fs * 512 + tid;
        const ush* fp2 = fbh + (size_t)b * R_ * F_ + f0;
        float cx = 0.f;
        #pragma unroll 4
        for (int r = 0; r < R_; ++r)
            cx = fmaf(sh_sc[r], bf2f(fp2[(size_t)r * F_]), cx);
        ctx_hi[(size_t)b * F_ + f0] = f2bf(cx);
    }
}

extern "C" void kernel_launch(void* const* d_in, const int* in_sizes, int n_in,
                              void* d_out, int out_size, void* d_ws, size_t ws_size,
                              hipStream_t stream)
{
    const float* feats    = (const float*)d_in[0];
    const int*   cap      = (const int*)  d_in[1];
    const float* emb      = (const float*)d_in[2];
    const float* W_init_h = (const float*)d_in[3];
    const float* b_init_h = (const float*)d_in[4];
    const float* W_init_c = (const float*)d_in[5];
    const float* b_init_c = (const float*)d_in[6];
    const float* W_ih     = (const float*)d_in[7];
    const float* b_ih     = (const float*)d_in[8];
    const float* W_hh     = (const float*)d_in[9];
    const float* b_hh     = (const float*)d_in[10];
    const float* W_featp  = (const float*)d_in[11];
    const float* b_featp  = (const float*)d_in[12];
    const float* W_hidp   = (const float*)d_in[13];
    const float* b_hidp   = (const float*)d_in[14];
    const float* W_score  = (const float*)d_in[15];
    const float* b_score  = (const float*)d_in[16];
    const float* W_out    = (const float*)d_in[17];
    const float* b_out    = (const float*)d_in[18];

    float* pred     = (float*)d_out;                          // (B,L,V)
    float* alph_out = pred + (size_t)B_ * L_ * V_;            // (B,L,R)

    char* p = (char*)d_ws;
    auto alloc = [&](size_t bytes) { char* q = p; p += (bytes + 255) & ~(size_t)255; return q; };

    ush*   fpb    = (ush*)  alloc((size_t)B_ * R_ * A_ * 2);
    ush*   eh     = (ush*)  alloc((size_t)B_ * L_ * E_ * 2);
    ush*   el     = (ush*)  alloc((size_t)B_ * L_ * E_ * 2);
    ush*   mh     = (ush*)  alloc((size_t)B_ * F_ * 2);
    ush*   ml     = (ush*)  alloc((size_t)B_ * F_ * 2);
    ush*   fbh    = (ush*)  alloc((size_t)B_ * R_ * F_ * 2);
    ush*   wfp_h  = (ush*)  alloc((size_t)A_ * F_ * 2);
    ush*   wiH    = (ush*)  alloc((size_t)1024 * F_ * 2);
    ush*   wiL    = (ush*)  alloc((size_t)1024 * F_ * 2);
    ush*   wxh    = (ush*)  alloc((size_t)2048 * E_ * 2);
    ush*   wxl    = (ush*)  alloc((size_t)2048 * E_ * 2);
    ush*   wg2h   = (ush*)  alloc((size_t)2048 * (F_ + H_) * 2);
    ush*   wg2l   = (ush*)  alloc((size_t)2048 * (F_ + H_) * 2);
    ush*   woh    = (ush*)  alloc((size_t)V_ * H_ * 2);
    ush*   wol    = (ush*)  alloc((size_t)V_ * H_ * 2);
    ush*   whpT   = (ush*)  alloc((size_t)H_ * A_ * 2);
    float* egates = (float*)alloc((size_t)B_ * L_ * 2048 * 4);
    float* h0f    = (float*)alloc((size_t)B_ * H_ * 4);
    float* c2     = (float*)alloc((size_t)2 * B_ * H_ * 4);   // double-buffered c
    ush*   h_hi   = (ush*)  alloc((size_t)B_ * H_ * 2);
    ush*   h_lo   = (ush*)  alloc((size_t)B_ * H_ * 2);
    ush*   hallh  = (ush*)  alloc((size_t)L_ * B_ * H_ * 2);
    ush*   halll  = (ush*)  alloc((size_t)L_ * B_ * H_ * 2);
    ush*   ctx_hi = (ush*)  alloc((size_t)B_ * F_ * 2);
    float* gparts = (float*)alloc((size_t)8 * B_ * 2048 * 4);
    float* initp  = (float*)alloc((size_t)8 * B_ * 1024 * 4);

    // ---- one-time prep ----
    prep_feats<<<dim3(4, B_), 256, 0, stream>>>(feats, fbh, mh, ml);
    gather_split<<<768, 256, 0, stream>>>(emb, cap, eh, el);
    split_kernel<<<2048, 256, 0, stream>>>(W_out, woh, wol, V_ * H_ / 4);
    split_kernel<<<512, 256, 0, stream>>>(W_init_h, wiH, wiL, H_ * F_ / 4);
    split_kernel<<<512, 256, 0, stream>>>(W_init_c, wiH + (size_t)512 * F_,
                                          wiL + (size_t)512 * F_, H_ * F_ / 4);
    split_kernel<<<512, 256, 0, stream>>>(W_featp, wfp_h, nullptr, A_ * F_ / 4);
    prep_wih<<<2048, 256, 0, stream>>>(W_ih, W_hh, wxh, wxl, wg2h, wg2l);
    transpose512<<<1024, 256, 0, stream>>>(W_hidp, whpT);

    // h0/c0 init: M=64, N=1024 (stacked), K=2048, split-K=8 (full accuracy)
    gemm_gates<3><<<dim3(16, 1, 8), 256, 0, stream>>>(
        mh, ml, F_, F_,
        mh, ml, F_,
        wiH, wiL, F_,
        initp, 1024, (long)B_ * 1024, F_ / 8);
    init_reduce<<<256, 256, 0, stream>>>(initp, b_init_h, b_init_c, h0f, c2, h_hi, h_lo);

    // feat_proj (SPLIT=1, bf16 out, NF=1): 64x64 tiles -> grid(196,8)=1568
    gemm_big<1, 1, true, 1><<<dim3(196, 8), 256, 0, stream>>>(
        fbh, nullptr, F_, wfp_h, nullptr, F_, b_featp, fpb, A_, A_, F_);

    // emb gate part for ALL steps (SPLIT=3, NF=2): grid(24,16)=384
    gemm_big<3, 0, false, 2><<<dim3(24, 16), 256, 0, stream>>>(
        eh, el, E_, wxh, wxl, E_, nullptr, egates, 2048, 2048, E_);

    // ---- sequential decode: 2 kernels per step ----
    for (int t = 0; t < L_; ++t) {
        step2_kernel<true><<<dim3(4, B_), 512, 0, stream>>>(
            gparts, egates, b_ih, b_hh, c2, h0f, h_hi, h_lo, hallh, halll,
            whpT, b_hidp, fpb, W_score, b_score, fbh, ctx_hi,
            alph_out, t);

        // gates: [ctx | h] @ wg2^T, K=2560, split-K=8; AMODE=2 (A hi only)
        gemm_gates<2><<<dim3(32, 1, 8), 256, 0, stream>>>(
            ctx_hi, nullptr, F_, F_,
            h_hi, nullptr, H_,
            wg2h, wg2l, F_ + H_,
            gparts, 4 * H_, (long)B_ * 4 * H_, (F_ + H_) / 8);
    }

    // final cell: h_L -> hall[L-1]
    step2_kernel<false><<<dim3(1, B_), 512, 0, stream>>>(
        gparts, egates, b_ih, b_hh, c2, h0f, h_hi, h_lo, hallh, halll,
        whpT, b_hidp, fpb, W_score, b_score, fbh, ctx_hi,
        alph_out, L_);

    // predictions for ALL steps (SPLIT=3): M=1536 -> 12 tiles of 128, N=12000
    gemm_big128<3, 2, false><<<dim3(12, 47), 512, 0, stream>>>(
        hallh, halll, H_, woh, wol, H_, b_out, pred, 0, V_, H_);
}

// Round 15
// 1919.673 us; speedup vs baseline: 1.7755x; 1.0072x over previous
//
#include <hip/hip_runtime.h>

#define B_ 64
#define R_ 196
#define F_ 2048
#define E_ 512
#define H_ 512
#define A_ 512
#define V_ 12000
#define L_ 24

typedef __attribute__((ext_vector_type(8))) short bf16x8;
typedef __attribute__((ext_vector_type(4))) float f32x4;
typedef unsigned short ush;

__device__ __forceinline__ float fast_tanh(float x) {
    float t = __expf(2.f * x);
    return 1.f - 2.f / (t + 1.f);
}
__device__ __forceinline__ float fast_sig(float x) {
    return 1.f / (1.f + __expf(-x));
}
__device__ __forceinline__ ush f2bf(float x) {
    unsigned int u = __float_as_uint(x);
    return (ush)((u + 0x7fffu + ((u >> 16) & 1u)) >> 16);
}
__device__ __forceinline__ float bf2f(ush b) {
    return __uint_as_float(((unsigned int)b) << 16);
}

#define LROW 40   // LDS row stride (32 k-elems + 8 pad)

// ---------------------------------------------------------------------------
// gemm_big128: C = A @ W^T (+bias). Tile 128M x 256N, BK=32, 512 threads.
// SPLIT=3: (Ahi,Alo)x(Whi,Wlo) 3 MFMAs. SPLIT=2: Ahi x (Whi,Wlo) 2 MFMAs
// (A-lo dropped -- r14 showed recurrent/output paths absorb it). SPLIT=1: hi.
// CMAP=2: pred layout C[(m&63)*L*V + (m>>6)*V + n], fp32 NT stores.
// ---------------------------------------------------------------------------
template<int SPLIT, int CMAP, bool NFAST>
__global__ __launch_bounds__(512) void gemm_big128(
    const ush* __restrict__ Ah, const ush* __restrict__ Al, int lda,
    const ush* __restrict__ Wh, const ush* __restrict__ Wl, int ldw,
    const float* __restrict__ bias, void* __restrict__ Cv,
    int ldc, int N, int K)
{
    // layout: sAh[10240] | sBh[20480] | sBl[20480 if SPLIT>=2] | sAl[10240 if SPLIT==3]
    constexpr int SMEM_BYTES = (SPLIT == 3) ? 61440 : (SPLIT == 2 ? 51200 : 30720);
    __shared__ __align__(16) char smem[SMEM_BYTES];
    ush* sAh = (ush*)smem;
    ush* sBh = (ush*)(smem + 10240);
    ush* sBl = (ush*)(smem + 30720);
    ush* sAl = (ush*)(smem + 51200);

    const int tid = threadIdx.x;
    const int lane = tid & 63, w = tid >> 6;
    const int mw = w >> 2, nw = w & 3;

    const int nbx = gridDim.x, nby = gridDim.y;
    const int nwg = nbx * nby;
    const int orig = blockIdx.x + nbx * blockIdx.y;
    const int q = nwg >> 3, r = nwg & 7;
    const int xcd = orig & 7, idx = orig >> 3;
    const int lin = (xcd < r ? xcd * (q + 1) : r * (q + 1) + (xcd - r) * q) + idx;
    int bx, by;
    if constexpr (NFAST) { by = lin % nby; bx = lin / nby; }
    else                 { bx = lin % nbx; by = lin / nbx; }
    const int mtile = bx * 128;
    const int ntile = by * 256;

    const int fr = lane & 15, kg = (lane >> 4) * 8;
    const int arow = tid >> 2, aq = (tid & 3) * 8;

    f32x4 acc[4][4];
    #pragma unroll
    for (int mf = 0; mf < 4; ++mf)
        #pragma unroll
        for (int nf = 0; nf < 4; ++nf) acc[mf][nf] = {0.f, 0.f, 0.f, 0.f};

    const uint4 zv = make_uint4(0u, 0u, 0u, 0u);

    for (int kb = 0; kb < K; kb += 32) {
        uint4 a_h = *(const uint4*)(Ah + (size_t)(mtile + arow) * lda + kb + aq);
        uint4 a_l;
        uint4 b_h[2], b_l[2];
        #pragma unroll
        for (int p = 0; p < 2; ++p) {
            const int row = ntile + arow + 128 * p;
            b_h[p] = (row < N) ? *(const uint4*)(Wh + (size_t)row * ldw + kb + aq) : zv;
        }
        if constexpr (SPLIT >= 2) {
            #pragma unroll
            for (int p = 0; p < 2; ++p) {
                const int row = ntile + arow + 128 * p;
                b_l[p] = (row < N) ? *(const uint4*)(Wl + (size_t)row * ldw + kb + aq) : zv;
            }
        }
        if constexpr (SPLIT == 3)
            a_l = *(const uint4*)(Al + (size_t)(mtile + arow) * lda + kb + aq);

        __syncthreads();
        *(uint4*)(sAh + arow * LROW + aq) = a_h;
        #pragma unroll
        for (int p = 0; p < 2; ++p)
            *(uint4*)(sBh + (arow + 128 * p) * LROW + aq) = b_h[p];
        if constexpr (SPLIT >= 2) {
            #pragma unroll
            for (int p = 0; p < 2; ++p)
                *(uint4*)(sBl + (arow + 128 * p) * LROW + aq) = b_l[p];
        }
        if constexpr (SPLIT == 3)
            *(uint4*)(sAl + arow * LROW + aq) = a_l;
        __syncthreads();

        bf16x8 bh[4], bl[4];
        #pragma unroll
        for (int nf = 0; nf < 4; ++nf) {
            bh[nf] = *(const bf16x8*)(sBh + (nw * 64 + nf * 16 + fr) * LROW + kg);
            if constexpr (SPLIT >= 2)
                bl[nf] = *(const bf16x8*)(sBl + (nw * 64 + nf * 16 + fr) * LROW + kg);
        }
        #pragma unroll
        for (int mf = 0; mf < 4; ++mf) {
            const bf16x8 ah = *(const bf16x8*)(sAh + (mw * 64 + mf * 16 + fr) * LROW + kg);
            #pragma unroll
            for (int nf = 0; nf < 4; ++nf) {
                acc[mf][nf] = __builtin_amdgcn_mfma_f32_16x16x32_bf16(ah, bh[nf], acc[mf][nf], 0, 0, 0);
                if constexpr (SPLIT >= 2)
                    acc[mf][nf] = __builtin_amdgcn_mfma_f32_16x16x32_bf16(ah, bl[nf], acc[mf][nf], 0, 0, 0);
            }
            if constexpr (SPLIT == 3) {
                const bf16x8 al = *(const bf16x8*)(sAl + (mw * 64 + mf * 16 + fr) * LROW + kg);
                #pragma unroll
                for (int nf = 0; nf < 4; ++nf)
                    acc[mf][nf] = __builtin_amdgcn_mfma_f32_16x16x32_bf16(al, bh[nf], acc[mf][nf], 0, 0, 0);
            }
        }
    }

    #pragma unroll
    for (int nf = 0; nf < 4; ++nf) {
        const int nn = ntile + nw * 64 + nf * 16 + fr;
        if (nn < N) {
            const float bv = bias ? bias[nn] : 0.f;
            #pragma unroll
            for (int mf = 0; mf < 4; ++mf) {
                #pragma unroll
                for (int rr = 0; rr < 4; ++rr) {
                    const int m = mtile + mw * 64 + mf * 16 + (lane >> 4) * 4 + rr;
                    const float v = acc[mf][nf][rr] + bv;
                    if constexpr (CMAP == 1)
                        ((ush*)Cv)[(size_t)m * ldc + nn] = f2bf(v);
                    else if constexpr (CMAP == 2) {
                        float* dst = (float*)Cv + (size_t)(m & 63) * (L_ * V_)
                                   + (size_t)(m >> 6) * V_ + nn;
                        __builtin_nontemporal_store(v, dst);
                    } else
                        ((float*)Cv)[(size_t)m * ldc + nn] = v;
                }
            }
        }
    }
}

// ---------------------------------------------------------------------------
// gemm_big: 64M x (64*NF)N tile, 256 threads. NF=1 -> 64x64 (max blocks).
// ---------------------------------------------------------------------------
template<int SPLIT, int CMAP, bool NFAST, int NF>
__global__ __launch_bounds__(256) void gemm_big(
    const ush* __restrict__ Ah, const ush* __restrict__ Al, int lda,
    const ush* __restrict__ Wh, const ush* __restrict__ Wl, int ldw,
    const float* __restrict__ bias, void* __restrict__ Cv,
    int ldc, int N, int K)
{
    constexpr int ABYTES = 64 * LROW * 2;
    constexpr int BBYTES = 64 * NF * LROW * 2;
    constexpr int SMEM_BYTES = (SPLIT == 3) ? 2 * (ABYTES + BBYTES) : (ABYTES + BBYTES);
    __shared__ __align__(16) char smem[SMEM_BYTES];
    ush* sAh = (ush*)smem;
    ush* sBh = (ush*)(smem + ABYTES);
    ush* sAl = (ush*)(smem + ABYTES + BBYTES);
    ush* sBl = (ush*)(smem + 2 * ABYTES + BBYTES);

    const int tid = threadIdx.x;
    const int lane = tid & 63, w = tid >> 6;

    const int nbx = gridDim.x, nby = gridDim.y;
    const int nwg = nbx * nby;
    int lin = blockIdx.x + nbx * blockIdx.y;
    if ((nwg & 7) == 0) {
        const int q = nwg >> 3;
        lin = (lin & 7) * q + (lin >> 3);
    }
    int bx, by;
    if constexpr (NFAST) { by = lin % nby; bx = lin / nby; }
    else                 { bx = lin % nbx; by = lin / nbx; }
    const int mtile = bx * 64;
    const int ntile = by * (64 * NF);

    const int fr = lane & 15, kg = (lane >> 4) * 8;
    const int arow = tid >> 2, aq = (tid & 3) * 8;

    f32x4 acc[4][NF];
    #pragma unroll
    for (int mf = 0; mf < 4; ++mf)
        #pragma unroll
        for (int nf = 0; nf < NF; ++nf) acc[mf][nf] = {0.f, 0.f, 0.f, 0.f};

    const uint4 zv = make_uint4(0u, 0u, 0u, 0u);

    for (int kb = 0; kb < K; kb += 32) {
        uint4 a_h = *(const uint4*)(Ah + (size_t)(mtile + arow) * lda + kb + aq);
        uint4 a_l;
        uint4 b_h[NF], b_l[NF];
        #pragma unroll
        for (int p = 0; p < NF; ++p) {
            const int row = ntile + arow + 64 * p;
            b_h[p] = (row < N) ? *(const uint4*)(Wh + (size_t)row * ldw + kb + aq) : zv;
        }
        if constexpr (SPLIT == 3) {
            a_l = *(const uint4*)(Al + (size_t)(mtile + arow) * lda + kb + aq);
            #pragma unroll
            for (int p = 0; p < NF; ++p) {
                const int row = ntile + arow + 64 * p;
                b_l[p] = (row < N) ? *(const uint4*)(Wl + (size_t)row * ldw + kb + aq) : zv;
            }
        }

        __syncthreads();
        *(uint4*)(sAh + arow * LROW + aq) = a_h;
        #pragma unroll
        for (int p = 0; p < NF; ++p)
            *(uint4*)(sBh + (arow + 64 * p) * LROW + aq) = b_h[p];
        if constexpr (SPLIT == 3) {
            *(uint4*)(sAl + arow * LROW + aq) = a_l;
            #pragma unroll
            for (int p = 0; p < NF; ++p)
                *(uint4*)(sBl + (arow + 64 * p) * LROW + aq) = b_l[p];
        }
        __syncthreads();

        bf16x8 bh[NF], bl[NF];
        #pragma unroll
        for (int nf = 0; nf < NF; ++nf) {
            bh[nf] = *(const bf16x8*)(sBh + (w * (16 * NF) + nf * 16 + fr) * LROW + kg);
            if constexpr (SPLIT == 3)
                bl[nf] = *(const bf16x8*)(sBl + (w * (16 * NF) + nf * 16 + fr) * LROW + kg);
        }
        #pragma unroll
        for (int mf = 0; mf < 4; ++mf) {
            const bf16x8 ah = *(const bf16x8*)(sAh + (mf * 16 + fr) * LROW + kg);
            if constexpr (SPLIT == 3) {
                const bf16x8 al = *(const bf16x8*)(sAl + (mf * 16 + fr) * LROW + kg);
                #pragma unroll
                for (int nf = 0; nf < NF; ++nf) {
                    acc[mf][nf] = __builtin_amdgcn_mfma_f32_16x16x32_bf16(ah, bh[nf], acc[mf][nf], 0, 0, 0);
                    acc[mf][nf] = __builtin_amdgcn_mfma_f32_16x16x32_bf16(ah, bl[nf], acc[mf][nf], 0, 0, 0);
                    acc[mf][nf] = __builtin_amdgcn_mfma_f32_16x16x32_bf16(al, bh[nf], acc[mf][nf], 0, 0, 0);
                }
            } else {
                #pragma unroll
                for (int nf = 0; nf < NF; ++nf)
                    acc[mf][nf] = __builtin_amdgcn_mfma_f32_16x16x32_bf16(ah, bh[nf], acc[mf][nf], 0, 0, 0);
            }
        }
    }

    #pragma unroll
    for (int nf = 0; nf < NF; ++nf) {
        const int nn = ntile + w * (16 * NF) + nf * 16 + fr;
        if (nn < N) {
            const float bv = bias ? bias[nn] : 0.f;
            #pragma unroll
            for (int mf = 0; mf < 4; ++mf) {
                #pragma unroll
                for (int rr = 0; rr < 4; ++rr) {
                    const int m = mtile + mf * 16 + (lane >> 4) * 4 + rr;
                    const float v = acc[mf][nf][rr] + bv;
                    if constexpr (CMAP == 1)
                        ((ush*)Cv)[(size_t)m * ldc + nn] = f2bf(v);
                    else
                        ((float*)Cv)[(size_t)m * ldc + nn] = v;
                }
            }
        }
    }
}

// ---------------------------------------------------------------------------
// gemm_gates<AMODE>: 64x64 tile, segmented A (2 segments), split-K via grid.z.
// AMODE=3: full bf16x2 (3 MFMAs). AMODE=2: drop A-lo term (2 MFMAs).
// ---------------------------------------------------------------------------
template<int AMODE>
__global__ __launch_bounds__(256) void gemm_gates(
    const ush* __restrict__ Ah0, const ush* __restrict__ Al0, int lda0, int k0,
    const ush* __restrict__ Ah1, const ush* __restrict__ Al1, int lda1,
    const ush* __restrict__ Wh, const ush* __restrict__ Wl, int ldw,
    float* __restrict__ C, int ldc, long zstride, int kChunk)
{
    __shared__ ush sAh[64 * LROW];
    __shared__ ush sBh[64 * LROW];
    __shared__ ush sAl[64 * LROW];
    __shared__ ush sBl[64 * LROW];

    const int tid = threadIdx.x;
    const int ntile = blockIdx.x * 64;
    const int kStart = blockIdx.z * kChunk;
    const int lane = tid & 63, w = tid >> 6;
    const int lrow = tid >> 2;
    const int lcol = (tid & 3) * 8;
    const int nrow = ntile + lrow;

    f32x4 acc[4];
    #pragma unroll
    for (int f = 0; f < 4; ++f) acc[f] = {0.f, 0.f, 0.f, 0.f};

    const int fr = lane & 15;
    const int kg = (lane >> 4) * 8;

    for (int kb = kStart; kb < kStart + kChunk; kb += 32) {
        const ush *ph, *pl; int lda, loc;
        if (kb < k0) { ph = Ah0; pl = Al0; lda = lda0; loc = kb; }
        else         { ph = Ah1; pl = Al1; lda = lda1; loc = kb - k0; }

        uint4 a_h = *(const uint4*)(ph + (size_t)lrow * lda + loc + lcol);
        uint4 b_h = *(const uint4*)(Wh + (size_t)nrow * ldw + kb + lcol);
        uint4 b_l = *(const uint4*)(Wl + (size_t)nrow * ldw + kb + lcol);
        uint4 a_l;
        if constexpr (AMODE == 3)
            a_l = *(const uint4*)(pl + (size_t)lrow * lda + loc + lcol);

        __syncthreads();
        *(uint4*)(sAh + lrow * LROW + lcol) = a_h;
        *(uint4*)(sBh + lrow * LROW + lcol) = b_h;
        *(uint4*)(sBl + lrow * LROW + lcol) = b_l;
        if constexpr (AMODE == 3)
            *(uint4*)(sAl + lrow * LROW + lcol) = a_l;
        __syncthreads();

        const bf16x8 bh = *(const bf16x8*)(sBh + (16 * w + fr) * LROW + kg);
        const bf16x8 bl = *(const bf16x8*)(sBl + (16 * w + fr) * LROW + kg);

        #pragma unroll
        for (int f = 0; f < 4; ++f) {
            const bf16x8 ah = *(const bf16x8*)(sAh + (16 * f + fr) * LROW + kg);
            acc[f] = __builtin_amdgcn_mfma_f32_16x16x32_bf16(ah, bh, acc[f], 0, 0, 0);
            acc[f] = __builtin_amdgcn_mfma_f32_16x16x32_bf16(ah, bl, acc[f], 0, 0, 0);
            if constexpr (AMODE == 3) {
                const bf16x8 al = *(const bf16x8*)(sAl + (16 * f + fr) * LROW + kg);
                acc[f] = __builtin_amdgcn_mfma_f32_16x16x32_bf16(al, bh, acc[f], 0, 0, 0);
            }
        }
    }

    const int n = ntile + 16 * w + (lane & 15);
    float* Cz = C + (size_t)blockIdx.z * zstride;
    #pragma unroll
    for (int f = 0; f < 4; ++f)
        #pragma unroll
        for (int rr = 0; rr < 4; ++rr) {
            const int m = 16 * f + (lane >> 4) * 4 + rr;
            Cz[(size_t)m * ldc + n] = acc[f][rr];
        }
}

// fused feats pass: fbh (bf16) + per-(b,f) mean -> mh/ml. block (fs, b).
__global__ __launch_bounds__(256) void prep_feats(
    const float* __restrict__ feats, ush* __restrict__ fbh,
    ush* __restrict__ mh, ush* __restrict__ ml)
{
    const int fs = blockIdx.x;
    const int b  = blockIdx.y;
    const int f = fs * 512 + threadIdx.x * 2;
    const float2* fp = (const float2*)(feats + (size_t)b * R_ * F_ + f);
    ush* fo = fbh + (size_t)b * R_ * F_ + f;
    float sx = 0.f, sy = 0.f;
    for (int r = 0; r < R_; ++r) {
        const float2 v = fp[(size_t)r * (F_ / 2)];
        sx += v.x; sy += v.y;
        ushort2 u; u.x = f2bf(v.x); u.y = f2bf(v.y);
        *(ushort2*)(fo + (size_t)r * F_) = u;
    }
    const float s = 1.f / (float)R_;
    sx *= s; sy *= s;
    const size_t mi = (size_t)b * F_ + f;
    const ush hx = f2bf(sx); mh[mi] = hx;     ml[mi] = f2bf(sx - bf2f(hx));
    const ush hy = f2bf(sy); mh[mi + 1] = hy; ml[mi + 1] = f2bf(sy - bf2f(hy));
}

// gather embeddings -> bf16 hi/lo (B,L,E)
__global__ __launch_bounds__(256) void gather_split(
    const float* __restrict__ emb, const int* __restrict__ cap,
    ush* __restrict__ eh, ush* __restrict__ el)
{
    const int idx = blockIdx.x * 256 + threadIdx.x;
    const int bt = idx >> 7, j = idx & 127;
    const int tok = cap[bt];
    const float4 v = reinterpret_cast<const float4*>(emb)[(size_t)tok * (E_ / 4) + j];
    const float a[4] = {v.x, v.y, v.z, v.w};
    #pragma unroll
    for (int c = 0; c < 4; ++c) {
        const ush hi = f2bf(a[c]);
        eh[idx * 4 + c] = hi;
        el[idx * 4 + c] = f2bf(a[c] - bf2f(hi));
    }
}

// fused weight-prep: one grid covers W_out, W_init_h, W_init_c (hi+lo) and
// W_featp (hi only). Segments by flat float4 index.
__global__ __launch_bounds__(256) void prep_weights(
    const float* __restrict__ W_out, const float* __restrict__ W_init_h,
    const float* __restrict__ W_init_c, const float* __restrict__ W_featp,
    ush* __restrict__ woh, ush* __restrict__ wol,
    ush* __restrict__ wiH, ush* __restrict__ wiL,
    ush* __restrict__ wfp_h)
{
    const int NWO = V_ * H_ / 4;            // 1536000
    const int NWI = H_ * F_ / 4;            // 262144
    const int NFP = A_ * F_ / 4;            // 262144
    const int total = NWO + 2 * NWI + NFP;
    for (int i = blockIdx.x * 256 + threadIdx.x; i < total; i += gridDim.x * 256) {
        const float* src; ush* dh; ush* dl; int j;
        if (i < NWO)                 { src = W_out;    dh = woh;  dl = wol;  j = i; }
        else if (i < NWO + NWI)      { src = W_init_h; dh = wiH;  dl = wiL;  j = i - NWO; }
        else if (i < NWO + 2 * NWI)  { src = W_init_c; dh = wiH + (size_t)512 * F_;
                                       dl = wiL + (size_t)512 * F_; j = i - NWO - NWI; }
        else                         { src = W_featp;  dh = wfp_h; dl = nullptr; j = i - NWO - 2 * NWI; }
        const float4 v = reinterpret_cast<const float4*>(src)[j];
        const float a[4] = {v.x, v.y, v.z, v.w};
        #pragma unroll
        for (int c = 0; c < 4; ++c) {
            const ush h = f2bf(a[c]);
            dh[j * 4 + c] = h;
            if (dl) dl[j * 4 + c] = f2bf(a[c] - bf2f(h));
        }
    }
}

// W_ih columns [0:E) -> wx (2048x512); [E:) ++ W_hh -> wg2 (2048x2560); hi/lo
__global__ __launch_bounds__(256) void prep_wih(
    const float* __restrict__ W_ih, const float* __restrict__ W_hh,
    ush* __restrict__ wxh, ush* __restrict__ wxl,
    ush* __restrict__ wg2h, ush* __restrict__ wg2l)
{
    const int nrow = blockIdx.x;
    for (int k = threadIdx.x; k < E_; k += 256) {
        const float v = W_ih[(size_t)nrow * (E_ + F_) + k];
        const ush h = f2bf(v);
        wxh[(size_t)nrow * E_ + k] = h;
        wxl[(size_t)nrow * E_ + k] = f2bf(v - bf2f(h));
    }
    for (int k = threadIdx.x; k < F_ + H_; k += 256) {
        const float v = (k < F_) ? W_ih[(size_t)nrow * (E_ + F_) + E_ + k]
                                 : W_hh[(size_t)nrow * H_ + (k - F_)];
        const ush h = f2bf(v);
        wg2h[(size_t)nrow * (F_ + H_) + k] = h;
        wg2l[(size_t)nrow * (F_ + H_) + k] = f2bf(v - bf2f(h));
    }
}

// transpose W_hidp (A x H) -> whpT (H x A), bf16
__global__ __launch_bounds__(256) void transpose512(
    const float* __restrict__ in, ush* __restrict__ out)
{
    const int idx = blockIdx.x * 256 + threadIdx.x;
    const int k = idx >> 9, a = idx & 511;
    out[idx] = f2bf(in[(size_t)a * 512 + k]);
}

// reduce init GEMM partials: n<512 -> h0 (+split), n>=512 -> c0 (buffer 0)
__global__ __launch_bounds__(256) void init_reduce(
    const float* __restrict__ initp, const float* __restrict__ b_init_h,
    const float* __restrict__ b_init_c, float* __restrict__ h0f,
    float* __restrict__ c0, ush* __restrict__ h_hi, ush* __restrict__ h_lo)
{
    const int idx = blockIdx.x * 256 + threadIdx.x;
    const int b = idx >> 10, n = idx & 1023;
    float s = 0.f;
    #pragma unroll
    for (int z = 0; z < 8; ++z)
        s += initp[(size_t)z * (B_ * 1024) + (size_t)b * 1024 + n];
    if (n < 512) {
        s += b_init_h[n];
        h0f[b * H_ + n] = s;
        const ush hi = f2bf(s);
        h_hi[b * H_ + n] = hi;
        h_lo[b * H_ + n] = f2bf(s - bf2f(hi));
    } else {
        s += b_init_c[n - 512];
        c0[b * H_ + (n - 512)] = s;
    }
}

// ---------------------------------------------------------------------------
// step2_kernel<ATT>: grid (4, B) when ATT (fs = f-quarter), (1, B) else.
// ---------------------------------------------------------------------------
template<bool ATT>
__global__ __launch_bounds__(512) void step2_kernel(
    const float* __restrict__ gparts, const float* __restrict__ egates,
    const float* __restrict__ b_ih, const float* __restrict__ b_hh,
    float* __restrict__ c2, const float* __restrict__ h0f,
    ush* __restrict__ h_hi, ush* __restrict__ h_lo,
    ush* __restrict__ hall_hi, ush* __restrict__ hall_lo,
    const ush* __restrict__ whpT, const float* __restrict__ b_hidp,
    const ush* __restrict__ fpb, const float* __restrict__ W_score,
    const float* __restrict__ b_score, const ush* __restrict__ fbh,
    ush* __restrict__ ctx_hi,
    float* __restrict__ alph_out, int t)
{
    __shared__ float sh_h[H_];
    __shared__ float sh_hp[A_];
    __shared__ float sh_ws[A_];
    __shared__ float sh_sc[200];
    __shared__ float red[2];
    const int tid = threadIdx.x;
    const int fs = blockIdx.x;
    const int b = blockIdx.y;
    const int n = tid;

    float hh;
    if (t > 0) {
        const float* c_old = c2 + (size_t)((t - 1) & 1) * B_ * H_;
        float* c_new = c2 + (size_t)(t & 1) * B_ * H_;
        const float* eg = egates + ((size_t)b * L_ + (t - 1)) * 2048;
        float gi = b_ih[n] + b_hh[n] + eg[n];
        float gf = b_ih[n + 512] + b_hh[n + 512] + eg[n + 512];
        float gg = b_ih[n + 1024] + b_hh[n + 1024] + eg[n + 1024];
        float go = b_ih[n + 1536] + b_hh[n + 1536] + eg[n + 1536];
        #pragma unroll
        for (int z = 0; z < 8; ++z) {
            const float* gz = gparts + (size_t)z * B_ * 2048 + (size_t)b * 2048;
            gi += gz[n]; gf += gz[n + 512]; gg += gz[n + 1024]; go += gz[n + 1536];
        }
        const float cc = fast_sig(gf) * c_old[b * H_ + n] + fast_sig(gi) * fast_tanh(gg);
        hh = fast_sig(go) * fast_tanh(cc);
        if (fs == 0) {
            c_new[b * H_ + n] = cc;
            const ush hi = f2bf(hh);
            const ush lo = f2bf(hh - bf2f(hi));
            h_hi[b * H_ + n] = hi;
            h_lo[b * H_ + n] = lo;
            const size_t hidx = ((size_t)(t - 1) * B_ + b) * H_ + n;
            hall_hi[hidx] = hi;
            hall_lo[hidx] = lo;
        }
    } else {
        hh = h0f[b * H_ + n];
    }
    if constexpr (!ATT) return;

    sh_h[n] = hh;
    sh_ws[n] = W_score[n];
    __syncthreads();

    // hid_proj (coalesced, bf16 whpT)
    {
        float a0 = 0.f, a1 = 0.f, a2 = 0.f, a3 = 0.f;
        #pragma unroll 4
        for (int k = 0; k < H_; k += 4) {
            a0 = fmaf(sh_h[k + 0], bf2f(whpT[(size_t)(k + 0) * A_ + tid]), a0);
            a1 = fmaf(sh_h[k + 1], bf2f(whpT[(size_t)(k + 1) * A_ + tid]), a1);
            a2 = fmaf(sh_h[k + 2], bf2f(whpT[(size_t)(k + 2) * A_ + tid]), a2);
            a3 = fmaf(sh_h[k + 3], bf2f(whpT[(size_t)(k + 3) * A_ + tid]), a3);
        }
        sh_hp[tid] = (a0 + a1) + (a2 + a3) + b_hidp[tid];
    }
    __syncthreads();

    const int lane = tid & 63, wid = tid >> 6;
    for (int r = wid; r < R_; r += 8) {
        const ushort2* row = reinterpret_cast<const ushort2*>(fpb + ((size_t)b * R_ + r) * A_);
        float acc = 0.f;
        #pragma unroll
        for (int j = 0; j < 4; ++j) {
            const ushort2 u = row[lane + 64 * j];
            const int a = 2 * (lane + 64 * j);
            acc += fast_tanh(bf2f(u.x) + sh_hp[a]) * sh_ws[a];
            acc += fast_tanh(bf2f(u.y) + sh_hp[a + 1]) * sh_ws[a + 1];
        }
        for (int off = 32; off > 0; off >>= 1) acc += __shfl_down(acc, off);
        if (lane == 0) sh_sc[r] = acc + b_score[0];
    }
    __syncthreads();

    if (tid < 64) {
        float m = -1e30f;
        for (int r = tid; r < R_; r += 64) m = fmaxf(m, sh_sc[r]);
        for (int off = 32; off > 0; off >>= 1) m = fmaxf(m, __shfl_xor(m, off));
        float s = 0.f;
        for (int r = tid; r < R_; r += 64) s += __expf(sh_sc[r] - m);
        for (int off = 32; off > 0; off >>= 1) s += __shfl_xor(s, off);
        if (tid == 0) { red[0] = m; red[1] = 1.f / s; }
    }
    __syncthreads();
    const float m = red[0], is = red[1];
    if (tid < R_) {
        const float av = __expf(sh_sc[tid] - m) * is;
        sh_sc[tid] = av;
        if (fs == 0) alph_out[((size_t)b * L_ + t) * R_ + tid] = av;
    }
    __syncthreads();

    // ---- ctx quarter: f = fs*512 + tid, sum over 196 regions (bf16 fbh) ----
    {
        const int f0 = fs * 512 + tid;
        const ush* fp2 = fbh + (size_t)b * R_ * F_ + f0;
        float cx = 0.f;
        #pragma unroll 4
        for (int r = 0; r < R_; ++r)
            cx = fmaf(sh_sc[r], bf2f(fp2[(size_t)r * F_]), cx);
        ctx_hi[(size_t)b * F_ + f0] = f2bf(cx);
    }
}

extern "C" void kernel_launch(void* const* d_in, const int* in_sizes, int n_in,
                              void* d_out, int out_size, void* d_ws, size_t ws_size,
                              hipStream_t stream)
{
    const float* feats    = (const float*)d_in[0];
    const int*   cap      = (const int*)  d_in[1];
    const float* emb      = (const float*)d_in[2];
    const float* W_init_h = (const float*)d_in[3];
    const float* b_init_h = (const float*)d_in[4];
    const float* W_init_c = (const float*)d_in[5];
    const float* b_init_c = (const float*)d_in[6];
    const float* W_ih     = (const float*)d_in[7];
    const float* b_ih     = (const float*)d_in[8];
    const float* W_hh     = (const float*)d_in[9];
    const float* b_hh     = (const float*)d_in[10];
    const float* W_featp  = (const float*)d_in[11];
    const float* b_featp  = (const float*)d_in[12];
    const float* W_hidp   = (const float*)d_in[13];
    const float* b_hidp   = (const float*)d_in[14];
    const float* W_score  = (const float*)d_in[15];
    const float* b_score  = (const float*)d_in[16];
    const float* W_out    = (const float*)d_in[17];
    const float* b_out    = (const float*)d_in[18];

    float* pred     = (float*)d_out;                          // (B,L,V)
    float* alph_out = pred + (size_t)B_ * L_ * V_;            // (B,L,R)

    char* p = (char*)d_ws;
    auto alloc = [&](size_t bytes) { char* q = p; p += (bytes + 255) & ~(size_t)255; return q; };

    ush*   fpb    = (ush*)  alloc((size_t)B_ * R_ * A_ * 2);
    ush*   eh     = (ush*)  alloc((size_t)B_ * L_ * E_ * 2);
    ush*   el     = (ush*)  alloc((size_t)B_ * L_ * E_ * 2);
    ush*   mh     = (ush*)  alloc((size_t)B_ * F_ * 2);
    ush*   ml     = (ush*)  alloc((size_t)B_ * F_ * 2);
    ush*   fbh    = (ush*)  alloc((size_t)B_ * R_ * F_ * 2);
    ush*   wfp_h  = (ush*)  alloc((size_t)A_ * F_ * 2);
    ush*   wiH    = (ush*)  alloc((size_t)1024 * F_ * 2);
    ush*   wiL    = (ush*)  alloc((size_t)1024 * F_ * 2);
    ush*   wxh    = (ush*)  alloc((size_t)2048 * E_ * 2);
    ush*   wxl    = (ush*)  alloc((size_t)2048 * E_ * 2);
    ush*   wg2h   = (ush*)  alloc((size_t)2048 * (F_ + H_) * 2);
    ush*   wg2l   = (ush*)  alloc((size_t)2048 * (F_ + H_) * 2);
    ush*   woh    = (ush*)  alloc((size_t)V_ * H_ * 2);
    ush*   wol    = (ush*)  alloc((size_t)V_ * H_ * 2);
    ush*   whpT   = (ush*)  alloc((size_t)H_ * A_ * 2);
    float* egates = (float*)alloc((size_t)B_ * L_ * 2048 * 4);
    float* h0f    = (float*)alloc((size_t)B_ * H_ * 4);
    float* c2     = (float*)alloc((size_t)2 * B_ * H_ * 4);   // double-buffered c
    ush*   h_hi   = (ush*)  alloc((size_t)B_ * H_ * 2);
    ush*   h_lo   = (ush*)  alloc((size_t)B_ * H_ * 2);
    ush*   hallh  = (ush*)  alloc((size_t)L_ * B_ * H_ * 2);
    ush*   halll  = (ush*)  alloc((size_t)L_ * B_ * H_ * 2);
    ush*   ctx_hi = (ush*)  alloc((size_t)B_ * F_ * 2);
    float* gparts = (float*)alloc((size_t)8 * B_ * 2048 * 4);
    float* initp  = (float*)alloc((size_t)8 * B_ * 1024 * 4);

    // ---- one-time prep ----
    prep_feats<<<dim3(4, B_), 256, 0, stream>>>(feats, fbh, mh, ml);
    gather_split<<<768, 256, 0, stream>>>(emb, cap, eh, el);
    prep_weights<<<2048, 256, 0, stream>>>(W_out, W_init_h, W_init_c, W_featp,
                                           woh, wol, wiH, wiL, wfp_h);
    prep_wih<<<2048, 256, 0, stream>>>(W_ih, W_hh, wxh, wxl, wg2h, wg2l);
    transpose512<<<1024, 256, 0, stream>>>(W_hidp, whpT);

    // h0/c0 init: M=64, N=1024 (stacked), K=2048, split-K=8 (full accuracy)
    gemm_gates<3><<<dim3(16, 1, 8), 256, 0, stream>>>(
        mh, ml, F_, F_,
        mh, ml, F_,
        wiH, wiL, F_,
        initp, 1024, (long)B_ * 1024, F_ / 8);
    init_reduce<<<256, 256, 0, stream>>>(initp, b_init_h, b_init_c, h0f, c2, h_hi, h_lo);

    // feat_proj (SPLIT=1, bf16 out, NF=1): 64x64 tiles -> grid(196,8)=1568
    gemm_big<1, 1, true, 1><<<dim3(196, 8), 256, 0, stream>>>(
        fbh, nullptr, F_, wfp_h, nullptr, F_, b_featp, fpb, A_, A_, F_);

    // emb gate part for ALL steps (SPLIT=3, NF=2): grid(24,16)=384
    gemm_big<3, 0, false, 2><<<dim3(24, 16), 256, 0, stream>>>(
        eh, el, E_, wxh, wxl, E_, nullptr, egates, 2048, 2048, E_);

    // ---- sequential decode: 2 kernels per step ----
    for (int t = 0; t < L_; ++t) {
        step2_kernel<true><<<dim3(4, B_), 512, 0, stream>>>(
            gparts, egates, b_ih, b_hh, c2, h0f, h_hi, h_lo, hallh, halll,
            whpT, b_hidp, fpb, W_score, b_score, fbh, ctx_hi,
            alph_out, t);

        // gates: [ctx | h] @ wg2^T, K=2560, split-K=8; AMODE=2 (A hi only)
        gemm_gates<2><<<dim3(32, 1, 8), 256, 0, stream>>>(
            ctx_hi, nullptr, F_, F_,
            h_hi, nullptr, H_,
            wg2h, wg2l, F_ + H_,
            gparts, 4 * H_, (long)B_ * 4 * H_, (F_ + H_) / 8);
    }

    // final cell: h_L -> hall[L-1]
    step2_kernel<false><<<dim3(1, B_), 512, 0, stream>>>(
        gparts, egates, b_ih, b_hh, c2, h0f, h_hi, h_lo, hallh, halll,
        whpT, b_hidp, fpb, W_score, b_score, fbh, ctx_hi,
        alph_out, L_);

    // predictions (SPLIT=2: h-hi x (Wout hi+lo)): M=1536 -> 12x128 tiles
    gemm_big128<2, 2, false><<<dim3(12, 47), 512, 0, stream>>>(
        hallh, nullptr, H_, woh, wol, H_, b_out, pred, 0, V_, H_);
}

// Round 16
// 1886.865 us; speedup vs baseline: 1.8064x; 1.0174x over previous
//
#include <hip/hip_runtime.h>

#define B_ 64
#define R_ 196
#define F_ 2048
#define E_ 512
#define H_ 512
#define A_ 512
#define V_ 12000
#define L_ 24

typedef __attribute__((ext_vector_type(8))) short bf16x8;
typedef __attribute__((ext_vector_type(4))) float f32x4;
typedef unsigned short ush;

__device__ __forceinline__ float fast_tanh(float x) {
    float t = __expf(2.f * x);
    return 1.f - 2.f / (t + 1.f);
}
__device__ __forceinline__ float fast_sig(float x) {
    return 1.f / (1.f + __expf(-x));
}
__device__ __forceinline__ ush f2bf(float x) {
    unsigned int u = __float_as_uint(x);
    return (ush)((u + 0x7fffu + ((u >> 16) & 1u)) >> 16);
}
__device__ __forceinline__ float bf2f(ush b) {
    return __uint_as_float(((unsigned int)b) << 16);
}

#define LROW 40   // LDS row stride (32 k-elems + 8 pad)

// ---------------------------------------------------------------------------
// gemm_big128: C = A @ W^T (+bias). Tile 128M x 256N, BK=32, 512 threads.
// SPLIT=2: Ahi x (Whi,Wlo) 2 MFMAs (A-lo dropped). CMAP=2: pred layout, NT.
// ---------------------------------------------------------------------------
template<int SPLIT, int CMAP, bool NFAST>
__global__ __launch_bounds__(512) void gemm_big128(
    const ush* __restrict__ Ah, const ush* __restrict__ Al, int lda,
    const ush* __restrict__ Wh, const ush* __restrict__ Wl, int ldw,
    const float* __restrict__ bias, void* __restrict__ Cv,
    int ldc, int N, int K)
{
    constexpr int SMEM_BYTES = (SPLIT == 3) ? 61440 : (SPLIT == 2 ? 51200 : 30720);
    __shared__ __align__(16) char smem[SMEM_BYTES];
    ush* sAh = (ush*)smem;
    ush* sBh = (ush*)(smem + 10240);
    ush* sBl = (ush*)(smem + 30720);
    ush* sAl = (ush*)(smem + 51200);

    const int tid = threadIdx.x;
    const int lane = tid & 63, w = tid >> 6;
    const int mw = w >> 2, nw = w & 3;

    const int nbx = gridDim.x, nby = gridDim.y;
    const int nwg = nbx * nby;
    const int orig = blockIdx.x + nbx * blockIdx.y;
    const int q = nwg >> 3, r = nwg & 7;
    const int xcd = orig & 7, idx = orig >> 3;
    const int lin = (xcd < r ? xcd * (q + 1) : r * (q + 1) + (xcd - r) * q) + idx;
    int bx, by;
    if constexpr (NFAST) { by = lin % nby; bx = lin / nby; }
    else                 { bx = lin % nbx; by = lin / nbx; }
    const int mtile = bx * 128;
    const int ntile = by * 256;

    const int fr = lane & 15, kg = (lane >> 4) * 8;
    const int arow = tid >> 2, aq = (tid & 3) * 8;

    f32x4 acc[4][4];
    #pragma unroll
    for (int mf = 0; mf < 4; ++mf)
        #pragma unroll
        for (int nf = 0; nf < 4; ++nf) acc[mf][nf] = {0.f, 0.f, 0.f, 0.f};

    const uint4 zv = make_uint4(0u, 0u, 0u, 0u);

    for (int kb = 0; kb < K; kb += 32) {
        uint4 a_h = *(const uint4*)(Ah + (size_t)(mtile + arow) * lda + kb + aq);
        uint4 a_l;
        uint4 b_h[2], b_l[2];
        #pragma unroll
        for (int p = 0; p < 2; ++p) {
            const int row = ntile + arow + 128 * p;
            b_h[p] = (row < N) ? *(const uint4*)(Wh + (size_t)row * ldw + kb + aq) : zv;
        }
        if constexpr (SPLIT >= 2) {
            #pragma unroll
            for (int p = 0; p < 2; ++p) {
                const int row = ntile + arow + 128 * p;
                b_l[p] = (row < N) ? *(const uint4*)(Wl + (size_t)row * ldw + kb + aq) : zv;
            }
        }
        if constexpr (SPLIT == 3)
            a_l = *(const uint4*)(Al + (size_t)(mtile + arow) * lda + kb + aq);

        __syncthreads();
        *(uint4*)(sAh + arow * LROW + aq) = a_h;
        #pragma unroll
        for (int p = 0; p < 2; ++p)
            *(uint4*)(sBh + (arow + 128 * p) * LROW + aq) = b_h[p];
        if constexpr (SPLIT >= 2) {
            #pragma unroll
            for (int p = 0; p < 2; ++p)
                *(uint4*)(sBl + (arow + 128 * p) * LROW + aq) = b_l[p];
        }
        if constexpr (SPLIT == 3)
            *(uint4*)(sAl + arow * LROW + aq) = a_l;
        __syncthreads();

        bf16x8 bh[4], bl[4];
        #pragma unroll
        for (int nf = 0; nf < 4; ++nf) {
            bh[nf] = *(const bf16x8*)(sBh + (nw * 64 + nf * 16 + fr) * LROW + kg);
            if constexpr (SPLIT >= 2)
                bl[nf] = *(const bf16x8*)(sBl + (nw * 64 + nf * 16 + fr) * LROW + kg);
        }
        #pragma unroll
        for (int mf = 0; mf < 4; ++mf) {
            const bf16x8 ah = *(const bf16x8*)(sAh + (mw * 64 + mf * 16 + fr) * LROW + kg);
            #pragma unroll
            for (int nf = 0; nf < 4; ++nf) {
                acc[mf][nf] = __builtin_amdgcn_mfma_f32_16x16x32_bf16(ah, bh[nf], acc[mf][nf], 0, 0, 0);
                if constexpr (SPLIT >= 2)
                    acc[mf][nf] = __builtin_amdgcn_mfma_f32_16x16x32_bf16(ah, bl[nf], acc[mf][nf], 0, 0, 0);
            }
            if constexpr (SPLIT == 3) {
                const bf16x8 al = *(const bf16x8*)(sAl + (mw * 64 + mf * 16 + fr) * LROW + kg);
                #pragma unroll
                for (int nf = 0; nf < 4; ++nf)
                    acc[mf][nf] = __builtin_amdgcn_mfma_f32_16x16x32_bf16(al, bh[nf], acc[mf][nf], 0, 0, 0);
            }
        }
    }

    #pragma unroll
    for (int nf = 0; nf < 4; ++nf) {
        const int nn = ntile + nw * 64 + nf * 16 + fr;
        if (nn < N) {
            const float bv = bias ? bias[nn] : 0.f;
            #pragma unroll
            for (int mf = 0; mf < 4; ++mf) {
                #pragma unroll
                for (int rr = 0; rr < 4; ++rr) {
                    const int m = mtile + mw * 64 + mf * 16 + (lane >> 4) * 4 + rr;
                    const float v = acc[mf][nf][rr] + bv;
                    if constexpr (CMAP == 1)
                        ((ush*)Cv)[(size_t)m * ldc + nn] = f2bf(v);
                    else if constexpr (CMAP == 2) {
                        float* dst = (float*)Cv + (size_t)(m & 63) * (L_ * V_)
                                   + (size_t)(m >> 6) * V_ + nn;
                        __builtin_nontemporal_store(v, dst);
                    } else
                        ((float*)Cv)[(size_t)m * ldc + nn] = v;
                }
            }
        }
    }
}

// ---------------------------------------------------------------------------
// gemm_big: 64M x (64*NF)N tile, 256 threads. NF=1 -> 64x64 (max blocks).
// ---------------------------------------------------------------------------
template<int SPLIT, int CMAP, bool NFAST, int NF>
__global__ __launch_bounds__(256) void gemm_big(
    const ush* __restrict__ Ah, const ush* __restrict__ Al, int lda,
    const ush* __restrict__ Wh, const ush* __restrict__ Wl, int ldw,
    const float* __restrict__ bias, void* __restrict__ Cv,
    int ldc, int N, int K)
{
    constexpr int ABYTES = 64 * LROW * 2;
    constexpr int BBYTES = 64 * NF * LROW * 2;
    constexpr int SMEM_BYTES = (SPLIT == 3) ? 2 * (ABYTES + BBYTES) : (ABYTES + BBYTES);
    __shared__ __align__(16) char smem[SMEM_BYTES];
    ush* sAh = (ush*)smem;
    ush* sBh = (ush*)(smem + ABYTES);
    ush* sAl = (ush*)(smem + ABYTES + BBYTES);
    ush* sBl = (ush*)(smem + 2 * ABYTES + BBYTES);

    const int tid = threadIdx.x;
    const int lane = tid & 63, w = tid >> 6;

    const int nbx = gridDim.x, nby = gridDim.y;
    const int nwg = nbx * nby;
    int lin = blockIdx.x + nbx * blockIdx.y;
    if ((nwg & 7) == 0) {
        const int q = nwg >> 3;
        lin = (lin & 7) * q + (lin >> 3);
    }
    int bx, by;
    if constexpr (NFAST) { by = lin % nby; bx = lin / nby; }
    else                 { bx = lin % nbx; by = lin / nbx; }
    const int mtile = bx * 64;
    const int ntile = by * (64 * NF);

    const int fr = lane & 15, kg = (lane >> 4) * 8;
    const int arow = tid >> 2, aq = (tid & 3) * 8;

    f32x4 acc[4][NF];
    #pragma unroll
    for (int mf = 0; mf < 4; ++mf)
        #pragma unroll
        for (int nf = 0; nf < NF; ++nf) acc[mf][nf] = {0.f, 0.f, 0.f, 0.f};

    const uint4 zv = make_uint4(0u, 0u, 0u, 0u);

    for (int kb = 0; kb < K; kb += 32) {
        uint4 a_h = *(const uint4*)(Ah + (size_t)(mtile + arow) * lda + kb + aq);
        uint4 a_l;
        uint4 b_h[NF], b_l[NF];
        #pragma unroll
        for (int p = 0; p < NF; ++p) {
            const int row = ntile + arow + 64 * p;
            b_h[p] = (row < N) ? *(const uint4*)(Wh + (size_t)row * ldw + kb + aq) : zv;
        }
        if constexpr (SPLIT == 3) {
            a_l = *(const uint4*)(Al + (size_t)(mtile + arow) * lda + kb + aq);
            #pragma unroll
            for (int p = 0; p < NF; ++p) {
                const int row = ntile + arow + 64 * p;
                b_l[p] = (row < N) ? *(const uint4*)(Wl + (size_t)row * ldw + kb + aq) : zv;
            }
        }

        __syncthreads();
        *(uint4*)(sAh + arow * LROW + aq) = a_h;
        #pragma unroll
        for (int p = 0; p < NF; ++p)
            *(uint4*)(sBh + (arow + 64 * p) * LROW + aq) = b_h[p];
        if constexpr (SPLIT == 3) {
            *(uint4*)(sAl + arow * LROW + aq) = a_l;
            #pragma unroll
            for (int p = 0; p < NF; ++p)
                *(uint4*)(sBl + (arow + 64 * p) * LROW + aq) = b_l[p];
        }
        __syncthreads();

        bf16x8 bh[NF], bl[NF];
        #pragma unroll
        for (int nf = 0; nf < NF; ++nf) {
            bh[nf] = *(const bf16x8*)(sBh + (w * (16 * NF) + nf * 16 + fr) * LROW + kg);
            if constexpr (SPLIT == 3)
                bl[nf] = *(const bf16x8*)(sBl + (w * (16 * NF) + nf * 16 + fr) * LROW + kg);
        }
        #pragma unroll
        for (int mf = 0; mf < 4; ++mf) {
            const bf16x8 ah = *(const bf16x8*)(sAh + (mf * 16 + fr) * LROW + kg);
            if constexpr (SPLIT == 3) {
                const bf16x8 al = *(const bf16x8*)(sAl + (mf * 16 + fr) * LROW + kg);
                #pragma unroll
                for (int nf = 0; nf < NF; ++nf) {
                    acc[mf][nf] = __builtin_amdgcn_mfma_f32_16x16x32_bf16(ah, bh[nf], acc[mf][nf], 0, 0, 0);
                    acc[mf][nf] = __builtin_amdgcn_mfma_f32_16x16x32_bf16(ah, bl[nf], acc[mf][nf], 0, 0, 0);
                    acc[mf][nf] = __builtin_amdgcn_mfma_f32_16x16x32_bf16(al, bh[nf], acc[mf][nf], 0, 0, 0);
                }
            } else {
                #pragma unroll
                for (int nf = 0; nf < NF; ++nf)
                    acc[mf][nf] = __builtin_amdgcn_mfma_f32_16x16x32_bf16(ah, bh[nf], acc[mf][nf], 0, 0, 0);
            }
        }
    }

    #pragma unroll
    for (int nf = 0; nf < NF; ++nf) {
        const int nn = ntile + w * (16 * NF) + nf * 16 + fr;
        if (nn < N) {
            const float bv = bias ? bias[nn] : 0.f;
            #pragma unroll
            for (int mf = 0; mf < 4; ++mf) {
                #pragma unroll
                for (int rr = 0; rr < 4; ++rr) {
                    const int m = mtile + mf * 16 + (lane >> 4) * 4 + rr;
                    const float v = acc[mf][nf][rr] + bv;
                    if constexpr (CMAP == 1)
                        ((ush*)Cv)[(size_t)m * ldc + nn] = f2bf(v);
                    else
                        ((float*)Cv)[(size_t)m * ldc + nn] = v;
                }
            }
        }
    }
}

// ---------------------------------------------------------------------------
// gemm_gates<ALO,WLO>: 64x64 tile, segmented A (2 segments), split-K grid.z.
// ALO/WLO: include A-lo / W-lo correction MFMAs. Loop gates: <false,false>
// (pure bf16, 1 MFMA/f) -- quant error ~1e-3 absorbed by gate nonlinearity.
// ---------------------------------------------------------------------------
template<bool ALO, bool WLO>
__global__ __launch_bounds__(256) void gemm_gates(
    const ush* __restrict__ Ah0, const ush* __restrict__ Al0, int lda0, int k0,
    const ush* __restrict__ Ah1, const ush* __restrict__ Al1, int lda1,
    const ush* __restrict__ Wh, const ush* __restrict__ Wl, int ldw,
    float* __restrict__ C, int ldc, long zstride, int kChunk)
{
    __shared__ ush sAh[64 * LROW];
    __shared__ ush sBh[64 * LROW];
    __shared__ ush sAl[64 * LROW];
    __shared__ ush sBl[64 * LROW];

    const int tid = threadIdx.x;
    const int ntile = blockIdx.x * 64;
    const int kStart = blockIdx.z * kChunk;
    const int lane = tid & 63, w = tid >> 6;
    const int lrow = tid >> 2;
    const int lcol = (tid & 3) * 8;
    const int nrow = ntile + lrow;

    f32x4 acc[4];
    #pragma unroll
    for (int f = 0; f < 4; ++f) acc[f] = {0.f, 0.f, 0.f, 0.f};

    const int fr = lane & 15;
    const int kg = (lane >> 4) * 8;

    for (int kb = kStart; kb < kStart + kChunk; kb += 32) {
        const ush *ph, *pl; int lda, loc;
        if (kb < k0) { ph = Ah0; pl = Al0; lda = lda0; loc = kb; }
        else         { ph = Ah1; pl = Al1; lda = lda1; loc = kb - k0; }

        uint4 a_h = *(const uint4*)(ph + (size_t)lrow * lda + loc + lcol);
        uint4 b_h = *(const uint4*)(Wh + (size_t)nrow * ldw + kb + lcol);
        uint4 b_l, a_l;
        if constexpr (WLO)
            b_l = *(const uint4*)(Wl + (size_t)nrow * ldw + kb + lcol);
        if constexpr (ALO)
            a_l = *(const uint4*)(pl + (size_t)lrow * lda + loc + lcol);

        __syncthreads();
        *(uint4*)(sAh + lrow * LROW + lcol) = a_h;
        *(uint4*)(sBh + lrow * LROW + lcol) = b_h;
        if constexpr (WLO)
            *(uint4*)(sBl + lrow * LROW + lcol) = b_l;
        if constexpr (ALO)
            *(uint4*)(sAl + lrow * LROW + lcol) = a_l;
        __syncthreads();

        const bf16x8 bh = *(const bf16x8*)(sBh + (16 * w + fr) * LROW + kg);
        bf16x8 bl;
        if constexpr (WLO)
            bl = *(const bf16x8*)(sBl + (16 * w + fr) * LROW + kg);

        #pragma unroll
        for (int f = 0; f < 4; ++f) {
            const bf16x8 ah = *(const bf16x8*)(sAh + (16 * f + fr) * LROW + kg);
            acc[f] = __builtin_amdgcn_mfma_f32_16x16x32_bf16(ah, bh, acc[f], 0, 0, 0);
            if constexpr (WLO)
                acc[f] = __builtin_amdgcn_mfma_f32_16x16x32_bf16(ah, bl, acc[f], 0, 0, 0);
            if constexpr (ALO) {
                const bf16x8 al = *(const bf16x8*)(sAl + (16 * f + fr) * LROW + kg);
                acc[f] = __builtin_amdgcn_mfma_f32_16x16x32_bf16(al, bh, acc[f], 0, 0, 0);
            }
        }
    }

    const int n = ntile + 16 * w + (lane & 15);
    float* Cz = C + (size_t)blockIdx.z * zstride;
    #pragma unroll
    for (int f = 0; f < 4; ++f)
        #pragma unroll
        for (int rr = 0; rr < 4; ++rr) {
            const int m = 16 * f + (lane >> 4) * 4 + rr;
            Cz[(size_t)m * ldc + n] = acc[f][rr];
        }
}

// fused feats pass: fbh (bf16) + per-(b,f) mean -> mh/ml. block (fs, b).
__global__ __launch_bounds__(256) void prep_feats(
    const float* __restrict__ feats, ush* __restrict__ fbh,
    ush* __restrict__ mh, ush* __restrict__ ml)
{
    const int fs = blockIdx.x;
    const int b  = blockIdx.y;
    const int f = fs * 512 + threadIdx.x * 2;
    const float2* fp = (const float2*)(feats + (size_t)b * R_ * F_ + f);
    ush* fo = fbh + (size_t)b * R_ * F_ + f;
    float sx = 0.f, sy = 0.f;
    for (int r = 0; r < R_; ++r) {
        const float2 v = fp[(size_t)r * (F_ / 2)];
        sx += v.x; sy += v.y;
        ushort2 u; u.x = f2bf(v.x); u.y = f2bf(v.y);
        *(ushort2*)(fo + (size_t)r * F_) = u;
    }
    const float s = 1.f / (float)R_;
    sx *= s; sy *= s;
    const size_t mi = (size_t)b * F_ + f;
    const ush hx = f2bf(sx); mh[mi] = hx;     ml[mi] = f2bf(sx - bf2f(hx));
    const ush hy = f2bf(sy); mh[mi + 1] = hy; ml[mi + 1] = f2bf(sy - bf2f(hy));
}

// gather embeddings -> bf16 hi/lo (B,L,E)
__global__ __launch_bounds__(256) void gather_split(
    const float* __restrict__ emb, const int* __restrict__ cap,
    ush* __restrict__ eh, ush* __restrict__ el)
{
    const int idx = blockIdx.x * 256 + threadIdx.x;
    const int bt = idx >> 7, j = idx & 127;
    const int tok = cap[bt];
    const float4 v = reinterpret_cast<const float4*>(emb)[(size_t)tok * (E_ / 4) + j];
    const float a[4] = {v.x, v.y, v.z, v.w};
    #pragma unroll
    for (int c = 0; c < 4; ++c) {
        const ush hi = f2bf(a[c]);
        eh[idx * 4 + c] = hi;
        el[idx * 4 + c] = f2bf(a[c] - bf2f(hi));
    }
}

// fused weight-prep: W_out, W_init_h, W_init_c (hi+lo) and W_featp (hi only).
__global__ __launch_bounds__(256) void prep_weights(
    const float* __restrict__ W_out, const float* __restrict__ W_init_h,
    const float* __restrict__ W_init_c, const float* __restrict__ W_featp,
    ush* __restrict__ woh, ush* __restrict__ wol,
    ush* __restrict__ wiH, ush* __restrict__ wiL,
    ush* __restrict__ wfp_h)
{
    const int NWO = V_ * H_ / 4;
    const int NWI = H_ * F_ / 4;
    const int NFP = A_ * F_ / 4;
    const int total = NWO + 2 * NWI + NFP;
    for (int i = blockIdx.x * 256 + threadIdx.x; i < total; i += gridDim.x * 256) {
        const float* src; ush* dh; ush* dl; int j;
        if (i < NWO)                 { src = W_out;    dh = woh;  dl = wol;  j = i; }
        else if (i < NWO + NWI)      { src = W_init_h; dh = wiH;  dl = wiL;  j = i - NWO; }
        else if (i < NWO + 2 * NWI)  { src = W_init_c; dh = wiH + (size_t)512 * F_;
                                       dl = wiL + (size_t)512 * F_; j = i - NWO - NWI; }
        else                         { src = W_featp;  dh = wfp_h; dl = nullptr; j = i - NWO - 2 * NWI; }
        const float4 v = reinterpret_cast<const float4*>(src)[j];
        const float a[4] = {v.x, v.y, v.z, v.w};
        #pragma unroll
        for (int c = 0; c < 4; ++c) {
            const ush h = f2bf(a[c]);
            dh[j * 4 + c] = h;
            if (dl) dl[j * 4 + c] = f2bf(a[c] - bf2f(h));
        }
    }
}

// W_ih columns [0:E) -> wx (2048x512); [E:) ++ W_hh -> wg2 (2048x2560); hi/lo
__global__ __launch_bounds__(256) void prep_wih(
    const float* __restrict__ W_ih, const float* __restrict__ W_hh,
    ush* __restrict__ wxh, ush* __restrict__ wxl,
    ush* __restrict__ wg2h, ush* __restrict__ wg2l)
{
    const int nrow = blockIdx.x;
    for (int k = threadIdx.x; k < E_; k += 256) {
        const float v = W_ih[(size_t)nrow * (E_ + F_) + k];
        const ush h = f2bf(v);
        wxh[(size_t)nrow * E_ + k] = h;
        wxl[(size_t)nrow * E_ + k] = f2bf(v - bf2f(h));
    }
    for (int k = threadIdx.x; k < F_ + H_; k += 256) {
        const float v = (k < F_) ? W_ih[(size_t)nrow * (E_ + F_) + E_ + k]
                                 : W_hh[(size_t)nrow * H_ + (k - F_)];
        const ush h = f2bf(v);
        wg2h[(size_t)nrow * (F_ + H_) + k] = h;
        wg2l[(size_t)nrow * (F_ + H_) + k] = f2bf(v - bf2f(h));
    }
}

// transpose W_hidp (A x H) -> whpT (H x A), bf16
__global__ __launch_bounds__(256) void transpose512(
    const float* __restrict__ in, ush* __restrict__ out)
{
    const int idx = blockIdx.x * 256 + threadIdx.x;
    const int k = idx >> 9, a = idx & 511;
    out[idx] = f2bf(in[(size_t)a * 512 + k]);
}

// reduce init GEMM partials: n<512 -> h0 (+bf16 hi), n>=512 -> c0 (buffer 0)
__global__ __launch_bounds__(256) void init_reduce(
    const float* __restrict__ initp, const float* __restrict__ b_init_h,
    const float* __restrict__ b_init_c, float* __restrict__ h0f,
    float* __restrict__ c0, ush* __restrict__ h_hi)
{
    const int idx = blockIdx.x * 256 + threadIdx.x;
    const int b = idx >> 10, n = idx & 1023;
    float s = 0.f;
    #pragma unroll
    for (int z = 0; z < 8; ++z)
        s += initp[(size_t)z * (B_ * 1024) + (size_t)b * 1024 + n];
    if (n < 512) {
        s += b_init_h[n];
        h0f[b * H_ + n] = s;
        h_hi[b * H_ + n] = f2bf(s);
    } else {
        s += b_init_c[n - 512];
        c0[b * H_ + (n - 512)] = s;
    }
}

// ---------------------------------------------------------------------------
// step2_kernel<ATT>: grid (4, B) when ATT (fs = f-quarter), (1, B) else.
// ---------------------------------------------------------------------------
template<bool ATT>
__global__ __launch_bounds__(512) void step2_kernel(
    const float* __restrict__ gparts, const float* __restrict__ egates,
    const float* __restrict__ b_ih, const float* __restrict__ b_hh,
    float* __restrict__ c2, const float* __restrict__ h0f,
    ush* __restrict__ h_hi, ush* __restrict__ hall_hi,
    const ush* __restrict__ whpT, const float* __restrict__ b_hidp,
    const ush* __restrict__ fpb, const float* __restrict__ W_score,
    const float* __restrict__ b_score, const ush* __restrict__ fbh,
    ush* __restrict__ ctx_hi,
    float* __restrict__ alph_out, int t)
{
    __shared__ float sh_h[H_];
    __shared__ float sh_hp[A_];
    __shared__ float sh_ws[A_];
    __shared__ float sh_sc[200];
    __shared__ float red[2];
    const int tid = threadIdx.x;
    const int fs = blockIdx.x;
    const int b = blockIdx.y;
    const int n = tid;

    float hh;
    if (t > 0) {
        const float* c_old = c2 + (size_t)((t - 1) & 1) * B_ * H_;
        float* c_new = c2 + (size_t)(t & 1) * B_ * H_;
        const float* eg = egates + ((size_t)b * L_ + (t - 1)) * 2048;
        float gi = b_ih[n] + b_hh[n] + eg[n];
        float gf = b_ih[n + 512] + b_hh[n + 512] + eg[n + 512];
        float gg = b_ih[n + 1024] + b_hh[n + 1024] + eg[n + 1024];
        float go = b_ih[n + 1536] + b_hh[n + 1536] + eg[n + 1536];
        #pragma unroll
        for (int z = 0; z < 8; ++z) {
            const float* gz = gparts + (size_t)z * B_ * 2048 + (size_t)b * 2048;
            gi += gz[n]; gf += gz[n + 512]; gg += gz[n + 1024]; go += gz[n + 1536];
        }
        const float cc = fast_sig(gf) * c_old[b * H_ + n] + fast_sig(gi) * fast_tanh(gg);
        hh = fast_sig(go) * fast_tanh(cc);
        if (fs == 0) {
            c_new[b * H_ + n] = cc;
            const ush hi = f2bf(hh);
            h_hi[b * H_ + n] = hi;
            hall_hi[((size_t)(t - 1) * B_ + b) * H_ + n] = hi;
        }
    } else {
        hh = h0f[b * H_ + n];
    }
    if constexpr (!ATT) return;

    sh_h[n] = hh;
    sh_ws[n] = W_score[n];
    __syncthreads();

    // hid_proj (coalesced, bf16 whpT)
    {
        float a0 = 0.f, a1 = 0.f, a2 = 0.f, a3 = 0.f;
        #pragma unroll 4
        for (int k = 0; k < H_; k += 4) {
            a0 = fmaf(sh_h[k + 0], bf2f(whpT[(size_t)(k + 0) * A_ + tid]), a0);
            a1 = fmaf(sh_h[k + 1], bf2f(whpT[(size_t)(k + 1) * A_ + tid]), a1);
            a2 = fmaf(sh_h[k + 2], bf2f(whpT[(size_t)(k + 2) * A_ + tid]), a2);
            a3 = fmaf(sh_h[k + 3], bf2f(whpT[(size_t)(k + 3) * A_ + tid]), a3);
        }
        sh_hp[tid] = (a0 + a1) + (a2 + a3) + b_hidp[tid];
    }
    __syncthreads();

    const int lane = tid & 63, wid = tid >> 6;
    for (int r = wid; r < R_; r += 8) {
        const ushort2* row = reinterpret_cast<const ushort2*>(fpb + ((size_t)b * R_ + r) * A_);
        float acc = 0.f;
        #pragma unroll
        for (int j = 0; j < 4; ++j) {
            const ushort2 u = row[lane + 64 * j];
            const int a = 2 * (lane + 64 * j);
            acc += fast_tanh(bf2f(u.x) + sh_hp[a]) * sh_ws[a];
            acc += fast_tanh(bf2f(u.y) + sh_hp[a + 1]) * sh_ws[a + 1];
        }
        for (int off = 32; off > 0; off >>= 1) acc += __shfl_down(acc, off);
        if (lane == 0) sh_sc[r] = acc + b_score[0];
    }
    __syncthreads();

    if (tid < 64) {
        float m = -1e30f;
        for (int r = tid; r < R_; r += 64) m = fmaxf(m, sh_sc[r]);
        for (int off = 32; off > 0; off >>= 1) m = fmaxf(m, __shfl_xor(m, off));
        float s = 0.f;
        for (int r = tid; r < R_; r += 64) s += __expf(sh_sc[r] - m);
        for (int off = 32; off > 0; off >>= 1) s += __shfl_xor(s, off);
        if (tid == 0) { red[0] = m; red[1] = 1.f / s; }
    }
    __syncthreads();
    const float m = red[0], is = red[1];
    if (tid < R_) {
        const float av = __expf(sh_sc[tid] - m) * is;
        sh_sc[tid] = av;
        if (fs == 0) alph_out[((size_t)b * L_ + t) * R_ + tid] = av;
    }
    __syncthreads();

    // ---- ctx quarter: f = fs*512 + tid, sum over 196 regions (bf16 fbh) ----
    {
        const int f0 = fs * 512 + tid;
        const ush* fp2 = fbh + (size_t)b * R_ * F_ + f0;
        float cx = 0.f;
        #pragma unroll 4
        for (int r = 0; r < R_; ++r)
            cx = fmaf(sh_sc[r], bf2f(fp2[(size_t)r * F_]), cx);
        ctx_hi[(size_t)b * F_ + f0] = f2bf(cx);
    }
}

extern "C" void kernel_launch(void* const* d_in, const int* in_sizes, int n_in,
                              void* d_out, int out_size, void* d_ws, size_t ws_size,
                              hipStream_t stream)
{
    const float* feats    = (const float*)d_in[0];
    const int*   cap      = (const int*)  d_in[1];
    const float* emb      = (const float*)d_in[2];
    const float* W_init_h = (const float*)d_in[3];
    const float* b_init_h = (const float*)d_in[4];
    const float* W_init_c = (const float*)d_in[5];
    const float* b_init_c = (const float*)d_in[6];
    const float* W_ih     = (const float*)d_in[7];
    const float* b_ih     = (const float*)d_in[8];
    const float* W_hh     = (const float*)d_in[9];
    const float* b_hh     = (const float*)d_in[10];
    const float* W_featp  = (const float*)d_in[11];
    const float* b_featp  = (const float*)d_in[12];
    const float* W_hidp   = (const float*)d_in[13];
    const float* b_hidp   = (const float*)d_in[14];
    const float* W_score  = (const float*)d_in[15];
    const float* b_score  = (const float*)d_in[16];
    const float* W_out    = (const float*)d_in[17];
    const float* b_out    = (const float*)d_in[18];

    float* pred     = (float*)d_out;                          // (B,L,V)
    float* alph_out = pred + (size_t)B_ * L_ * V_;            // (B,L,R)

    char* p = (char*)d_ws;
    auto alloc = [&](size_t bytes) { char* q = p; p += (bytes + 255) & ~(size_t)255; return q; };

    ush*   fpb    = (ush*)  alloc((size_t)B_ * R_ * A_ * 2);
    ush*   eh     = (ush*)  alloc((size_t)B_ * L_ * E_ * 2);
    ush*   el     = (ush*)  alloc((size_t)B_ * L_ * E_ * 2);
    ush*   mh     = (ush*)  alloc((size_t)B_ * F_ * 2);
    ush*   ml     = (ush*)  alloc((size_t)B_ * F_ * 2);
    ush*   fbh    = (ush*)  alloc((size_t)B_ * R_ * F_ * 2);
    ush*   wfp_h  = (ush*)  alloc((size_t)A_ * F_ * 2);
    ush*   wiH    = (ush*)  alloc((size_t)1024 * F_ * 2);
    ush*   wiL    = (ush*)  alloc((size_t)1024 * F_ * 2);
    ush*   wxh    = (ush*)  alloc((size_t)2048 * E_ * 2);
    ush*   wxl    = (ush*)  alloc((size_t)2048 * E_ * 2);
    ush*   wg2h   = (ush*)  alloc((size_t)2048 * (F_ + H_) * 2);
    ush*   wg2l   = (ush*)  alloc((size_t)2048 * (F_ + H_) * 2);
    ush*   woh    = (ush*)  alloc((size_t)V_ * H_ * 2);
    ush*   wol    = (ush*)  alloc((size_t)V_ * H_ * 2);
    ush*   whpT   = (ush*)  alloc((size_t)H_ * A_ * 2);
    float* egates = (float*)alloc((size_t)B_ * L_ * 2048 * 4);
    float* h0f    = (float*)alloc((size_t)B_ * H_ * 4);
    float* c2     = (float*)alloc((size_t)2 * B_ * H_ * 4);   // double-buffered c
    ush*   h_hi   = (ush*)  alloc((size_t)B_ * H_ * 2);
    ush*   hallh  = (ush*)  alloc((size_t)L_ * B_ * H_ * 2);
    ush*   ctx_hi = (ush*)  alloc((size_t)B_ * F_ * 2);
    float* gparts = (float*)alloc((size_t)8 * B_ * 2048 * 4);
    float* initp  = (float*)alloc((size_t)8 * B_ * 1024 * 4);

    // ---- one-time prep ----
    prep_feats<<<dim3(4, B_), 256, 0, stream>>>(feats, fbh, mh, ml);
    gather_split<<<768, 256, 0, stream>>>(emb, cap, eh, el);
    prep_weights<<<2048, 256, 0, stream>>>(W_out, W_init_h, W_init_c, W_featp,
                                           woh, wol, wiH, wiL, wfp_h);
    prep_wih<<<2048, 256, 0, stream>>>(W_ih, W_hh, wxh, wxl, wg2h, wg2l);
    transpose512<<<1024, 256, 0, stream>>>(W_hidp, whpT);

    // h0/c0 init: M=64, N=1024 (stacked), K=2048, split-K=8 (full accuracy)
    gemm_gates<true, true><<<dim3(16, 1, 8), 256, 0, stream>>>(
        mh, ml, F_, F_,
        mh, ml, F_,
        wiH, wiL, F_,
        initp, 1024, (long)B_ * 1024, F_ / 8);
    init_reduce<<<256, 256, 0, stream>>>(initp, b_init_h, b_init_c, h0f, c2, h_hi);

    // feat_proj (SPLIT=1, bf16 out, NF=1): 64x64 tiles -> grid(196,8)=1568
    gemm_big<1, 1, true, 1><<<dim3(196, 8), 256, 0, stream>>>(
        fbh, nullptr, F_, wfp_h, nullptr, F_, b_featp, fpb, A_, A_, F_);

    // emb gate part for ALL steps (SPLIT=3, NF=2): grid(24,16)=384
    gemm_big<3, 0, false, 2><<<dim3(24, 16), 256, 0, stream>>>(
        eh, el, E_, wxh, wxl, E_, nullptr, egates, 2048, 2048, E_);

    // ---- sequential decode: 2 kernels per step ----
    for (int t = 0; t < L_; ++t) {
        step2_kernel<true><<<dim3(4, B_), 512, 0, stream>>>(
            gparts, egates, b_ih, b_hh, c2, h0f, h_hi, hallh,
            whpT, b_hidp, fpb, W_score, b_score, fbh, ctx_hi,
            alph_out, t);

        // gates: [ctx | h] @ wg2^T, K=2560, split-K=8; pure bf16 (1 MFMA)
        gemm_gates<false, false><<<dim3(32, 1, 8), 256, 0, stream>>>(
            ctx_hi, nullptr, F_, F_,
            h_hi, nullptr, H_,
            wg2h, nullptr, F_ + H_,
            gparts, 4 * H_, (long)B_ * 4 * H_, (F_ + H_) / 8);
    }

    // final cell: h_L -> hall[L-1]
    step2_kernel<false><<<dim3(1, B_), 512, 0, stream>>>(
        gparts, egates, b_ih, b_hh, c2, h0f, h_hi, hallh,
        whpT, b_hidp, fpb, W_score, b_score, fbh, ctx_hi,
        alph_out, L_);

    // predictions (SPLIT=2: h-hi x (Wout hi+lo)): M=1536 -> 12x128 tiles
    gemm_big128<2, 2, false><<<dim3(12, 47), 512, 0, stream>>>(
        hallh, nullptr, H_, woh, wol, H_, b_out, pred, 0, V_, H_);
}

// Round 17
// 1885.129 us; speedup vs baseline: 1.8081x; 1.0009x over previous
//
#include <hip/hip_runtime.h>

#define B_ 64
#define R_ 196
#define F_ 2048
#define E_ 512
#define H_ 512
#define A_ 512
#define V_ 12000
#define L_ 24

typedef __attribute__((ext_vector_type(8))) short bf16x8;
typedef __attribute__((ext_vector_type(4))) float f32x4;
typedef unsigned short ush;

__device__ __forceinline__ float fast_tanh(float x) {
    float t = __expf(2.f * x);
    return 1.f - 2.f / (t + 1.f);
}
__device__ __forceinline__ float fast_sig(float x) {
    return 1.f / (1.f + __expf(-x));
}
__device__ __forceinline__ ush f2bf(float x) {
    unsigned int u = __float_as_uint(x);
    return (ush)((u + 0x7fffu + ((u >> 16) & 1u)) >> 16);
}
__device__ __forceinline__ float bf2f(ush b) {
    return __uint_as_float(((unsigned int)b) << 16);
}

#define LROW 40   // LDS row stride (32 k-elems + 8 pad)

// ---------------------------------------------------------------------------
// gemm_big128: C = A @ W^T (+bias). Tile 128M x 256N, BK=32, 512 threads.
// Register-prefetch K-loop: next tile's global loads issue before the MFMA
// cluster, overlapping load latency with compute.
// SPLIT=2: Ahi x (Whi,Wlo) 2 MFMAs. CMAP=2: pred layout, fp32 NT stores.
// ---------------------------------------------------------------------------
template<int SPLIT, int CMAP, bool NFAST>
__global__ __launch_bounds__(512) void gemm_big128(
    const ush* __restrict__ Ah, const ush* __restrict__ Al, int lda,
    const ush* __restrict__ Wh, const ush* __restrict__ Wl, int ldw,
    const float* __restrict__ bias, void* __restrict__ Cv,
    int ldc, int N, int K)
{
    constexpr int SMEM_BYTES = (SPLIT == 3) ? 61440 : (SPLIT == 2 ? 51200 : 30720);
    __shared__ __align__(16) char smem[SMEM_BYTES];
    ush* sAh = (ush*)smem;
    ush* sBh = (ush*)(smem + 10240);
    ush* sBl = (ush*)(smem + 30720);
    ush* sAl = (ush*)(smem + 51200);

    const int tid = threadIdx.x;
    const int lane = tid & 63, w = tid >> 6;
    const int mw = w >> 2, nw = w & 3;

    const int nbx = gridDim.x, nby = gridDim.y;
    const int nwg = nbx * nby;
    const int orig = blockIdx.x + nbx * blockIdx.y;
    const int q = nwg >> 3, r = nwg & 7;
    const int xcd = orig & 7, idx = orig >> 3;
    const int lin = (xcd < r ? xcd * (q + 1) : r * (q + 1) + (xcd - r) * q) + idx;
    int bx, by;
    if constexpr (NFAST) { by = lin % nby; bx = lin / nby; }
    else                 { bx = lin % nbx; by = lin / nbx; }
    const int mtile = bx * 128;
    const int ntile = by * 256;

    const int fr = lane & 15, kg = (lane >> 4) * 8;
    const int arow = tid >> 2, aq = (tid & 3) * 8;

    f32x4 acc[4][4];
    #pragma unroll
    for (int mf = 0; mf < 4; ++mf)
        #pragma unroll
        for (int nf = 0; nf < 4; ++nf) acc[mf][nf] = {0.f, 0.f, 0.f, 0.f};

    const uint4 zv = make_uint4(0u, 0u, 0u, 0u);
    bool rowok[2];
    #pragma unroll
    for (int p = 0; p < 2; ++p) rowok[p] = (ntile + arow + 128 * p) < N;

    // prologue: load k-tile 0
    uint4 a_h = *(const uint4*)(Ah + (size_t)(mtile + arow) * lda + aq);
    uint4 a_l, b_h[2], b_l[2];
    #pragma unroll
    for (int p = 0; p < 2; ++p)
        b_h[p] = rowok[p] ? *(const uint4*)(Wh + (size_t)(ntile + arow + 128 * p) * ldw + aq) : zv;
    if constexpr (SPLIT >= 2) {
        #pragma unroll
        for (int p = 0; p < 2; ++p)
            b_l[p] = rowok[p] ? *(const uint4*)(Wl + (size_t)(ntile + arow + 128 * p) * ldw + aq) : zv;
    }
    if constexpr (SPLIT == 3)
        a_l = *(const uint4*)(Al + (size_t)(mtile + arow) * lda + aq);

    for (int kb = 0; kb < K; kb += 32) {
        __syncthreads();
        *(uint4*)(sAh + arow * LROW + aq) = a_h;
        #pragma unroll
        for (int p = 0; p < 2; ++p)
            *(uint4*)(sBh + (arow + 128 * p) * LROW + aq) = b_h[p];
        if constexpr (SPLIT >= 2) {
            #pragma unroll
            for (int p = 0; p < 2; ++p)
                *(uint4*)(sBl + (arow + 128 * p) * LROW + aq) = b_l[p];
        }
        if constexpr (SPLIT == 3)
            *(uint4*)(sAl + arow * LROW + aq) = a_l;
        __syncthreads();

        // prefetch next k-tile (overlaps the MFMA cluster below)
        const int kn = kb + 32;
        if (kn < K) {
            a_h = *(const uint4*)(Ah + (size_t)(mtile + arow) * lda + kn + aq);
            #pragma unroll
            for (int p = 0; p < 2; ++p)
                b_h[p] = rowok[p] ? *(const uint4*)(Wh + (size_t)(ntile + arow + 128 * p) * ldw + kn + aq) : zv;
            if constexpr (SPLIT >= 2) {
                #pragma unroll
                for (int p = 0; p < 2; ++p)
                    b_l[p] = rowok[p] ? *(const uint4*)(Wl + (size_t)(ntile + arow + 128 * p) * ldw + kn + aq) : zv;
            }
            if constexpr (SPLIT == 3)
                a_l = *(const uint4*)(Al + (size_t)(mtile + arow) * lda + kn + aq);
        }

        bf16x8 bhf[4], blf[4];
        #pragma unroll
        for (int nf = 0; nf < 4; ++nf) {
            bhf[nf] = *(const bf16x8*)(sBh + (nw * 64 + nf * 16 + fr) * LROW + kg);
            if constexpr (SPLIT >= 2)
                blf[nf] = *(const bf16x8*)(sBl + (nw * 64 + nf * 16 + fr) * LROW + kg);
        }
        #pragma unroll
        for (int mf = 0; mf < 4; ++mf) {
            const bf16x8 ahf = *(const bf16x8*)(sAh + (mw * 64 + mf * 16 + fr) * LROW + kg);
            #pragma unroll
            for (int nf = 0; nf < 4; ++nf) {
                acc[mf][nf] = __builtin_amdgcn_mfma_f32_16x16x32_bf16(ahf, bhf[nf], acc[mf][nf], 0, 0, 0);
                if constexpr (SPLIT >= 2)
                    acc[mf][nf] = __builtin_amdgcn_mfma_f32_16x16x32_bf16(ahf, blf[nf], acc[mf][nf], 0, 0, 0);
            }
            if constexpr (SPLIT == 3) {
                const bf16x8 alf = *(const bf16x8*)(sAl + (mw * 64 + mf * 16 + fr) * LROW + kg);
                #pragma unroll
                for (int nf = 0; nf < 4; ++nf)
                    acc[mf][nf] = __builtin_amdgcn_mfma_f32_16x16x32_bf16(alf, bhf[nf], acc[mf][nf], 0, 0, 0);
            }
        }
    }

    #pragma unroll
    for (int nf = 0; nf < 4; ++nf) {
        const int nn = ntile + nw * 64 + nf * 16 + fr;
        if (nn < N) {
            const float bv = bias ? bias[nn] : 0.f;
            #pragma unroll
            for (int mf = 0; mf < 4; ++mf) {
                #pragma unroll
                for (int rr = 0; rr < 4; ++rr) {
                    const int m = mtile + mw * 64 + mf * 16 + (lane >> 4) * 4 + rr;
                    const float v = acc[mf][nf][rr] + bv;
                    if constexpr (CMAP == 1)
                        ((ush*)Cv)[(size_t)m * ldc + nn] = f2bf(v);
                    else if constexpr (CMAP == 2) {
                        float* dst = (float*)Cv + (size_t)(m & 63) * (L_ * V_)
                                   + (size_t)(m >> 6) * V_ + nn;
                        __builtin_nontemporal_store(v, dst);
                    } else
                        ((float*)Cv)[(size_t)m * ldc + nn] = v;
                }
            }
        }
    }
}

// ---------------------------------------------------------------------------
// gemm_big: 64M x (64*NF)N tile, 256 threads, register-prefetch K-loop.
// ---------------------------------------------------------------------------
template<int SPLIT, int CMAP, bool NFAST, int NF>
__global__ __launch_bounds__(256) void gemm_big(
    const ush* __restrict__ Ah, const ush* __restrict__ Al, int lda,
    const ush* __restrict__ Wh, const ush* __restrict__ Wl, int ldw,
    const float* __restrict__ bias, void* __restrict__ Cv,
    int ldc, int N, int K)
{
    constexpr int ABYTES = 64 * LROW * 2;
    constexpr int BBYTES = 64 * NF * LROW * 2;
    constexpr int SMEM_BYTES = (SPLIT == 3) ? 2 * (ABYTES + BBYTES) : (ABYTES + BBYTES);
    __shared__ __align__(16) char smem[SMEM_BYTES];
    ush* sAh = (ush*)smem;
    ush* sBh = (ush*)(smem + ABYTES);
    ush* sAl = (ush*)(smem + ABYTES + BBYTES);
    ush* sBl = (ush*)(smem + 2 * ABYTES + BBYTES);

    const int tid = threadIdx.x;
    const int lane = tid & 63, w = tid >> 6;

    const int nbx = gridDim.x, nby = gridDim.y;
    const int nwg = nbx * nby;
    int lin = blockIdx.x + nbx * blockIdx.y;
    if ((nwg & 7) == 0) {
        const int q = nwg >> 3;
        lin = (lin & 7) * q + (lin >> 3);
    }
    int bx, by;
    if constexpr (NFAST) { by = lin % nby; bx = lin / nby; }
    else                 { bx = lin % nbx; by = lin / nbx; }
    const int mtile = bx * 64;
    const int ntile = by * (64 * NF);

    const int fr = lane & 15, kg = (lane >> 4) * 8;
    const int arow = tid >> 2, aq = (tid & 3) * 8;

    f32x4 acc[4][NF];
    #pragma unroll
    for (int mf = 0; mf < 4; ++mf)
        #pragma unroll
        for (int nf = 0; nf < NF; ++nf) acc[mf][nf] = {0.f, 0.f, 0.f, 0.f};

    const uint4 zv = make_uint4(0u, 0u, 0u, 0u);
    bool rowok[NF];
    #pragma unroll
    for (int p = 0; p < NF; ++p) rowok[p] = (ntile + arow + 64 * p) < N;

    uint4 a_h = *(const uint4*)(Ah + (size_t)(mtile + arow) * lda + aq);
    uint4 a_l, b_h[NF], b_l[NF];
    #pragma unroll
    for (int p = 0; p < NF; ++p)
        b_h[p] = rowok[p] ? *(const uint4*)(Wh + (size_t)(ntile + arow + 64 * p) * ldw + aq) : zv;
    if constexpr (SPLIT == 3) {
        a_l = *(const uint4*)(Al + (size_t)(mtile + arow) * lda + aq);
        #pragma unroll
        for (int p = 0; p < NF; ++p)
            b_l[p] = rowok[p] ? *(const uint4*)(Wl + (size_t)(ntile + arow + 64 * p) * ldw + aq) : zv;
    }

    for (int kb = 0; kb < K; kb += 32) {
        __syncthreads();
        *(uint4*)(sAh + arow * LROW + aq) = a_h;
        #pragma unroll
        for (int p = 0; p < NF; ++p)
            *(uint4*)(sBh + (arow + 64 * p) * LROW + aq) = b_h[p];
        if constexpr (SPLIT == 3) {
            *(uint4*)(sAl + arow * LROW + aq) = a_l;
            #pragma unroll
            for (int p = 0; p < NF; ++p)
                *(uint4*)(sBl + (arow + 64 * p) * LROW + aq) = b_l[p];
        }
        __syncthreads();

        const int kn = kb + 32;
        if (kn < K) {
            a_h = *(const uint4*)(Ah + (size_t)(mtile + arow) * lda + kn + aq);
            #pragma unroll
            for (int p = 0; p < NF; ++p)
                b_h[p] = rowok[p] ? *(const uint4*)(Wh + (size_t)(ntile + arow + 64 * p) * ldw + kn + aq) : zv;
            if constexpr (SPLIT == 3) {
                a_l = *(const uint4*)(Al + (size_t)(mtile + arow) * lda + kn + aq);
                #pragma unroll
                for (int p = 0; p < NF; ++p)
                    b_l[p] = rowok[p] ? *(const uint4*)(Wl + (size_t)(ntile + arow + 64 * p) * ldw + kn + aq) : zv;
            }
        }

        bf16x8 bhf[NF], blf[NF];
        #pragma unroll
        for (int nf = 0; nf < NF; ++nf) {
            bhf[nf] = *(const bf16x8*)(sBh + (w * (16 * NF) + nf * 16 + fr) * LROW + kg);
            if constexpr (SPLIT == 3)
                blf[nf] = *(const bf16x8*)(sBl + (w * (16 * NF) + nf * 16 + fr) * LROW + kg);
        }
        #pragma unroll
        for (int mf = 0; mf < 4; ++mf) {
            const bf16x8 ahf = *(const bf16x8*)(sAh + (mf * 16 + fr) * LROW + kg);
            if constexpr (SPLIT == 3) {
                const bf16x8 alf = *(const bf16x8*)(sAl + (mf * 16 + fr) * LROW + kg);
                #pragma unroll
                for (int nf = 0; nf < NF; ++nf) {
                    acc[mf][nf] = __builtin_amdgcn_mfma_f32_16x16x32_bf16(ahf, bhf[nf], acc[mf][nf], 0, 0, 0);
                    acc[mf][nf] = __builtin_amdgcn_mfma_f32_16x16x32_bf16(ahf, blf[nf], acc[mf][nf], 0, 0, 0);
                    acc[mf][nf] = __builtin_amdgcn_mfma_f32_16x16x32_bf16(alf, bhf[nf], acc[mf][nf], 0, 0, 0);
                }
            } else {
                #pragma unroll
                for (int nf = 0; nf < NF; ++nf)
                    acc[mf][nf] = __builtin_amdgcn_mfma_f32_16x16x32_bf16(ahf, bhf[nf], acc[mf][nf], 0, 0, 0);
            }
        }
    }

    #pragma unroll
    for (int nf = 0; nf < NF; ++nf) {
        const int nn = ntile + w * (16 * NF) + nf * 16 + fr;
        if (nn < N) {
            const float bv = bias ? bias[nn] : 0.f;
            #pragma unroll
            for (int mf = 0; mf < 4; ++mf) {
                #pragma unroll
                for (int rr = 0; rr < 4; ++rr) {
                    const int m = mtile + mf * 16 + (lane >> 4) * 4 + rr;
                    const float v = acc[mf][nf][rr] + bv;
                    if constexpr (CMAP == 1)
                        ((ush*)Cv)[(size_t)m * ldc + nn] = f2bf(v);
                    else
                        ((float*)Cv)[(size_t)m * ldc + nn] = v;
                }
            }
        }
    }
}

// ---------------------------------------------------------------------------
// gemm_gates<ALO,WLO>: 64x64 tile, segmented A, split-K, register-prefetch.
// Loop gates: <false,false> (pure bf16, 1 MFMA/f).
// ---------------------------------------------------------------------------
template<bool ALO, bool WLO>
__global__ __launch_bounds__(256) void gemm_gates(
    const ush* __restrict__ Ah0, const ush* __restrict__ Al0, int lda0, int k0,
    const ush* __restrict__ Ah1, const ush* __restrict__ Al1, int lda1,
    const ush* __restrict__ Wh, const ush* __restrict__ Wl, int ldw,
    float* __restrict__ C, int ldc, long zstride, int kChunk)
{
    __shared__ ush sAh[64 * LROW];
    __shared__ ush sBh[64 * LROW];
    __shared__ ush sAl[64 * LROW];
    __shared__ ush sBl[64 * LROW];

    const int tid = threadIdx.x;
    const int ntile = blockIdx.x * 64;
    const int kStart = blockIdx.z * kChunk;
    const int kEnd = kStart + kChunk;
    const int lane = tid & 63, w = tid >> 6;
    const int lrow = tid >> 2;
    const int lcol = (tid & 3) * 8;
    const int nrow = ntile + lrow;

    f32x4 acc[4];
    #pragma unroll
    for (int f = 0; f < 4; ++f) acc[f] = {0.f, 0.f, 0.f, 0.f};

    const int fr = lane & 15;
    const int kg = (lane >> 4) * 8;

    auto loadA = [&](int kb, uint4& ah, uint4& al) {
        const ush *ph, *pl; int lda, loc;
        if (kb < k0) { ph = Ah0; pl = Al0; lda = lda0; loc = kb; }
        else         { ph = Ah1; pl = Al1; lda = lda1; loc = kb - k0; }
        ah = *(const uint4*)(ph + (size_t)lrow * lda + loc + lcol);
        if constexpr (ALO)
            al = *(const uint4*)(pl + (size_t)lrow * lda + loc + lcol);
    };

    uint4 a_h, a_l, b_h, b_l;
    loadA(kStart, a_h, a_l);
    b_h = *(const uint4*)(Wh + (size_t)nrow * ldw + kStart + lcol);
    if constexpr (WLO)
        b_l = *(const uint4*)(Wl + (size_t)nrow * ldw + kStart + lcol);

    for (int kb = kStart; kb < kEnd; kb += 32) {
        __syncthreads();
        *(uint4*)(sAh + lrow * LROW + lcol) = a_h;
        *(uint4*)(sBh + lrow * LROW + lcol) = b_h;
        if constexpr (WLO)
            *(uint4*)(sBl + lrow * LROW + lcol) = b_l;
        if constexpr (ALO)
            *(uint4*)(sAl + lrow * LROW + lcol) = a_l;
        __syncthreads();

        const int kn = kb + 32;
        if (kn < kEnd) {
            loadA(kn, a_h, a_l);
            b_h = *(const uint4*)(Wh + (size_t)nrow * ldw + kn + lcol);
            if constexpr (WLO)
                b_l = *(const uint4*)(Wl + (size_t)nrow * ldw + kn + lcol);
        }

        const bf16x8 bh = *(const bf16x8*)(sBh + (16 * w + fr) * LROW + kg);
        bf16x8 bl;
        if constexpr (WLO)
            bl = *(const bf16x8*)(sBl + (16 * w + fr) * LROW + kg);

        #pragma unroll
        for (int f = 0; f < 4; ++f) {
            const bf16x8 ah = *(const bf16x8*)(sAh + (16 * f + fr) * LROW + kg);
            acc[f] = __builtin_amdgcn_mfma_f32_16x16x32_bf16(ah, bh, acc[f], 0, 0, 0);
            if constexpr (WLO)
                acc[f] = __builtin_amdgcn_mfma_f32_16x16x32_bf16(ah, bl, acc[f], 0, 0, 0);
            if constexpr (ALO) {
                const bf16x8 al = *(const bf16x8*)(sAl + (16 * f + fr) * LROW + kg);
                acc[f] = __builtin_amdgcn_mfma_f32_16x16x32_bf16(al, bh, acc[f], 0, 0, 0);
            }
        }
    }

    const int n = ntile + 16 * w + (lane & 15);
    float* Cz = C + (size_t)blockIdx.z * zstride;
    #pragma unroll
    for (int f = 0; f < 4; ++f)
        #pragma unroll
        for (int rr = 0; rr < 4; ++rr) {
            const int m = 16 * f + (lane >> 4) * 4 + rr;
            Cz[(size_t)m * ldc + n] = acc[f][rr];
        }
}

// fused feats pass: fbh (bf16) + per-(b,f) mean -> mh/ml. block (fs, b).
__global__ __launch_bounds__(256) void prep_feats(
    const float* __restrict__ feats, ush* __restrict__ fbh,
    ush* __restrict__ mh, ush* __restrict__ ml)
{
    const int fs = blockIdx.x;
    const int b  = blockIdx.y;
    const int f = fs * 512 + threadIdx.x * 2;
    const float2* fp = (const float2*)(feats + (size_t)b * R_ * F_ + f);
    ush* fo = fbh + (size_t)b * R_ * F_ + f;
    float sx = 0.f, sy = 0.f;
    for (int r = 0; r < R_; ++r) {
        const float2 v = fp[(size_t)r * (F_ / 2)];
        sx += v.x; sy += v.y;
        ushort2 u; u.x = f2bf(v.x); u.y = f2bf(v.y);
        *(ushort2*)(fo + (size_t)r * F_) = u;
    }
    const float s = 1.f / (float)R_;
    sx *= s; sy *= s;
    const size_t mi = (size_t)b * F_ + f;
    const ush hx = f2bf(sx); mh[mi] = hx;     ml[mi] = f2bf(sx - bf2f(hx));
    const ush hy = f2bf(sy); mh[mi + 1] = hy; ml[mi + 1] = f2bf(sy - bf2f(hy));
}

// gather embeddings -> bf16 hi/lo (B,L,E)
__global__ __launch_bounds__(256) void gather_split(
    const float* __restrict__ emb, const int* __restrict__ cap,
    ush* __restrict__ eh, ush* __restrict__ el)
{
    const int idx = blockIdx.x * 256 + threadIdx.x;
    const int bt = idx >> 7, j = idx & 127;
    const int tok = cap[bt];
    const float4 v = reinterpret_cast<const float4*>(emb)[(size_t)tok * (E_ / 4) + j];
    const float a[4] = {v.x, v.y, v.z, v.w};
    #pragma unroll
    for (int c = 0; c < 4; ++c) {
        const ush hi = f2bf(a[c]);
        eh[idx * 4 + c] = hi;
        el[idx * 4 + c] = f2bf(a[c] - bf2f(hi));
    }
}

// fused weight-prep: W_out, W_init_h, W_init_c (hi+lo) and W_featp (hi only).
__global__ __launch_bounds__(256) void prep_weights(
    const float* __restrict__ W_out, const float* __restrict__ W_init_h,
    const float* __restrict__ W_init_c, const float* __restrict__ W_featp,
    ush* __restrict__ woh, ush* __restrict__ wol,
    ush* __restrict__ wiH, ush* __restrict__ wiL,
    ush* __restrict__ wfp_h)
{
    const int NWO = V_ * H_ / 4;
    const int NWI = H_ * F_ / 4;
    const int NFP = A_ * F_ / 4;
    const int total = NWO + 2 * NWI + NFP;
    for (int i = blockIdx.x * 256 + threadIdx.x; i < total; i += gridDim.x * 256) {
        const float* src; ush* dh; ush* dl; int j;
        if (i < NWO)                 { src = W_out;    dh = woh;  dl = wol;  j = i; }
        else if (i < NWO + NWI)      { src = W_init_h; dh = wiH;  dl = wiL;  j = i - NWO; }
        else if (i < NWO + 2 * NWI)  { src = W_init_c; dh = wiH + (size_t)512 * F_;
                                       dl = wiL + (size_t)512 * F_; j = i - NWO - NWI; }
        else                         { src = W_featp;  dh = wfp_h; dl = nullptr; j = i - NWO - 2 * NWI; }
        const float4 v = reinterpret_cast<const float4*>(src)[j];
        const float a[4] = {v.x, v.y, v.z, v.w};
        #pragma unroll
        for (int c = 0; c < 4; ++c) {
            const ush h = f2bf(a[c]);
            dh[j * 4 + c] = h;
            if (dl) dl[j * 4 + c] = f2bf(a[c] - bf2f(h));
        }
    }
}

// W_ih columns [0:E) -> wx (2048x512); [E:) ++ W_hh -> wg2 (2048x2560); hi/lo
__global__ __launch_bounds__(256) void prep_wih(
    const float* __restrict__ W_ih, const float* __restrict__ W_hh,
    ush* __restrict__ wxh, ush* __restrict__ wxl,
    ush* __restrict__ wg2h, ush* __restrict__ wg2l)
{
    const int nrow = blockIdx.x;
    for (int k = threadIdx.x; k < E_; k += 256) {
        const float v = W_ih[(size_t)nrow * (E_ + F_) + k];
        const ush h = f2bf(v);
        wxh[(size_t)nrow * E_ + k] = h;
        wxl[(size_t)nrow * E_ + k] = f2bf(v - bf2f(h));
    }
    for (int k = threadIdx.x; k < F_ + H_; k += 256) {
        const float v = (k < F_) ? W_ih[(size_t)nrow * (E_ + F_) + E_ + k]
                                 : W_hh[(size_t)nrow * H_ + (k - F_)];
        const ush h = f2bf(v);
        wg2h[(size_t)nrow * (F_ + H_) + k] = h;
        wg2l[(size_t)nrow * (F_ + H_) + k] = f2bf(v - bf2f(h));
    }
}

// transpose W_hidp (A x H) -> whpT (H x A), bf16
__global__ __launch_bounds__(256) void transpose512(
    const float* __restrict__ in, ush* __restrict__ out)
{
    const int idx = blockIdx.x * 256 + threadIdx.x;
    const int k = idx >> 9, a = idx & 511;
    out[idx] = f2bf(in[(size_t)a * 512 + k]);
}

// reduce init GEMM partials: n<512 -> h0 (+bf16 hi), n>=512 -> c0 (buffer 0)
__global__ __launch_bounds__(256) void init_reduce(
    const float* __restrict__ initp, const float* __restrict__ b_init_h,
    const float* __restrict__ b_init_c, float* __restrict__ h0f,
    float* __restrict__ c0, ush* __restrict__ h_hi)
{
    const int idx = blockIdx.x * 256 + threadIdx.x;
    const int b = idx >> 10, n = idx & 1023;
    float s = 0.f;
    #pragma unroll
    for (int z = 0; z < 8; ++z)
        s += initp[(size_t)z * (B_ * 1024) + (size_t)b * 1024 + n];
    if (n < 512) {
        s += b_init_h[n];
        h0f[b * H_ + n] = s;
        h_hi[b * H_ + n] = f2bf(s);
    } else {
        s += b_init_c[n - 512];
        c0[b * H_ + (n - 512)] = s;
    }
}

// ---------------------------------------------------------------------------
// step2_kernel<ATT>: grid (4, B) when ATT (fs = f-quarter), (1, B) else.
// ---------------------------------------------------------------------------
template<bool ATT>
__global__ __launch_bounds__(512) void step2_kernel(
    const float* __restrict__ gparts, const float* __restrict__ egates,
    const float* __restrict__ b_ih, const float* __restrict__ b_hh,
    float* __restrict__ c2, const float* __restrict__ h0f,
    ush* __restrict__ h_hi, ush* __restrict__ hall_hi,
    const ush* __restrict__ whpT, const float* __restrict__ b_hidp,
    const ush* __restrict__ fpb, const float* __restrict__ W_score,
    const float* __restrict__ b_score, const ush* __restrict__ fbh,
    ush* __restrict__ ctx_hi,
    float* __restrict__ alph_out, int t)
{
    __shared__ float sh_h[H_];
    __shared__ float sh_hp[A_];
    __shared__ float sh_ws[A_];
    __shared__ float sh_sc[200];
    __shared__ float red[2];
    const int tid = threadIdx.x;
    const int fs = blockIdx.x;
    const int b = blockIdx.y;
    const int n = tid;

    float hh;
    if (t > 0) {
        const float* c_old = c2 + (size_t)((t - 1) & 1) * B_ * H_;
        float* c_new = c2 + (size_t)(t & 1) * B_ * H_;
        const float* eg = egates + ((size_t)b * L_ + (t - 1)) * 2048;
        float gi = b_ih[n] + b_hh[n] + eg[n];
        float gf = b_ih[n + 512] + b_hh[n + 512] + eg[n + 512];
        float gg = b_ih[n + 1024] + b_hh[n + 1024] + eg[n + 1024];
        float go = b_ih[n + 1536] + b_hh[n + 1536] + eg[n + 1536];
        #pragma unroll
        for (int z = 0; z < 8; ++z) {
            const float* gz = gparts + (size_t)z * B_ * 2048 + (size_t)b * 2048;
            gi += gz[n]; gf += gz[n + 512]; gg += gz[n + 1024]; go += gz[n + 1536];
        }
        const float cc = fast_sig(gf) * c_old[b * H_ + n] + fast_sig(gi) * fast_tanh(gg);
        hh = fast_sig(go) * fast_tanh(cc);
        if (fs == 0) {
            c_new[b * H_ + n] = cc;
            const ush hi = f2bf(hh);
            h_hi[b * H_ + n] = hi;
            hall_hi[((size_t)(t - 1) * B_ + b) * H_ + n] = hi;
        }
    } else {
        hh = h0f[b * H_ + n];
    }
    if constexpr (!ATT) return;

    sh_h[n] = hh;
    sh_ws[n] = W_score[n];
    __syncthreads();

    // hid_proj (coalesced, bf16 whpT)
    {
        float a0 = 0.f, a1 = 0.f, a2 = 0.f, a3 = 0.f;
        #pragma unroll 4
        for (int k = 0; k < H_; k += 4) {
            a0 = fmaf(sh_h[k + 0], bf2f(whpT[(size_t)(k + 0) * A_ + tid]), a0);
            a1 = fmaf(sh_h[k + 1], bf2f(whpT[(size_t)(k + 1) * A_ + tid]), a1);
            a2 = fmaf(sh_h[k + 2], bf2f(whpT[(size_t)(k + 2) * A_ + tid]), a2);
            a3 = fmaf(sh_h[k + 3], bf2f(whpT[(size_t)(k + 3) * A_ + tid]), a3);
        }
        sh_hp[tid] = (a0 + a1) + (a2 + a3) + b_hidp[tid];
    }
    __syncthreads();

    const int lane = tid & 63, wid = tid >> 6;
    for (int r = wid; r < R_; r += 8) {
        const ushort2* row = reinterpret_cast<const ushort2*>(fpb + ((size_t)b * R_ + r) * A_);
        float acc = 0.f;
        #pragma unroll
        for (int j = 0; j < 4; ++j) {
            const ushort2 u = row[lane + 64 * j];
            const int a = 2 * (lane + 64 * j);
            acc += fast_tanh(bf2f(u.x) + sh_hp[a]) * sh_ws[a];
            acc += fast_tanh(bf2f(u.y) + sh_hp[a + 1]) * sh_ws[a + 1];
        }
        for (int off = 32; off > 0; off >>= 1) acc += __shfl_down(acc, off);
        if (lane == 0) sh_sc[r] = acc + b_score[0];
    }
    __syncthreads();

    if (tid < 64) {
        float m = -1e30f;
        for (int r = tid; r < R_; r += 64) m = fmaxf(m, sh_sc[r]);
        for (int off = 32; off > 0; off >>= 1) m = fmaxf(m, __shfl_xor(m, off));
        float s = 0.f;
        for (int r = tid; r < R_; r += 64) s += __expf(sh_sc[r] - m);
        for (int off = 32; off > 0; off >>= 1) s += __shfl_xor(s, off);
        if (tid == 0) { red[0] = m; red[1] = 1.f / s; }
    }
    __syncthreads();
    const float m = red[0], is = red[1];
    if (tid < R_) {
        const float av = __expf(sh_sc[tid] - m) * is;
        sh_sc[tid] = av;
        if (fs == 0) alph_out[((size_t)b * L_ + t) * R_ + tid] = av;
    }
    __syncthreads();

    // ---- ctx quarter: f = fs*512 + tid, sum over 196 regions (bf16 fbh) ----
    {
        const int f0 = fs * 512 + tid;
        const ush* fp2 = fbh + (size_t)b * R_ * F_ + f0;
        float cx = 0.f;
        #pragma unroll 4
        for (int r = 0; r < R_; ++r)
            cx = fmaf(sh_sc[r], bf2f(fp2[(size_t)r * F_]), cx);
        ctx_hi[(size_t)b * F_ + f0] = f2bf(cx);
    }
}

extern "C" void kernel_launch(void* const* d_in, const int* in_sizes, int n_in,
                              void* d_out, int out_size, void* d_ws, size_t ws_size,
                              hipStream_t stream)
{
    const float* feats    = (const float*)d_in[0];
    const int*   cap      = (const int*)  d_in[1];
    const float* emb      = (const float*)d_in[2];
    const float* W_init_h = (const float*)d_in[3];
    const float* b_init_h = (const float*)d_in[4];
    const float* W_init_c = (const float*)d_in[5];
    const float* b_init_c = (const float*)d_in[6];
    const float* W_ih     = (const float*)d_in[7];
    const float* b_ih     = (const float*)d_in[8];
    const float* W_hh     = (const float*)d_in[9];
    const float* b_hh     = (const float*)d_in[10];
    const float* W_featp  = (const float*)d_in[11];
    const float* b_featp  = (const float*)d_in[12];
    const float* W_hidp   = (const float*)d_in[13];
    const float* b_hidp   = (const float*)d_in[14];
    const float* W_score  = (const float*)d_in[15];
    const float* b_score  = (const float*)d_in[16];
    const float* W_out    = (const float*)d_in[17];
    const float* b_out    = (const float*)d_in[18];

    float* pred     = (float*)d_out;                          // (B,L,V)
    float* alph_out = pred + (size_t)B_ * L_ * V_;            // (B,L,R)

    char* p = (char*)d_ws;
    auto alloc = [&](size_t bytes) { char* q = p; p += (bytes + 255) & ~(size_t)255; return q; };

    ush*   fpb    = (ush*)  alloc((size_t)B_ * R_ * A_ * 2);
    ush*   eh     = (ush*)  alloc((size_t)B_ * L_ * E_ * 2);
    ush*   el     = (ush*)  alloc((size_t)B_ * L_ * E_ * 2);
    ush*   mh     = (ush*)  alloc((size_t)B_ * F_ * 2);
    ush*   ml     = (ush*)  alloc((size_t)B_ * F_ * 2);
    ush*   fbh    = (ush*)  alloc((size_t)B_ * R_ * F_ * 2);
    ush*   wfp_h  = (ush*)  alloc((size_t)A_ * F_ * 2);
    ush*   wiH    = (ush*)  alloc((size_t)1024 * F_ * 2);
    ush*   wiL    = (ush*)  alloc((size_t)1024 * F_ * 2);
    ush*   wxh    = (ush*)  alloc((size_t)2048 * E_ * 2);
    ush*   wxl    = (ush*)  alloc((size_t)2048 * E_ * 2);
    ush*   wg2h   = (ush*)  alloc((size_t)2048 * (F_ + H_) * 2);
    ush*   wg2l   = (ush*)  alloc((size_t)2048 * (F_ + H_) * 2);
    ush*   woh    = (ush*)  alloc((size_t)V_ * H_ * 2);
    ush*   wol    = (ush*)  alloc((size_t)V_ * H_ * 2);
    ush*   whpT   = (ush*)  alloc((size_t)H_ * A_ * 2);
    float* egates = (float*)alloc((size_t)B_ * L_ * 2048 * 4);
    float* h0f    = (float*)alloc((size_t)B_ * H_ * 4);
    float* c2     = (float*)alloc((size_t)2 * B_ * H_ * 4);   // double-buffered c
    ush*   h_hi   = (ush*)  alloc((size_t)B_ * H_ * 2);
    ush*   hallh  = (ush*)  alloc((size_t)L_ * B_ * H_ * 2);
    ush*   ctx_hi = (ush*)  alloc((size_t)B_ * F_ * 2);
    float* gparts = (float*)alloc((size_t)8 * B_ * 2048 * 4);
    float* initp  = (float*)alloc((size_t)8 * B_ * 1024 * 4);

    // ---- one-time prep ----
    prep_feats<<<dim3(4, B_), 256, 0, stream>>>(feats, fbh, mh, ml);
    gather_split<<<768, 256, 0, stream>>>(emb, cap, eh, el);
    prep_weights<<<2048, 256, 0, stream>>>(W_out, W_init_h, W_init_c, W_featp,
                                           woh, wol, wiH, wiL, wfp_h);
    prep_wih<<<2048, 256, 0, stream>>>(W_ih, W_hh, wxh, wxl, wg2h, wg2l);
    transpose512<<<1024, 256, 0, stream>>>(W_hidp, whpT);

    // h0/c0 init: M=64, N=1024 (stacked), K=2048, split-K=8 (full accuracy)
    gemm_gates<true, true><<<dim3(16, 1, 8), 256, 0, stream>>>(
        mh, ml, F_, F_,
        mh, ml, F_,
        wiH, wiL, F_,
        initp, 1024, (long)B_ * 1024, F_ / 8);
    init_reduce<<<256, 256, 0, stream>>>(initp, b_init_h, b_init_c, h0f, c2, h_hi);

    // feat_proj (SPLIT=1, bf16 out, NF=1): 64x64 tiles -> grid(196,8)=1568
    gemm_big<1, 1, true, 1><<<dim3(196, 8), 256, 0, stream>>>(
        fbh, nullptr, F_, wfp_h, nullptr, F_, b_featp, fpb, A_, A_, F_);

    // emb gate part for ALL steps (SPLIT=3, NF=2): grid(24,16)=384
    gemm_big<3, 0, false, 2><<<dim3(24, 16), 256, 0, stream>>>(
        eh, el, E_, wxh, wxl, E_, nullptr, egates, 2048, 2048, E_);

    // ---- sequential decode: 2 kernels per step ----
    for (int t = 0; t < L_; ++t) {
        step2_kernel<true><<<dim3(4, B_), 512, 0, stream>>>(
            gparts, egates, b_ih, b_hh, c2, h0f, h_hi, hallh,
            whpT, b_hidp, fpb, W_score, b_score, fbh, ctx_hi,
            alph_out, t);

        // gates: [ctx | h] @ wg2^T, K=2560, split-K=8; pure bf16 (1 MFMA)
        gemm_gates<false, false><<<dim3(32, 1, 8), 256, 0, stream>>>(
            ctx_hi, nullptr, F_, F_,
            h_hi, nullptr, H_,
            wg2h, nullptr, F_ + H_,
            gparts, 4 * H_, (long)B_ * 4 * H_, (F_ + H_) / 8);
    }

    // final cell: h_L -> hall[L-1]
    step2_kernel<false><<<dim3(1, B_), 512, 0, stream>>>(
        gparts, egates, b_ih, b_hh, c2, h0f, h_hi, hallh,
        whpT, b_hidp, fpb, W_score, b_score, fbh, ctx_hi,
        alph_out, L_);

    // predictions (SPLIT=2: h-hi x (Wout hi+lo)): M=1536 -> 12x128 tiles
    gemm_big128<2, 2, false><<<dim3(12, 47), 512, 0, stream>>>(
        hallh, nullptr, H_, woh, wol, H_, b_out, pred, 0, V_, H_);
}

// Round 18
// 1875.819 us; speedup vs baseline: 1.8171x; 1.0050x over previous
//
#include <hip/hip_runtime.h>

#define B_ 64
#define R_ 196
#define F_ 2048
#define E_ 512
#define H_ 512
#define A_ 512
#define V_ 12000
#define L_ 24

typedef __attribute__((ext_vector_type(8))) short bf16x8;
typedef __attribute__((ext_vector_type(4))) float f32x4;
typedef unsigned short ush;

__device__ __forceinline__ float fast_tanh(float x) {
    float t = __expf(2.f * x);
    return 1.f - 2.f / (t + 1.f);
}
__device__ __forceinline__ float fast_sig(float x) {
    return 1.f / (1.f + __expf(-x));
}
__device__ __forceinline__ ush f2bf(float x) {
    unsigned int u = __float_as_uint(x);
    return (ush)((u + 0x7fffu + ((u >> 16) & 1u)) >> 16);
}
__device__ __forceinline__ float bf2f(ush b) {
    return __uint_as_float(((unsigned int)b) << 16);
}

#define LROW 40   // LDS row stride (32 k-elems + 8 pad)

// ---------------------------------------------------------------------------
// gemm_big128: C = A @ W^T (+bias). Tile 128M x 256N, BK=32, 512 threads.
// NO register prefetch (r17 showed it costs occupancy here: 60->68 VGPR,
// 29->17% occ, +9us). SPLIT=2: Ahi x (Whi,Wlo). CMAP=2: pred layout, NT.
// ---------------------------------------------------------------------------
template<int SPLIT, int CMAP, bool NFAST>
__global__ __launch_bounds__(512) void gemm_big128(
    const ush* __restrict__ Ah, const ush* __restrict__ Al, int lda,
    const ush* __restrict__ Wh, const ush* __restrict__ Wl, int ldw,
    const float* __restrict__ bias, void* __restrict__ Cv,
    int ldc, int N, int K)
{
    constexpr int SMEM_BYTES = (SPLIT == 3) ? 61440 : (SPLIT == 2 ? 51200 : 30720);
    __shared__ __align__(16) char smem[SMEM_BYTES];
    ush* sAh = (ush*)smem;
    ush* sBh = (ush*)(smem + 10240);
    ush* sBl = (ush*)(smem + 30720);
    ush* sAl = (ush*)(smem + 51200);

    const int tid = threadIdx.x;
    const int lane = tid & 63, w = tid >> 6;
    const int mw = w >> 2, nw = w & 3;

    const int nbx = gridDim.x, nby = gridDim.y;
    const int nwg = nbx * nby;
    const int orig = blockIdx.x + nbx * blockIdx.y;
    const int q = nwg >> 3, r = nwg & 7;
    const int xcd = orig & 7, idx = orig >> 3;
    const int lin = (xcd < r ? xcd * (q + 1) : r * (q + 1) + (xcd - r) * q) + idx;
    int bx, by;
    if constexpr (NFAST) { by = lin % nby; bx = lin / nby; }
    else                 { bx = lin % nbx; by = lin / nbx; }
    const int mtile = bx * 128;
    const int ntile = by * 256;

    const int fr = lane & 15, kg = (lane >> 4) * 8;
    const int arow = tid >> 2, aq = (tid & 3) * 8;

    f32x4 acc[4][4];
    #pragma unroll
    for (int mf = 0; mf < 4; ++mf)
        #pragma unroll
        for (int nf = 0; nf < 4; ++nf) acc[mf][nf] = {0.f, 0.f, 0.f, 0.f};

    const uint4 zv = make_uint4(0u, 0u, 0u, 0u);

    for (int kb = 0; kb < K; kb += 32) {
        uint4 a_h = *(const uint4*)(Ah + (size_t)(mtile + arow) * lda + kb + aq);
        uint4 a_l;
        uint4 b_h[2], b_l[2];
        #pragma unroll
        for (int p = 0; p < 2; ++p) {
            const int row = ntile + arow + 128 * p;
            b_h[p] = (row < N) ? *(const uint4*)(Wh + (size_t)row * ldw + kb + aq) : zv;
        }
        if constexpr (SPLIT >= 2) {
            #pragma unroll
            for (int p = 0; p < 2; ++p) {
                const int row = ntile + arow + 128 * p;
                b_l[p] = (row < N) ? *(const uint4*)(Wl + (size_t)row * ldw + kb + aq) : zv;
            }
        }
        if constexpr (SPLIT == 3)
            a_l = *(const uint4*)(Al + (size_t)(mtile + arow) * lda + kb + aq);

        __syncthreads();
        *(uint4*)(sAh + arow * LROW + aq) = a_h;
        #pragma unroll
        for (int p = 0; p < 2; ++p)
            *(uint4*)(sBh + (arow + 128 * p) * LROW + aq) = b_h[p];
        if constexpr (SPLIT >= 2) {
            #pragma unroll
            for (int p = 0; p < 2; ++p)
                *(uint4*)(sBl + (arow + 128 * p) * LROW + aq) = b_l[p];
        }
        if constexpr (SPLIT == 3)
            *(uint4*)(sAl + arow * LROW + aq) = a_l;
        __syncthreads();

        bf16x8 bh[4], bl[4];
        #pragma unroll
        for (int nf = 0; nf < 4; ++nf) {
            bh[nf] = *(const bf16x8*)(sBh + (nw * 64 + nf * 16 + fr) * LROW + kg);
            if constexpr (SPLIT >= 2)
                bl[nf] = *(const bf16x8*)(sBl + (nw * 64 + nf * 16 + fr) * LROW + kg);
        }
        #pragma unroll
        for (int mf = 0; mf < 4; ++mf) {
            const bf16x8 ah = *(const bf16x8*)(sAh + (mw * 64 + mf * 16 + fr) * LROW + kg);
            #pragma unroll
            for (int nf = 0; nf < 4; ++nf) {
                acc[mf][nf] = __builtin_amdgcn_mfma_f32_16x16x32_bf16(ah, bh[nf], acc[mf][nf], 0, 0, 0);
                if constexpr (SPLIT >= 2)
                    acc[mf][nf] = __builtin_amdgcn_mfma_f32_16x16x32_bf16(ah, bl[nf], acc[mf][nf], 0, 0, 0);
            }
            if constexpr (SPLIT == 3) {
                const bf16x8 al = *(const bf16x8*)(sAl + (mw * 64 + mf * 16 + fr) * LROW + kg);
                #pragma unroll
                for (int nf = 0; nf < 4; ++nf)
                    acc[mf][nf] = __builtin_amdgcn_mfma_f32_16x16x32_bf16(al, bh[nf], acc[mf][nf], 0, 0, 0);
            }
        }
    }

    #pragma unroll
    for (int nf = 0; nf < 4; ++nf) {
        const int nn = ntile + nw * 64 + nf * 16 + fr;
        if (nn < N) {
            const float bv = bias ? bias[nn] : 0.f;
            #pragma unroll
            for (int mf = 0; mf < 4; ++mf) {
                #pragma unroll
                for (int rr = 0; rr < 4; ++rr) {
                    const int m = mtile + mw * 64 + mf * 16 + (lane >> 4) * 4 + rr;
                    const float v = acc[mf][nf][rr] + bv;
                    if constexpr (CMAP == 1)
                        ((ush*)Cv)[(size_t)m * ldc + nn] = f2bf(v);
                    else if constexpr (CMAP == 2) {
                        float* dst = (float*)Cv + (size_t)(m & 63) * (L_ * V_)
                                   + (size_t)(m >> 6) * V_ + nn;
                        __builtin_nontemporal_store(v, dst);
                    } else
                        ((float*)Cv)[(size_t)m * ldc + nn] = v;
                }
            }
        }
    }
}

// ---------------------------------------------------------------------------
// gemm_big: 64M x (64*NF)N tile, 256 threads, register-prefetch K-loop
// (helped the small-tile latency-bound kernels in r17).
// ---------------------------------------------------------------------------
template<int SPLIT, int CMAP, bool NFAST, int NF>
__global__ __launch_bounds__(256) void gemm_big(
    const ush* __restrict__ Ah, const ush* __restrict__ Al, int lda,
    const ush* __restrict__ Wh, const ush* __restrict__ Wl, int ldw,
    const float* __restrict__ bias, void* __restrict__ Cv,
    int ldc, int N, int K)
{
    constexpr int ABYTES = 64 * LROW * 2;
    constexpr int BBYTES = 64 * NF * LROW * 2;
    constexpr int SMEM_BYTES = (SPLIT == 3) ? 2 * (ABYTES + BBYTES) : (ABYTES + BBYTES);
    __shared__ __align__(16) char smem[SMEM_BYTES];
    ush* sAh = (ush*)smem;
    ush* sBh = (ush*)(smem + ABYTES);
    ush* sAl = (ush*)(smem + ABYTES + BBYTES);
    ush* sBl = (ush*)(smem + 2 * ABYTES + BBYTES);

    const int tid = threadIdx.x;
    const int lane = tid & 63, w = tid >> 6;

    const int nbx = gridDim.x, nby = gridDim.y;
    const int nwg = nbx * nby;
    int lin = blockIdx.x + nbx * blockIdx.y;
    if ((nwg & 7) == 0) {
        const int q = nwg >> 3;
        lin = (lin & 7) * q + (lin >> 3);
    }
    int bx, by;
    if constexpr (NFAST) { by = lin % nby; bx = lin / nby; }
    else                 { bx = lin % nbx; by = lin / nbx; }
    const int mtile = bx * 64;
    const int ntile = by * (64 * NF);

    const int fr = lane & 15, kg = (lane >> 4) * 8;
    const int arow = tid >> 2, aq = (tid & 3) * 8;

    f32x4 acc[4][NF];
    #pragma unroll
    for (int mf = 0; mf < 4; ++mf)
        #pragma unroll
        for (int nf = 0; nf < NF; ++nf) acc[mf][nf] = {0.f, 0.f, 0.f, 0.f};

    const uint4 zv = make_uint4(0u, 0u, 0u, 0u);
    bool rowok[NF];
    #pragma unroll
    for (int p = 0; p < NF; ++p) rowok[p] = (ntile + arow + 64 * p) < N;

    uint4 a_h = *(const uint4*)(Ah + (size_t)(mtile + arow) * lda + aq);
    uint4 a_l, b_h[NF], b_l[NF];
    #pragma unroll
    for (int p = 0; p < NF; ++p)
        b_h[p] = rowok[p] ? *(const uint4*)(Wh + (size_t)(ntile + arow + 64 * p) * ldw + aq) : zv;
    if constexpr (SPLIT == 3) {
        a_l = *(const uint4*)(Al + (size_t)(mtile + arow) * lda + aq);
        #pragma unroll
        for (int p = 0; p < NF; ++p)
            b_l[p] = rowok[p] ? *(const uint4*)(Wl + (size_t)(ntile + arow + 64 * p) * ldw + aq) : zv;
    }

    for (int kb = 0; kb < K; kb += 32) {
        __syncthreads();
        *(uint4*)(sAh + arow * LROW + aq) = a_h;
        #pragma unroll
        for (int p = 0; p < NF; ++p)
            *(uint4*)(sBh + (arow + 64 * p) * LROW + aq) = b_h[p];
        if constexpr (SPLIT == 3) {
            *(uint4*)(sAl + arow * LROW + aq) = a_l;
            #pragma unroll
            for (int p = 0; p < NF; ++p)
                *(uint4*)(sBl + (arow + 64 * p) * LROW + aq) = b_l[p];
        }
        __syncthreads();

        const int kn = kb + 32;
        if (kn < K) {
            a_h = *(const uint4*)(Ah + (size_t)(mtile + arow) * lda + kn + aq);
            #pragma unroll
            for (int p = 0; p < NF; ++p)
                b_h[p] = rowok[p] ? *(const uint4*)(Wh + (size_t)(ntile + arow + 64 * p) * ldw + kn + aq) : zv;
            if constexpr (SPLIT == 3) {
                a_l = *(const uint4*)(Al + (size_t)(mtile + arow) * lda + kn + aq);
                #pragma unroll
                for (int p = 0; p < NF; ++p)
                    b_l[p] = rowok[p] ? *(const uint4*)(Wl + (size_t)(ntile + arow + 64 * p) * ldw + kn + aq) : zv;
            }
        }

        bf16x8 bhf[NF], blf[NF];
        #pragma unroll
        for (int nf = 0; nf < NF; ++nf) {
            bhf[nf] = *(const bf16x8*)(sBh + (w * (16 * NF) + nf * 16 + fr) * LROW + kg);
            if constexpr (SPLIT == 3)
                blf[nf] = *(const bf16x8*)(sBl + (w * (16 * NF) + nf * 16 + fr) * LROW + kg);
        }
        #pragma unroll
        for (int mf = 0; mf < 4; ++mf) {
            const bf16x8 ahf = *(const bf16x8*)(sAh + (mf * 16 + fr) * LROW + kg);
            if constexpr (SPLIT == 3) {
                const bf16x8 alf = *(const bf16x8*)(sAl + (mf * 16 + fr) * LROW + kg);
                #pragma unroll
                for (int nf = 0; nf < NF; ++nf) {
                    acc[mf][nf] = __builtin_amdgcn_mfma_f32_16x16x32_bf16(ahf, bhf[nf], acc[mf][nf], 0, 0, 0);
                    acc[mf][nf] = __builtin_amdgcn_mfma_f32_16x16x32_bf16(ahf, blf[nf], acc[mf][nf], 0, 0, 0);
                    acc[mf][nf] = __builtin_amdgcn_mfma_f32_16x16x32_bf16(alf, bhf[nf], acc[mf][nf], 0, 0, 0);
                }
            } else {
                #pragma unroll
                for (int nf = 0; nf < NF; ++nf)
                    acc[mf][nf] = __builtin_amdgcn_mfma_f32_16x16x32_bf16(ahf, bhf[nf], acc[mf][nf], 0, 0, 0);
            }
        }
    }

    #pragma unroll
    for (int nf = 0; nf < NF; ++nf) {
        const int nn = ntile + w * (16 * NF) + nf * 16 + fr;
        if (nn < N) {
            const float bv = bias ? bias[nn] : 0.f;
            #pragma unroll
            for (int mf = 0; mf < 4; ++mf) {
                #pragma unroll
                for (int rr = 0; rr < 4; ++rr) {
                    const int m = mtile + mf * 16 + (lane >> 4) * 4 + rr;
                    const float v = acc[mf][nf][rr] + bv;
                    if constexpr (CMAP == 1)
                        ((ush*)Cv)[(size_t)m * ldc + nn] = f2bf(v);
                    else
                        ((float*)Cv)[(size_t)m * ldc + nn] = v;
                }
            }
        }
    }
}

// ---------------------------------------------------------------------------
// gemm_gates<ALO,WLO>: 64x64 tile, segmented A, split-K, register-prefetch.
// Loop gates: <false,false> (pure bf16, 1 MFMA/f).
// ---------------------------------------------------------------------------
template<bool ALO, bool WLO>
__global__ __launch_bounds__(256) void gemm_gates(
    const ush* __restrict__ Ah0, const ush* __restrict__ Al0, int lda0, int k0,
    const ush* __restrict__ Ah1, const ush* __restrict__ Al1, int lda1,
    const ush* __restrict__ Wh, const ush* __restrict__ Wl, int ldw,
    float* __restrict__ C, int ldc, long zstride, int kChunk)
{
    __shared__ ush sAh[64 * LROW];
    __shared__ ush sBh[64 * LROW];
    __shared__ ush sAl[64 * LROW];
    __shared__ ush sBl[64 * LROW];

    const int tid = threadIdx.x;
    const int ntile = blockIdx.x * 64;
    const int kStart = blockIdx.z * kChunk;
    const int kEnd = kStart + kChunk;
    const int lane = tid & 63, w = tid >> 6;
    const int lrow = tid >> 2;
    const int lcol = (tid & 3) * 8;
    const int nrow = ntile + lrow;

    f32x4 acc[4];
    #pragma unroll
    for (int f = 0; f < 4; ++f) acc[f] = {0.f, 0.f, 0.f, 0.f};

    const int fr = lane & 15;
    const int kg = (lane >> 4) * 8;

    auto loadA = [&](int kb, uint4& ah, uint4& al) {
        const ush *ph, *pl; int lda, loc;
        if (kb < k0) { ph = Ah0; pl = Al0; lda = lda0; loc = kb; }
        else         { ph = Ah1; pl = Al1; lda = lda1; loc = kb - k0; }
        ah = *(const uint4*)(ph + (size_t)lrow * lda + loc + lcol);
        if constexpr (ALO)
            al = *(const uint4*)(pl + (size_t)lrow * lda + loc + lcol);
    };

    uint4 a_h, a_l, b_h, b_l;
    loadA(kStart, a_h, a_l);
    b_h = *(const uint4*)(Wh + (size_t)nrow * ldw + kStart + lcol);
    if constexpr (WLO)
        b_l = *(const uint4*)(Wl + (size_t)nrow * ldw + kStart + lcol);

    for (int kb = kStart; kb < kEnd; kb += 32) {
        __syncthreads();
        *(uint4*)(sAh + lrow * LROW + lcol) = a_h;
        *(uint4*)(sBh + lrow * LROW + lcol) = b_h;
        if constexpr (WLO)
            *(uint4*)(sBl + lrow * LROW + lcol) = b_l;
        if constexpr (ALO)
            *(uint4*)(sAl + lrow * LROW + lcol) = a_l;
        __syncthreads();

        const int kn = kb + 32;
        if (kn < kEnd) {
            loadA(kn, a_h, a_l);
            b_h = *(const uint4*)(Wh + (size_t)nrow * ldw + kn + lcol);
            if constexpr (WLO)
                b_l = *(const uint4*)(Wl + (size_t)nrow * ldw + kn + lcol);
        }

        const bf16x8 bh = *(const bf16x8*)(sBh + (16 * w + fr) * LROW + kg);
        bf16x8 bl;
        if constexpr (WLO)
            bl = *(const bf16x8*)(sBl + (16 * w + fr) * LROW + kg);

        #pragma unroll
        for (int f = 0; f < 4; ++f) {
            const bf16x8 ah = *(const bf16x8*)(sAh + (16 * f + fr) * LROW + kg);
            acc[f] = __builtin_amdgcn_mfma_f32_16x16x32_bf16(ah, bh, acc[f], 0, 0, 0);
            if constexpr (WLO)
                acc[f] = __builtin_amdgcn_mfma_f32_16x16x32_bf16(ah, bl, acc[f], 0, 0, 0);
            if constexpr (ALO) {
                const bf16x8 al = *(const bf16x8*)(sAl + (16 * f + fr) * LROW + kg);
                acc[f] = __builtin_amdgcn_mfma_f32_16x16x32_bf16(al, bh, acc[f], 0, 0, 0);
            }
        }
    }

    const int n = ntile + 16 * w + (lane & 15);
    float* Cz = C + (size_t)blockIdx.z * zstride;
    #pragma unroll
    for (int f = 0; f < 4; ++f)
        #pragma unroll
        for (int rr = 0; rr < 4; ++rr) {
            const int m = 16 * f + (lane >> 4) * 4 + rr;
            Cz[(size_t)m * ldc + n] = acc[f][rr];
        }
}

// fused feats pass: fbh (bf16) + per-(b,f) mean -> mh/ml. block (fs, b).
__global__ __launch_bounds__(256) void prep_feats(
    const float* __restrict__ feats, ush* __restrict__ fbh,
    ush* __restrict__ mh, ush* __restrict__ ml)
{
    const int fs = blockIdx.x;
    const int b  = blockIdx.y;
    const int f = fs * 512 + threadIdx.x * 2;
    const float2* fp = (const float2*)(feats + (size_t)b * R_ * F_ + f);
    ush* fo = fbh + (size_t)b * R_ * F_ + f;
    float sx = 0.f, sy = 0.f;
    for (int r = 0; r < R_; ++r) {
        const float2 v = fp[(size_t)r * (F_ / 2)];
        sx += v.x; sy += v.y;
        ushort2 u; u.x = f2bf(v.x); u.y = f2bf(v.y);
        *(ushort2*)(fo + (size_t)r * F_) = u;
    }
    const float s = 1.f / (float)R_;
    sx *= s; sy *= s;
    const size_t mi = (size_t)b * F_ + f;
    const ush hx = f2bf(sx); mh[mi] = hx;     ml[mi] = f2bf(sx - bf2f(hx));
    const ush hy = f2bf(sy); mh[mi + 1] = hy; ml[mi + 1] = f2bf(sy - bf2f(hy));
}

// gather embeddings -> bf16 hi/lo (B,L,E)
__global__ __launch_bounds__(256) void gather_split(
    const float* __restrict__ emb, const int* __restrict__ cap,
    ush* __restrict__ eh, ush* __restrict__ el)
{
    const int idx = blockIdx.x * 256 + threadIdx.x;
    const int bt = idx >> 7, j = idx & 127;
    const int tok = cap[bt];
    const float4 v = reinterpret_cast<const float4*>(emb)[(size_t)tok * (E_ / 4) + j];
    const float a[4] = {v.x, v.y, v.z, v.w};
    #pragma unroll
    for (int c = 0; c < 4; ++c) {
        const ush hi = f2bf(a[c]);
        eh[idx * 4 + c] = hi;
        el[idx * 4 + c] = f2bf(a[c] - bf2f(hi));
    }
}

// fused weight-prep: W_out, W_init_h, W_init_c (hi+lo) and W_featp (hi only).
__global__ __launch_bounds__(256) void prep_weights(
    const float* __restrict__ W_out, const float* __restrict__ W_init_h,
    const float* __restrict__ W_init_c, const float* __restrict__ W_featp,
    ush* __restrict__ woh, ush* __restrict__ wol,
    ush* __restrict__ wiH, ush* __restrict__ wiL,
    ush* __restrict__ wfp_h)
{
    const int NWO = V_ * H_ / 4;
    const int NWI = H_ * F_ / 4;
    const int NFP = A_ * F_ / 4;
    const int total = NWO + 2 * NWI + NFP;
    for (int i = blockIdx.x * 256 + threadIdx.x; i < total; i += gridDim.x * 256) {
        const float* src; ush* dh; ush* dl; int j;
        if (i < NWO)                 { src = W_out;    dh = woh;  dl = wol;  j = i; }
        else if (i < NWO + NWI)      { src = W_init_h; dh = wiH;  dl = wiL;  j = i - NWO; }
        else if (i < NWO + 2 * NWI)  { src = W_init_c; dh = wiH + (size_t)512 * F_;
                                       dl = wiL + (size_t)512 * F_; j = i - NWO - NWI; }
        else                         { src = W_featp;  dh = wfp_h; dl = nullptr; j = i - NWO - 2 * NWI; }
        const float4 v = reinterpret_cast<const float4*>(src)[j];
        const float a[4] = {v.x, v.y, v.z, v.w};
        #pragma unroll
        for (int c = 0; c < 4; ++c) {
            const ush h = f2bf(a[c]);
            dh[j * 4 + c] = h;
            if (dl) dl[j * 4 + c] = f2bf(a[c] - bf2f(h));
        }
    }
}

// W_ih columns [0:E) -> wx (2048x512); [E:) ++ W_hh -> wg2 (2048x2560); hi/lo
__global__ __launch_bounds__(256) void prep_wih(
    const float* __restrict__ W_ih, const float* __restrict__ W_hh,
    ush* __restrict__ wxh, ush* __restrict__ wxl,
    ush* __restrict__ wg2h, ush* __restrict__ wg2l)
{
    const int nrow = blockIdx.x;
    for (int k = threadIdx.x; k < E_; k += 256) {
        const float v = W_ih[(size_t)nrow * (E_ + F_) + k];
        const ush h = f2bf(v);
        wxh[(size_t)nrow * E_ + k] = h;
        wxl[(size_t)nrow * E_ + k] = f2bf(v - bf2f(h));
    }
    for (int k = threadIdx.x; k < F_ + H_; k += 256) {
        const float v = (k < F_) ? W_ih[(size_t)nrow * (E_ + F_) + E_ + k]
                                 : W_hh[(size_t)nrow * H_ + (k - F_)];
        const ush h = f2bf(v);
        wg2h[(size_t)nrow * (F_ + H_) + k] = h;
        wg2l[(size_t)nrow * (F_ + H_) + k] = f2bf(v - bf2f(h));
    }
}

// transpose W_hidp (A x H) -> whpT (H x A), bf16
__global__ __launch_bounds__(256) void transpose512(
    const float* __restrict__ in, ush* __restrict__ out)
{
    const int idx = blockIdx.x * 256 + threadIdx.x;
    const int k = idx >> 9, a = idx & 511;
    out[idx] = f2bf(in[(size_t)a * 512 + k]);
}

// reduce init GEMM partials: n<512 -> h0 (+bf16 hi), n>=512 -> c0 (buffer 0)
__global__ __launch_bounds__(256) void init_reduce(
    const float* __restrict__ initp, const float* __restrict__ b_init_h,
    const float* __restrict__ b_init_c, float* __restrict__ h0f,
    float* __restrict__ c0, ush* __restrict__ h_hi)
{
    const int idx = blockIdx.x * 256 + threadIdx.x;
    const int b = idx >> 10, n = idx & 1023;
    float s = 0.f;
    #pragma unroll
    for (int z = 0; z < 8; ++z)
        s += initp[(size_t)z * (B_ * 1024) + (size_t)b * 1024 + n];
    if (n < 512) {
        s += b_init_h[n];
        h0f[b * H_ + n] = s;
        h_hi[b * H_ + n] = f2bf(s);
    } else {
        s += b_init_c[n - 512];
        c0[b * H_ + (n - 512)] = s;
    }
}

// ---------------------------------------------------------------------------
// step2_kernel<ATT>: grid (4, B) when ATT (fs = f-quarter), (1, B) else.
// ---------------------------------------------------------------------------
template<bool ATT>
__global__ __launch_bounds__(512) void step2_kernel(
    const float* __restrict__ gparts, const float* __restrict__ egates,
    const float* __restrict__ b_ih, const float* __restrict__ b_hh,
    float* __restrict__ c2, const float* __restrict__ h0f,
    ush* __restrict__ h_hi, ush* __restrict__ hall_hi,
    const ush* __restrict__ whpT, const float* __restrict__ b_hidp,
    const ush* __restrict__ fpb, const float* __restrict__ W_score,
    const float* __restrict__ b_score, const ush* __restrict__ fbh,
    ush* __restrict__ ctx_hi,
    float* __restrict__ alph_out, int t)
{
    __shared__ float sh_h[H_];
    __shared__ float sh_hp[A_];
    __shared__ float sh_ws[A_];
    __shared__ float sh_sc[200];
    __shared__ float red[2];
    const int tid = threadIdx.x;
    const int fs = blockIdx.x;
    const int b = blockIdx.y;
    const int n = tid;

    float hh;
    if (t > 0) {
        const float* c_old = c2 + (size_t)((t - 1) & 1) * B_ * H_;
        float* c_new = c2 + (size_t)(t & 1) * B_ * H_;
        const float* eg = egates + ((size_t)b * L_ + (t - 1)) * 2048;
        float gi = b_ih[n] + b_hh[n] + eg[n];
        float gf = b_ih[n + 512] + b_hh[n + 512] + eg[n + 512];
        float gg = b_ih[n + 1024] + b_hh[n + 1024] + eg[n + 1024];
        float go = b_ih[n + 1536] + b_hh[n + 1536] + eg[n + 1536];
        #pragma unroll
        for (int z = 0; z < 8; ++z) {
            const float* gz = gparts + (size_t)z * B_ * 2048 + (size_t)b * 2048;
            gi += gz[n]; gf += gz[n + 512]; gg += gz[n + 1024]; go += gz[n + 1536];
        }
        const float cc = fast_sig(gf) * c_old[b * H_ + n] + fast_sig(gi) * fast_tanh(gg);
        hh = fast_sig(go) * fast_tanh(cc);
        if (fs == 0) {
            c_new[b * H_ + n] = cc;
            const ush hi = f2bf(hh);
            h_hi[b * H_ + n] = hi;
            hall_hi[((size_t)(t - 1) * B_ + b) * H_ + n] = hi;
        }
    } else {
        hh = h0f[b * H_ + n];
    }
    if constexpr (!ATT) return;

    sh_h[n] = hh;
    sh_ws[n] = W_score[n];
    __syncthreads();

    // hid_proj (coalesced, bf16 whpT)
    {
        float a0 = 0.f, a1 = 0.f, a2 = 0.f, a3 = 0.f;
        #pragma unroll 4
        for (int k = 0; k < H_; k += 4) {
            a0 = fmaf(sh_h[k + 0], bf2f(whpT[(size_t)(k + 0) * A_ + tid]), a0);
            a1 = fmaf(sh_h[k + 1], bf2f(whpT[(size_t)(k + 1) * A_ + tid]), a1);
            a2 = fmaf(sh_h[k + 2], bf2f(whpT[(size_t)(k + 2) * A_ + tid]), a2);
            a3 = fmaf(sh_h[k + 3], bf2f(whpT[(size_t)(k + 3) * A_ + tid]), a3);
        }
        sh_hp[tid] = (a0 + a1) + (a2 + a3) + b_hidp[tid];
    }
    __syncthreads();

    const int lane = tid & 63, wid = tid >> 6;
    for (int r = wid; r < R_; r += 8) {
        const ushort2* row = reinterpret_cast<const ushort2*>(fpb + ((size_t)b * R_ + r) * A_);
        float acc = 0.f;
        #pragma unroll
        for (int j = 0; j < 4; ++j) {
            const ushort2 u = row[lane + 64 * j];
            const int a = 2 * (lane + 64 * j);
            acc += fast_tanh(bf2f(u.x) + sh_hp[a]) * sh_ws[a];
            acc += fast_tanh(bf2f(u.y) + sh_hp[a + 1]) * sh_ws[a + 1];
        }
        for (int off = 32; off > 0; off >>= 1) acc += __shfl_down(acc, off);
        if (lane == 0) sh_sc[r] = acc + b_score[0];
    }
    __syncthreads();

    if (tid < 64) {
        float m = -1e30f;
        for (int r = tid; r < R_; r += 64) m = fmaxf(m, sh_sc[r]);
        for (int off = 32; off > 0; off >>= 1) m = fmaxf(m, __shfl_xor(m, off));
        float s = 0.f;
        for (int r = tid; r < R_; r += 64) s += __expf(sh_sc[r] - m);
        for (int off = 32; off > 0; off >>= 1) s += __shfl_xor(s, off);
        if (tid == 0) { red[0] = m; red[1] = 1.f / s; }
    }
    __syncthreads();
    const float m = red[0], is = red[1];
    if (tid < R_) {
        const float av = __expf(sh_sc[tid] - m) * is;
        sh_sc[tid] = av;
        if (fs == 0) alph_out[((size_t)b * L_ + t) * R_ + tid] = av;
    }
    __syncthreads();

    // ---- ctx quarter: f = fs*512 + tid, sum over 196 regions (bf16 fbh) ----
    {
        const int f0 = fs * 512 + tid;
        const ush* fp2 = fbh + (size_t)b * R_ * F_ + f0;
        float cx = 0.f;
        #pragma unroll 4
        for (int r = 0; r < R_; ++r)
            cx = fmaf(sh_sc[r], bf2f(fp2[(size_t)r * F_]), cx);
        ctx_hi[(size_t)b * F_ + f0] = f2bf(cx);
    }
}

extern "C" void kernel_launch(void* const* d_in, const int* in_sizes, int n_in,
                              void* d_out, int out_size, void* d_ws, size_t ws_size,
                              hipStream_t stream)
{
    const float* feats    = (const float*)d_in[0];
    const int*   cap      = (const int*)  d_in[1];
    const float* emb      = (const float*)d_in[2];
    const float* W_init_h = (const float*)d_in[3];
    const float* b_init_h = (const float*)d_in[4];
    const float* W_init_c = (const float*)d_in[5];
    const float* b_init_c = (const float*)d_in[6];
    const float* W_ih     = (const float*)d_in[7];
    const float* b_ih     = (const float*)d_in[8];
    const float* W_hh     = (const float*)d_in[9];
    const float* b_hh     = (const float*)d_in[10];
    const float* W_featp  = (const float*)d_in[11];
    const float* b_featp  = (const float*)d_in[12];
    const float* W_hidp   = (const float*)d_in[13];
    const float* b_hidp   = (const float*)d_in[14];
    const float* W_score  = (const float*)d_in[15];
    const float* b_score  = (const float*)d_in[16];
    const float* W_out    = (const float*)d_in[17];
    const float* b_out    = (const float*)d_in[18];

    float* pred     = (float*)d_out;                          // (B,L,V)
    float* alph_out = pred + (size_t)B_ * L_ * V_;            // (B,L,R)

    char* p = (char*)d_ws;
    auto alloc = [&](size_t bytes) { char* q = p; p += (bytes + 255) & ~(size_t)255; return q; };

    ush*   fpb    = (ush*)  alloc((size_t)B_ * R_ * A_ * 2);
    ush*   eh     = (ush*)  alloc((size_t)B_ * L_ * E_ * 2);
    ush*   el     = (ush*)  alloc((size_t)B_ * L_ * E_ * 2);
    ush*   mh     = (ush*)  alloc((size_t)B_ * F_ * 2);
    ush*   ml     = (ush*)  alloc((size_t)B_ * F_ * 2);
    ush*   fbh    = (ush*)  alloc((size_t)B_ * R_ * F_ * 2);
    ush*   wfp_h  = (ush*)  alloc((size_t)A_ * F_ * 2);
    ush*   wiH    = (ush*)  alloc((size_t)1024 * F_ * 2);
    ush*   wiL    = (ush*)  alloc((size_t)1024 * F_ * 2);
    ush*   wxh    = (ush*)  alloc((size_t)2048 * E_ * 2);
    ush*   wxl    = (ush*)  alloc((size_t)2048 * E_ * 2);
    ush*   wg2h   = (ush*)  alloc((size_t)2048 * (F_ + H_) * 2);
    ush*   wg2l   = (ush*)  alloc((size_t)2048 * (F_ + H_) * 2);
    ush*   woh    = (ush*)  alloc((size_t)V_ * H_ * 2);
    ush*   wol    = (ush*)  alloc((size_t)V_ * H_ * 2);
    ush*   whpT   = (ush*)  alloc((size_t)H_ * A_ * 2);
    float* egates = (float*)alloc((size_t)B_ * L_ * 2048 * 4);
    float* h0f    = (float*)alloc((size_t)B_ * H_ * 4);
    float* c2     = (float*)alloc((size_t)2 * B_ * H_ * 4);   // double-buffered c
    ush*   h_hi   = (ush*)  alloc((size_t)B_ * H_ * 2);
    ush*   hallh  = (ush*)  alloc((size_t)L_ * B_ * H_ * 2);
    ush*   ctx_hi = (ush*)  alloc((size_t)B_ * F_ * 2);
    float* gparts = (float*)alloc((size_t)8 * B_ * 2048 * 4);
    float* initp  = (float*)alloc((size_t)8 * B_ * 1024 * 4);

    // ---- one-time prep ----
    prep_feats<<<dim3(4, B_), 256, 0, stream>>>(feats, fbh, mh, ml);
    gather_split<<<768, 256, 0, stream>>>(emb, cap, eh, el);
    prep_weights<<<2048, 256, 0, stream>>>(W_out, W_init_h, W_init_c, W_featp,
                                           woh, wol, wiH, wiL, wfp_h);
    prep_wih<<<2048, 256, 0, stream>>>(W_ih, W_hh, wxh, wxl, wg2h, wg2l);
    transpose512<<<1024, 256, 0, stream>>>(W_hidp, whpT);

    // h0/c0 init: M=64, N=1024 (stacked), K=2048, split-K=8 (full accuracy)
    gemm_gates<true, true><<<dim3(16, 1, 8), 256, 0, stream>>>(
        mh, ml, F_, F_,
        mh, ml, F_,
        wiH, wiL, F_,
        initp, 1024, (long)B_ * 1024, F_ / 8);
    init_reduce<<<256, 256, 0, stream>>>(initp, b_init_h, b_init_c, h0f, c2, h_hi);

    // feat_proj (SPLIT=1, bf16 out, NF=1): 64x64 tiles -> grid(196,8)=1568
    gemm_big<1, 1, true, 1><<<dim3(196, 8), 256, 0, stream>>>(
        fbh, nullptr, F_, wfp_h, nullptr, F_, b_featp, fpb, A_, A_, F_);

    // emb gate part for ALL steps (SPLIT=3, NF=2): grid(24,16)=384
    gemm_big<3, 0, false, 2><<<dim3(24, 16), 256, 0, stream>>>(
        eh, el, E_, wxh, wxl, E_, nullptr, egates, 2048, 2048, E_);

    // ---- sequential decode: 2 kernels per step ----
    for (int t = 0; t < L_; ++t) {
        step2_kernel<true><<<dim3(4, B_), 512, 0, stream>>>(
            gparts, egates, b_ih, b_hh, c2, h0f, h_hi, hallh,
            whpT, b_hidp, fpb, W_score, b_score, fbh, ctx_hi,
            alph_out, t);

        // gates: [ctx | h] @ wg2^T, K=2560, split-K=8; pure bf16 (1 MFMA)
        gemm_gates<false, false><<<dim3(32, 1, 8), 256, 0, stream>>>(
            ctx_hi, nullptr, F_, F_,
            h_hi, nullptr, H_,
            wg2h, nullptr, F_ + H_,
            gparts, 4 * H_, (long)B_ * 4 * H_, (F_ + H_) / 8);
    }

    // final cell: h_L -> hall[L-1]
    step2_kernel<false><<<dim3(1, B_), 512, 0, stream>>>(
        gparts, egates, b_ih, b_hh, c2, h0f, h_hi, hallh,
        whpT, b_hidp, fpb, W_score, b_score, fbh, ctx_hi,
        alph_out, L_);

    // predictions (SPLIT=2: h-hi x (Wout hi+lo)): M=1536 -> 12x128 tiles
    gemm_big128<2, 2, false><<<dim3(12, 47), 512, 0, stream>>>(
        hallh, nullptr, H_, woh, wol, H_, b_out, pred, 0, V_, H_);
}